// Round 7
// baseline (1050.778 us; speedup 1.0000x reference)
//
#include <hip/hip_runtime.h>
#include <cstdint>

typedef unsigned short u16;
typedef __bf16 bf16x8 __attribute__((ext_vector_type(8)));
typedef float f32x4 __attribute__((ext_vector_type(4)));

__device__ __forceinline__ float bf2f(u16 h) {
  union { uint32_t u; float f; } v; v.u = (uint32_t)h << 16; return v.f;
}
__device__ __forceinline__ u16 f2bf(float f) {
  union { float f; uint32_t u; } v; v.f = f;
  uint32_t r = v.u + 0x7fffu + ((v.u >> 16) & 1u);
  return (u16)(r >> 16);
}
__device__ __forceinline__ float sigmoidf_(float x) {
  return 1.0f / (1.0f + __expf(-x));
}
__device__ __forceinline__ void load_lds16(const void* g, void* l) {
  __builtin_amdgcn_global_load_lds(
      (const __attribute__((address_space(1))) void*)g,
      (__attribute__((address_space(3))) void*)l, 16, 0, 0);
}
#define BAR() __builtin_amdgcn_s_barrier()
#define SB0() __builtin_amdgcn_sched_barrier(0)

// ---------------- flat convert f32 -> bf16 (n multiple of 4) -------------
__global__ __launch_bounds__(256) void cvt_f2b(const float* __restrict__ in,
                                               u16* __restrict__ out) {
  long i = ((long)blockIdx.x * 256 + threadIdx.x) * 4;
  float4 v = *(const float4*)(in + i);
  uint2 o;
  o.x = (uint32_t)f2bf(v.x) | ((uint32_t)f2bf(v.y) << 16);
  o.y = (uint32_t)f2bf(v.z) | ((uint32_t)f2bf(v.w) << 16);
  *((uint2*)(out + i)) = o;
}

// ------------- transpose+convert: in f32 [K][N] -> out bf16 [N][K] -------
__global__ __launch_bounds__(256) void transpose_cvt(
    const float* __restrict__ in, u16* __restrict__ out, int K, int N) {
  __shared__ float t[32][33];
  int n0 = blockIdx.x * 32, k0 = blockIdx.y * 32;
  int tx = threadIdx.x & 31, ty = threadIdx.x >> 5;
#pragma unroll
  for (int i = 0; i < 32; i += 8)
    t[ty + i][tx] = in[(long)(k0 + ty + i) * N + n0 + tx];
  __syncthreads();
#pragma unroll
  for (int i = 0; i < 32; i += 8)
    out[(long)(n0 + ty + i) * K + k0 + tx] = f2bf(t[tx][ty + i]);
}

// ------ fused q,k projection from bf16: [T,1024]@[1024,16]x2 -> f32 ------
__global__ __launch_bounds__(256) void proj_qk_b(
    const u16* __restrict__ xb, const float* __restrict__ wq,
    const float* __restrict__ bq, const float* __restrict__ wk,
    const float* __restrict__ bk, float* __restrict__ qout,
    float* __restrict__ kout) {
  int tid = threadIdx.x;
  long t0 = (long)blockIdx.x * 16;
  int col = tid & 15, tok = tid >> 4;
  const u16* xr = xb + (t0 + tok) * 1024;
  float aq = 0.f, ak = 0.f;
  for (int k = 0; k < 1024; k += 4) {
    uint2 xv = *(const uint2*)(xr + k);
    float x0 = bf2f((u16)(xv.x & 0xffff)), x1 = bf2f((u16)(xv.x >> 16));
    float x2 = bf2f((u16)(xv.y & 0xffff)), x3 = bf2f((u16)(xv.y >> 16));
    aq += x0 * wq[(long)k * 16 + col] + x1 * wq[(long)(k + 1) * 16 + col] +
          x2 * wq[(long)(k + 2) * 16 + col] + x3 * wq[(long)(k + 3) * 16 + col];
    ak += x0 * wk[(long)k * 16 + col] + x1 * wk[(long)(k + 1) * 16 + col] +
          x2 * wk[(long)(k + 2) * 16 + col] + x3 * wk[(long)(k + 3) * 16 + col];
  }
  qout[(t0 + tok) * 16 + col] = aq + bq[col];
  kout[(t0 + tok) * 16 + col] = ak + bk[col];
}

// ------ single projection from bf16 ------
__global__ __launch_bounds__(256) void proj_b(const u16* __restrict__ xb,
                                              const float* __restrict__ w,
                                              const float* __restrict__ b,
                                              float* __restrict__ out) {
  int tid = threadIdx.x;
  long t0 = (long)blockIdx.x * 16;
  int col = tid & 15, tok = tid >> 4;
  const u16* xr = xb + (t0 + tok) * 1024;
  float acc = 0.f;
  for (int k = 0; k < 1024; k += 4) {
    uint2 xv = *(const uint2*)(xr + k);
    acc += bf2f((u16)(xv.x & 0xffff)) * w[(long)k * 16 + col] +
           bf2f((u16)(xv.x >> 16)) * w[(long)(k + 1) * 16 + col] +
           bf2f((u16)(xv.y & 0xffff)) * w[(long)(k + 2) * 16 + col] +
           bf2f((u16)(xv.y >> 16)) * w[(long)(k + 3) * 16 + col];
  }
  out[(t0 + tok) * 16 + col] = acc + b[col];
}

// ------ single projection from f32 ------
__global__ __launch_bounds__(256) void proj_f(const float* __restrict__ in,
                                              const float* __restrict__ w,
                                              const float* __restrict__ b,
                                              float* __restrict__ out) {
  int tid = threadIdx.x;
  long t0 = (long)blockIdx.x * 16;
  int col = tid & 15, tok = tid >> 4;
  const float* xr = in + (t0 + tok) * 1024;
  float acc = 0.f;
  for (int k = 0; k < 1024; k += 4) {
    float4 xv = *(const float4*)(xr + k);
    acc += xv.x * w[(long)k * 16 + col] + xv.y * w[(long)(k + 1) * 16 + col] +
           xv.z * w[(long)(k + 2) * 16 + col] + xv.w * w[(long)(k + 3) * 16 + col];
  }
  out[(t0 + tok) * 16 + col] = acc + b[col];
}

// ===== 256x256 MFMA GEMM, register-pipelined 1-barrier phases =============
// C[M,N] = act(A[M,K]bf16 @ BT[N,K]^T + bias). M%256==0, N%256==0, K%256==0
// (KT=K/64 even, >=4). 512 thr = 8 waves (2Mx4N). LDS 128KB = 4 slots
// S(t%4)=[buf=(t>>1)&1][kk=t&1], each 16KB A + 16KB B, st-swizzled via
// inverse-swizzled global source + swizzled ds_read.
// Phase t: {ldab regNEXT <- S(t+1); lgkmcnt(12); MFMA(regCUR); stage S(t%4)
// with ktile(t)+2; vmcnt(8); s_barrier}. Landing: vm(8)+BAR at end of q
// guarantees stage(q-2) landed => ldab(t) slot (staged t-3) is safe.
// Overwrite: stage(t) rewrites the slot consumed at t (reads done via
// lgkm12 before mma; cross-wave margin ~1000cyc past shared barrier).
template <int ACT>
__global__ __launch_bounds__(512) void gemm256(
    const u16* __restrict__ A, const u16* __restrict__ BT,
    const float* __restrict__ bias, u16* __restrict__ C, int M, int N,
    int K) {
  __shared__ __attribute__((aligned(16))) u16 lds[65536];  // 128 KB
  const int tid = threadIdx.x;
  const int wid = tid >> 6, lane = tid & 63;
  const int wm = wid >> 2, wn = wid & 3;
  const int lrow = lane & 15, g = lane >> 4;

  int nwg = gridDim.x * gridDim.y;
  int orig = blockIdx.y * gridDim.x + blockIdx.x;
  int wg = (nwg & 7) ? orig : ((orig & 7) * (nwg >> 3) + (orig >> 3));
  const long bn = (long)(wg % gridDim.x) * 256;
  const long bm = (long)(wg / gridDim.x) * 256;

  const int rr = wid * 16 + (lane >> 2);                        // staging row
  const int esrc = ((lane & 3) * 8) ^ (((lane >> 5) & 1) * 16); // src swizzle
  const u16* Abase = A + (bm + rr) * (long)K + esrc;
  const u16* Bbase = BT + (bn + rr) * (long)K + esrc;
  const long jstep = (long)128 * K;
  char* ldsc = (char*)lds;
  const int ldsw = wid * 1024;

  const int swr = ((lrow >> 3) & 1) * 32;
  const int aoff = (wm * 128 + lrow) * 64 + ((g * 16) ^ swr);
  const int boff = 32768 + (wn * 64 + lrow) * 64 + ((g * 16) ^ swr);

  f32x4 acc[8][4] = {};
  const int KT = K >> 6;

  auto stage = [&](int buf, int kk, int kt) {  // 4 x global_load_lds
    const u16* sA = Abase + (long)kt * 64 + kk * 32;
    const u16* sB = Bbase + (long)kt * 64 + kk * 32;
    int dA = buf * 65536 + kk * 16384 + ldsw;
    int dB = dA + 32768;
    load_lds16(sA, ldsc + dA);
    load_lds16(sA + jstep, ldsc + dA + 8192);
    load_lds16(sB, ldsc + dB);
    load_lds16(sB + jstep, ldsc + dB + 8192);
  };

#define LDAB(AF, BQ, BUF, KK)                                               \
  {                                                                         \
    const char* _b = ldsc + (BUF) * 65536 + (KK) * 16384;                   \
    _Pragma("unroll") for (int m = 0; m < 8; m++)                           \
        AF[m] = *(const bf16x8*)(_b + aoff + m * 1024);                     \
    _Pragma("unroll") for (int n = 0; n < 4; n++)                           \
        BQ[n] = *(const bf16x8*)(_b + boff + n * 1024);                     \
  }
#define MMA(AF, BQ)                                                         \
  __builtin_amdgcn_s_setprio(1);                                            \
  _Pragma("unroll") for (int m = 0; m < 8; m++)                             \
  _Pragma("unroll") for (int n = 0; n < 4; n++)                             \
      acc[m][n] = __builtin_amdgcn_mfma_f32_16x16x32_bf16(AF[m], BQ[n],     \
                                                          acc[m][n], 0, 0,  \
                                                          0);               \
  __builtin_amdgcn_s_setprio(0);
#define WLG12() asm volatile("s_waitcnt lgkmcnt(12)" ::: "memory")
#define WLG0() asm volatile("s_waitcnt lgkmcnt(0)" ::: "memory")
#define PHASE(CAF, CBQ, NAF, NBQ, NBUF, NKK, SBUF, SKK, SKT)                \
  LDAB(NAF, NBQ, NBUF, NKK);                                                \
  WLG12();                                                                  \
  SB0();                                                                    \
  MMA(CAF, CBQ);                                                            \
  stage(SBUF, SKK, SKT);                                                    \
  asm volatile("s_waitcnt vmcnt(8)" ::: "memory");                          \
  BAR();

  bf16x8 afA[8], bqA[4], afB[8], bqB[4];

  // prologue: fill all 4 slots (ktiles 0,0,1,1); S0,S1 landed; preload regA
  stage(0, 0, 0);
  stage(0, 1, 0);
  stage(1, 0, 1);
  stage(1, 1, 1);
  asm volatile("s_waitcnt vmcnt(8)" ::: "memory");
  BAR();
  LDAB(afA, bqA, 0, 0);

  for (int kt = 0; kt + 3 < KT; kt += 2) {
    PHASE(afA, bqA, afB, bqB, 0, 1, 0, 0, kt + 2);  // consume (0,0)=ktile kt,k0
    PHASE(afB, bqB, afA, bqA, 1, 0, 0, 1, kt + 2);  // consume (0,1)
    PHASE(afA, bqA, afB, bqB, 1, 1, 1, 0, kt + 3);  // consume (1,0)
    PHASE(afB, bqB, afA, bqA, 0, 0, 1, 1, kt + 3);  // consume (1,1)
  }
  // peeled tail: consume ktiles KT-2, KT-1 (no staging; exact vm drains)
  LDAB(afB, bqB, 0, 1);
  WLG12(); SB0();
  MMA(afA, bqA);
  asm volatile("s_waitcnt vmcnt(4)" ::: "memory");
  BAR();
  LDAB(afA, bqA, 1, 0);
  WLG12(); SB0();
  MMA(afB, bqB);
  asm volatile("s_waitcnt vmcnt(0)" ::: "memory");
  BAR();
  LDAB(afB, bqB, 1, 1);
  WLG12(); SB0();
  MMA(afA, bqA);
  BAR();
  WLG0(); SB0();
  MMA(afB, bqB);
  BAR();  // all reads done before epilogue overwrites LDS

  // ---- epilogue: bias/act -> LDS (bf16 tile) -> coalesced uint4 stores ----
#pragma unroll
  for (int n = 0; n < 4; n++) {
    int cl = wn * 64 + n * 16 + lrow;
    float bb = bias[bn + cl];
#pragma unroll
    for (int m = 0; m < 8; m++) {
      int rl = wm * 128 + m * 16 + g * 4;
#pragma unroll
      for (int i = 0; i < 4; i++) {
        float v = acc[m][n][i] + bb;
        if (ACT == 1) v = fmaxf(v, 0.f);
        lds[(rl + i) * 256 + cl] = f2bf(v);
      }
    }
  }
  BAR();
  const uint4* lv = (const uint4*)lds;
#pragma unroll
  for (int it = 0; it < 16; it++) {
    int idx = it * 512 + tid;
    int row = idx >> 5;
    int cu = (idx & 31) * 8;
    *(uint4*)&C[(bm + row) * (long)N + bn + cu] = lv[idx];
  }
#undef LDAB
#undef MMA
#undef WLG12
#undef WLG0
#undef PHASE
}

// -- kv partial: part[b,h,sc,d] = sum_{s in chunk} sig(k)*v  (v bf16) -----
__global__ __launch_bounds__(256) void kv_part(const float* __restrict__ kp,
                                               const u16* __restrict__ v,
                                               float* __restrict__ part) {
  int bid = blockIdx.x;
  int sc = bid & 7, h = (bid >> 3) & 15, b = bid >> 7;
  int d = threadIdx.x & 63, si = threadIdx.x >> 6;
  float acc = 0.f;
  int s0 = sc * 512;
  for (int s = s0 + si; s < s0 + 512; s += 4) {
    long tok = (long)b * 4096 + s;
    float sk = sigmoidf_(kp[tok * 16 + h]);
    acc += sk * bf2f(v[tok * 1024 + h * 64 + d]);
  }
  __shared__ float red[4][64];
  red[si][d] = acc;
  __syncthreads();
  if (si == 0)
    part[(long)bid * 64 + d] = red[0][d] + red[1][d] + red[2][d] + red[3][d];
}

// ---------------- reduce chunks + cumsum over heads ----------------------
__global__ __launch_bounds__(64) void kv_finish(const float* __restrict__ part,
                                                float* __restrict__ scum) {
  int b = blockIdx.x, d = threadIdx.x;
  float run = 0.f;
  for (int h = 0; h < 16; h++) {
    float s = 0.f;
    for (int sc = 0; sc < 8; sc++)
      s += part[(((long)b * 16 + h) * 8 + sc) * 64 + d];
    run += s;
    scum[((long)b * 16 + h) * 64 + d] = run;
  }
}

// ------- pre[t, h*64+d] = sigmoid(q[t,h]) * scum[b,h,d]  -> bf16 ---------
__global__ __launch_bounds__(256) void premul(const float* __restrict__ qp,
                                              const float* __restrict__ scum,
                                              u16* __restrict__ out) {
  long idx = ((long)blockIdx.x * 256 + threadIdx.x) * 8;
  long tok = idx >> 10;
  int c = (int)(idx & 1023);
  int h = c >> 6, d0 = c & 63;
  int b = (int)(tok >> 12);
  float sq = sigmoidf_(qp[tok * 16 + h]);
  const float* sp = scum + ((long)b * 16 + h) * 64 + d0;
  uint4 o;
  o.x = (uint32_t)f2bf(sq * sp[0]) | ((uint32_t)f2bf(sq * sp[1]) << 16);
  o.y = (uint32_t)f2bf(sq * sp[2]) | ((uint32_t)f2bf(sq * sp[3]) << 16);
  o.z = (uint32_t)f2bf(sq * sp[4]) | ((uint32_t)f2bf(sq * sp[5]) << 16);
  o.w = (uint32_t)f2bf(sq * sp[6]) | ((uint32_t)f2bf(sq * sp[7]) << 16);
  *((uint4*)(out + idx)) = o;
}

// --- out_f32 = LayerNorm(a_bf16 + r_f32)*g + be ; optional bf16 copy -----
__global__ __launch_bounds__(256) void ln_res(const u16* __restrict__ a,
                                              const float* __restrict__ r,
                                              const float* __restrict__ g,
                                              const float* __restrict__ be,
                                              float* __restrict__ out,
                                              u16* __restrict__ outb) {
  long row = blockIdx.x;
  int tid = threadIdx.x;
  uint2 av = ((const uint2*)(a + row * 1024))[tid];
  float4 rv = ((const float4*)(r + row * 1024))[tid];
  float y[4];
  y[0] = bf2f((u16)(av.x & 0xffff)) + rv.x;
  y[1] = bf2f((u16)(av.x >> 16)) + rv.y;
  y[2] = bf2f((u16)(av.y & 0xffff)) + rv.z;
  y[3] = bf2f((u16)(av.y >> 16)) + rv.w;
  float s = y[0] + y[1] + y[2] + y[3];
  float q = y[0] * y[0] + y[1] * y[1] + y[2] * y[2] + y[3] * y[3];
#pragma unroll
  for (int o = 32; o > 0; o >>= 1) {
    s += __shfl_down(s, o);
    q += __shfl_down(q, o);
  }
  __shared__ float s1[4], s2[4];
  int wid = tid >> 6, lane = tid & 63;
  if (lane == 0) { s1[wid] = s; s2[wid] = q; }
  __syncthreads();
  s = s1[0] + s1[1] + s1[2] + s1[3];
  q = s2[0] + s2[1] + s2[2] + s2[3];
  float mu = s * (1.f / 1024.f);
  float var = q * (1.f / 1024.f) - mu * mu;
  float inv = rsqrtf(fmaxf(var, 0.f) + 1e-6f);
  float4 gv = ((const float4*)g)[tid], bv = ((const float4*)be)[tid];
  float o0 = gv.x * (y[0] - mu) * inv + bv.x;
  float o1 = gv.y * (y[1] - mu) * inv + bv.y;
  float o2 = gv.z * (y[2] - mu) * inv + bv.z;
  float o3 = gv.w * (y[3] - mu) * inv + bv.w;
  ((float4*)(out + row * 1024))[tid] = make_float4(o0, o1, o2, o3);
  if (outb != nullptr) {
    uint2 ob;
    ob.x = (uint32_t)f2bf(o0) | ((uint32_t)f2bf(o1) << 16);
    ob.y = (uint32_t)f2bf(o2) | ((uint32_t)f2bf(o3) << 16);
    ((uint2*)(outb + row * 1024))[tid] = ob;
  }
}

extern "C" void kernel_launch(void* const* d_in, const int* in_sizes, int n_in,
                              void* d_out, int out_size, void* d_ws,
                              size_t ws_size, hipStream_t stream) {
  const float* x   = (const float*)d_in[0];
  const float* enc = (const float*)d_in[1];
  const float* wq1 = (const float*)d_in[2];  const float* bq1 = (const float*)d_in[3];
  const float* wk1 = (const float*)d_in[4];  const float* bk1 = (const float*)d_in[5];
  const float* wv1 = (const float*)d_in[6];  const float* bv1 = (const float*)d_in[7];
  const float* wo1 = (const float*)d_in[8];  const float* bo1 = (const float*)d_in[9];
  const float* wq2 = (const float*)d_in[10]; const float* bq2 = (const float*)d_in[11];
  const float* wk2 = (const float*)d_in[12]; const float* bk2 = (const float*)d_in[13];
  const float* wv2 = (const float*)d_in[14]; const float* bv2 = (const float*)d_in[15];
  const float* wo2 = (const float*)d_in[16]; const float* bo2 = (const float*)d_in[17];
  const float* wf1 = (const float*)d_in[18]; const float* bf1 = (const float*)d_in[19];
  const float* wf2 = (const float*)d_in[20]; const float* bf2 = (const float*)d_in[21];
  const float* g1 = (const float*)d_in[22];  const float* be1 = (const float*)d_in[23];
  const float* g2 = (const float*)d_in[24];  const float* be2 = (const float*)d_in[25];
  const float* g3 = (const float*)d_in[26];  const float* be3 = (const float*)d_in[27];
  (void)in_sizes; (void)n_in; (void)out_size; (void)ws_size;

  const size_t S = (size_t)16384 * 1024;  // tokens * d_model
  float* O0 = (float*)d_out;              // out3

  char* base = (char*)d_ws;
  size_t off = 0;
  auto alloc = [&](size_t bytes) -> void* {
    void* p = base + off;
    off += (bytes + 255) & ~(size_t)255;
    return p;
  };
  u16* WT1   = (u16*)alloc((size_t)4096 * 1024 * 2);  // weight^T bf16
  u16* WT2   = (u16*)alloc((size_t)4096 * 1024 * 2);
  float* qb  = (float*)alloc((size_t)16384 * 16 * 4);
  float* kb  = (float*)alloc((size_t)16384 * 16 * 4);
  float* kvp = (float*)alloc((size_t)512 * 64 * 4);
  float* scm = (float*)alloc((size_t)4 * 16 * 64 * 4);
  u16* FA    = (u16*)alloc(S * 2);                    // bf16: v / attn / ffn_out
  u16* XB    = (u16*)alloc(S * 2);                    // bf16: x / enc / out2
  u16* FB    = (u16*)alloc(S * 2);                    // bf16: pre (attn input)
  u16* FM    = (u16*)alloc((size_t)16384 * 4096 * 2); // bf16: ffn mid (134MB)
  float* O1f = (float*)alloc(S * 4);                  // f32 out1
  float* O2f = (float*)alloc(S * 4);                  // f32 out2

  const int T = 16384;
  dim3 blk(256), gblk(512);

  // ---- MHA1 (q=k=v from x) ----
  cvt_f2b<<<16384, blk, 0, stream>>>(x, XB);
  transpose_cvt<<<dim3(32, 32), blk, 0, stream>>>(wv1, WT1, 1024, 1024);
  gemm256<0><<<dim3(4, 64), gblk, 0, stream>>>(XB, WT1, bv1, FA, T, 1024, 1024);
  proj_qk_b<<<1024, blk, 0, stream>>>(XB, wq1, bq1, wk1, bk1, qb, kb);
  kv_part<<<512, blk, 0, stream>>>(kb, FA, kvp);
  kv_finish<<<4, 64, 0, stream>>>(kvp, scm);
  premul<<<8192, blk, 0, stream>>>(qb, scm, FB);
  transpose_cvt<<<dim3(32, 32), blk, 0, stream>>>(wo1, WT1, 1024, 1024);
  gemm256<0><<<dim3(4, 64), gblk, 0, stream>>>(FB, WT1, bo1, FA, T, 1024, 1024);
  ln_res<<<16384, blk, 0, stream>>>(FA, x, g1, be1, O1f, nullptr);  // out1

  // ---- MHA2 (q from out1, k/v from enc) ----
  cvt_f2b<<<16384, blk, 0, stream>>>(enc, XB);
  transpose_cvt<<<dim3(32, 32), blk, 0, stream>>>(wv2, WT1, 1024, 1024);
  gemm256<0><<<dim3(4, 64), gblk, 0, stream>>>(XB, WT1, bv2, FA, T, 1024, 1024);
  proj_f<<<1024, blk, 0, stream>>>(O1f, wq2, bq2, qb);
  proj_b<<<1024, blk, 0, stream>>>(XB, wk2, bk2, kb);
  kv_part<<<512, blk, 0, stream>>>(kb, FA, kvp);
  kv_finish<<<4, 64, 0, stream>>>(kvp, scm);
  premul<<<8192, blk, 0, stream>>>(qb, scm, FB);
  transpose_cvt<<<dim3(32, 32), blk, 0, stream>>>(wo2, WT1, 1024, 1024);
  gemm256<0><<<dim3(4, 64), gblk, 0, stream>>>(FB, WT1, bo2, FA, T, 1024, 1024);
  ln_res<<<16384, blk, 0, stream>>>(FA, O1f, g2, be2, O2f, XB);  // out2 (+bf16)

  // ---- FFN ----
  transpose_cvt<<<dim3(128, 32), blk, 0, stream>>>(wf1, WT1, 1024, 4096);
  transpose_cvt<<<dim3(32, 128), blk, 0, stream>>>(wf2, WT2, 4096, 1024);
  gemm256<1><<<dim3(16, 64), gblk, 0, stream>>>(XB, WT1, bf1, FM, T, 4096, 1024);
  gemm256<0><<<dim3(4, 64), gblk, 0, stream>>>(FM, WT2, bf2, FA, T, 1024, 4096);
  ln_res<<<16384, blk, 0, stream>>>(FA, O2f, g3, be3, O0, nullptr);  // out3

  // outputs 1 and 2 must be zeros
  hipMemsetAsync((float*)d_out + S, 0, 2 * S * 4, stream);
}

// Round 8
// 932.438 us; speedup vs baseline: 1.1269x; 1.1269x over previous
//
#include <hip/hip_runtime.h>
#include <cstdint>

typedef unsigned short u16;
typedef __bf16 bf16x8 __attribute__((ext_vector_type(8)));
typedef float f32x4 __attribute__((ext_vector_type(4)));

__device__ __forceinline__ float bf2f(u16 h) {
  union { uint32_t u; float f; } v; v.u = (uint32_t)h << 16; return v.f;
}
__device__ __forceinline__ u16 f2bf(float f) {
  union { float f; uint32_t u; } v; v.f = f;
  uint32_t r = v.u + 0x7fffu + ((v.u >> 16) & 1u);
  return (u16)(r >> 16);
}
__device__ __forceinline__ float sigmoidf_(float x) {
  return 1.0f / (1.0f + __expf(-x));
}
__device__ __forceinline__ void load_lds16(const void* g, void* l) {
  __builtin_amdgcn_global_load_lds(
      (const __attribute__((address_space(1))) void*)g,
      (__attribute__((address_space(3))) void*)l, 16, 0, 0);
}
#define BAR() __builtin_amdgcn_s_barrier()
#define SB0() __builtin_amdgcn_sched_barrier(0)

// ---------------- flat convert f32 -> bf16 (n multiple of 4) -------------
__global__ __launch_bounds__(256) void cvt_f2b(const float* __restrict__ in,
                                               u16* __restrict__ out) {
  long i = ((long)blockIdx.x * 256 + threadIdx.x) * 4;
  float4 v = *(const float4*)(in + i);
  uint2 o;
  o.x = (uint32_t)f2bf(v.x) | ((uint32_t)f2bf(v.y) << 16);
  o.y = (uint32_t)f2bf(v.z) | ((uint32_t)f2bf(v.w) << 16);
  *((uint2*)(out + i)) = o;
}

// ------------- transpose+convert: in f32 [K][N] -> out bf16 [N][K] -------
__global__ __launch_bounds__(256) void transpose_cvt(
    const float* __restrict__ in, u16* __restrict__ out, int K, int N) {
  __shared__ float t[32][33];
  int n0 = blockIdx.x * 32, k0 = blockIdx.y * 32;
  int tx = threadIdx.x & 31, ty = threadIdx.x >> 5;
#pragma unroll
  for (int i = 0; i < 32; i += 8)
    t[ty + i][tx] = in[(long)(k0 + ty + i) * N + n0 + tx];
  __syncthreads();
#pragma unroll
  for (int i = 0; i < 32; i += 8)
    out[(long)(n0 + ty + i) * K + k0 + tx] = f2bf(t[tx][ty + i]);
}

// ------ fused q,k projection from bf16: [T,1024]@[1024,16]x2 -> f32 ------
__global__ __launch_bounds__(256) void proj_qk_b(
    const u16* __restrict__ xb, const float* __restrict__ wq,
    const float* __restrict__ bq, const float* __restrict__ wk,
    const float* __restrict__ bk, float* __restrict__ qout,
    float* __restrict__ kout) {
  int tid = threadIdx.x;
  long t0 = (long)blockIdx.x * 16;
  int col = tid & 15, tok = tid >> 4;
  const u16* xr = xb + (t0 + tok) * 1024;
  float aq = 0.f, ak = 0.f;
  for (int k = 0; k < 1024; k += 4) {
    uint2 xv = *(const uint2*)(xr + k);
    float x0 = bf2f((u16)(xv.x & 0xffff)), x1 = bf2f((u16)(xv.x >> 16));
    float x2 = bf2f((u16)(xv.y & 0xffff)), x3 = bf2f((u16)(xv.y >> 16));
    aq += x0 * wq[(long)k * 16 + col] + x1 * wq[(long)(k + 1) * 16 + col] +
          x2 * wq[(long)(k + 2) * 16 + col] + x3 * wq[(long)(k + 3) * 16 + col];
    ak += x0 * wk[(long)k * 16 + col] + x1 * wk[(long)(k + 1) * 16 + col] +
          x2 * wk[(long)(k + 2) * 16 + col] + x3 * wk[(long)(k + 3) * 16 + col];
  }
  qout[(t0 + tok) * 16 + col] = aq + bq[col];
  kout[(t0 + tok) * 16 + col] = ak + bk[col];
}

// ------ single projection from bf16 ------
__global__ __launch_bounds__(256) void proj_b(const u16* __restrict__ xb,
                                              const float* __restrict__ w,
                                              const float* __restrict__ b,
                                              float* __restrict__ out) {
  int tid = threadIdx.x;
  long t0 = (long)blockIdx.x * 16;
  int col = tid & 15, tok = tid >> 4;
  const u16* xr = xb + (t0 + tok) * 1024;
  float acc = 0.f;
  for (int k = 0; k < 1024; k += 4) {
    uint2 xv = *(const uint2*)(xr + k);
    acc += bf2f((u16)(xv.x & 0xffff)) * w[(long)k * 16 + col] +
           bf2f((u16)(xv.x >> 16)) * w[(long)(k + 1) * 16 + col] +
           bf2f((u16)(xv.y & 0xffff)) * w[(long)(k + 2) * 16 + col] +
           bf2f((u16)(xv.y >> 16)) * w[(long)(k + 3) * 16 + col];
  }
  out[(t0 + tok) * 16 + col] = acc + b[col];
}

// ------ single projection from f32 ------
__global__ __launch_bounds__(256) void proj_f(const float* __restrict__ in,
                                              const float* __restrict__ w,
                                              const float* __restrict__ b,
                                              float* __restrict__ out) {
  int tid = threadIdx.x;
  long t0 = (long)blockIdx.x * 16;
  int col = tid & 15, tok = tid >> 4;
  const float* xr = in + (t0 + tok) * 1024;
  float acc = 0.f;
  for (int k = 0; k < 1024; k += 4) {
    float4 xv = *(const float4*)(xr + k);
    acc += xv.x * w[(long)k * 16 + col] + xv.y * w[(long)(k + 1) * 16 + col] +
           xv.z * w[(long)(k + 2) * 16 + col] + xv.w * w[(long)(k + 3) * 16 + col];
  }
  out[(t0 + tok) * 16 + col] = acc + b[col];
}

// ===== 256x256 MFMA GEMM, A-prefetch register pipeline =====================
// C[M,N] = act(A[M,K]bf16 @ BT[N,K]^T + bias). M%256==0, N%256==0, K%256==0
// (KT=K/64 even, >=4). 512 thr = 8 waves (2Mx4N). LDS 128KB = 4 slots
// S=[buf][kk] of {16KB A + 16KB B}, st-swizzled (inverse-swizzled global
// source + swizzled ds_read). Register budget (~100 VGPR + 128 AGPR acc,
// no spill): ping-pong A fragments only; B read per-phase.
// Phase t: {LDB bq<-S(t).B; SB0; LDA afNXT<-S(t+1).A; lgkmcnt(8) [= prev
// phase's 8 A-reads + this bq, FIFO-exact thanks to SB0 pinning issue
// order]; MFMA(afCUR,bq) setprio-wrapped; stage S(t)<-ktile+2; vmcnt(8);
// s_barrier}. Landing: vmcnt(8) at end of q => stage(q-2) landed; reads at
// t target slots staged <= t-3. Tail peeled with vm(4)/vm(0)/lgkm(0).
template <int ACT>
__global__ __launch_bounds__(512) void gemm256(
    const u16* __restrict__ A, const u16* __restrict__ BT,
    const float* __restrict__ bias, u16* __restrict__ C, int M, int N,
    int K) {
  __shared__ __attribute__((aligned(16))) u16 lds[65536];  // 128 KB
  const int tid = threadIdx.x;
  const int wid = tid >> 6, lane = tid & 63;
  const int wm = wid >> 2, wn = wid & 3;
  const int lrow = lane & 15, g = lane >> 4;

  int nwg = gridDim.x * gridDim.y;
  int orig = blockIdx.y * gridDim.x + blockIdx.x;
  int wg = (nwg & 7) ? orig : ((orig & 7) * (nwg >> 3) + (orig >> 3));
  const long bn = (long)(wg % gridDim.x) * 256;
  const long bm = (long)(wg / gridDim.x) * 256;

  const int rr = wid * 16 + (lane >> 2);                        // staging row
  const int esrc = ((lane & 3) * 8) ^ (((lane >> 5) & 1) * 16); // src swizzle
  const u16* Abase = A + (bm + rr) * (long)K + esrc;
  const u16* Bbase = BT + (bn + rr) * (long)K + esrc;
  const long jstep = (long)128 * K;
  char* ldsc = (char*)lds;
  const int ldsw = wid * 1024;

  const int swr = ((lrow >> 3) & 1) * 32;
  const int aoff = (wm * 128 + lrow) * 64 + ((g * 16) ^ swr);
  const int boff = 32768 + (wn * 64 + lrow) * 64 + ((g * 16) ^ swr);

  f32x4 acc[8][4] = {};
  const int KT = K >> 6;

  auto stage = [&](int buf, int kk, int kt) {  // 4 x global_load_lds
    const u16* sA = Abase + (long)kt * 64 + kk * 32;
    const u16* sB = Bbase + (long)kt * 64 + kk * 32;
    int dA = buf * 65536 + kk * 16384 + ldsw;
    int dB = dA + 32768;
    load_lds16(sA, ldsc + dA);
    load_lds16(sA + jstep, ldsc + dA + 8192);
    load_lds16(sB, ldsc + dB);
    load_lds16(sB + jstep, ldsc + dB + 8192);
  };

#define LDA(AF, BUF, KK)                                                    \
  {                                                                         \
    const char* _b = ldsc + (BUF) * 65536 + (KK) * 16384;                   \
    _Pragma("unroll") for (int m = 0; m < 8; m++)                           \
        AF[m] = *(const bf16x8*)(_b + aoff + m * 1024);                     \
  }
#define LDB(BQ, BUF, KK)                                                    \
  {                                                                         \
    const char* _b = ldsc + (BUF) * 65536 + (KK) * 16384;                   \
    _Pragma("unroll") for (int n = 0; n < 4; n++)                           \
        BQ[n] = *(const bf16x8*)(_b + boff + n * 1024);                     \
  }
#define MMA(AF, BQ)                                                         \
  __builtin_amdgcn_s_setprio(1);                                            \
  _Pragma("unroll") for (int m = 0; m < 8; m++)                             \
  _Pragma("unroll") for (int n = 0; n < 4; n++)                             \
      acc[m][n] = __builtin_amdgcn_mfma_f32_16x16x32_bf16(AF[m], BQ[n],     \
                                                          acc[m][n], 0, 0,  \
                                                          0);               \
  __builtin_amdgcn_s_setprio(0);
#define WLG8() asm volatile("s_waitcnt lgkmcnt(8)" ::: "memory")
#define WLG0() asm volatile("s_waitcnt lgkmcnt(0)" ::: "memory")
#define WVM8() asm volatile("s_waitcnt vmcnt(8)" ::: "memory")
// phase: consume slot (CB,CK); prefetch A of slot (NB,NK); restage (CB,CK)
#define PHASE(CAF, NAF, CB, CK, NB, NK, SKT)                                \
  LDB(bq, CB, CK);                                                          \
  SB0();                                                                    \
  LDA(NAF, NB, NK);                                                         \
  WLG8();                                                                   \
  SB0();                                                                    \
  MMA(CAF, bq);                                                             \
  stage(CB, CK, SKT);                                                       \
  WVM8();                                                                   \
  BAR();

  bf16x8 afA[8], afB[8], bq[4];

  // prologue: fill 4 slots (ktiles 0,0,1,1); slots 0,1 landed; prefetch afA
  stage(0, 0, 0);
  stage(0, 1, 0);
  stage(1, 0, 1);
  stage(1, 1, 1);
  WVM8();
  BAR();
  LDA(afA, 0, 0);  // 8 LDS reads in flight into afA

  for (int kt = 0; kt + 3 < KT; kt += 2) {
    PHASE(afA, afB, 0, 0, 0, 1, kt + 2);  // ktile kt   kk0
    PHASE(afB, afA, 0, 1, 1, 0, kt + 2);  // ktile kt   kk1
    PHASE(afA, afB, 1, 0, 1, 1, kt + 3);  // ktile kt+1 kk0
    PHASE(afB, afA, 1, 1, 0, 0, kt + 3);  // ktile kt+1 kk1
  }
  // peeled tail: ktiles KT-2 (slots 0,*), KT-1 (slots 1,*); exact drains
  LDB(bq, 0, 0); SB0(); LDA(afB, 0, 1);
  WLG8(); SB0();
  MMA(afA, bq);
  asm volatile("s_waitcnt vmcnt(4)" ::: "memory");
  BAR();
  LDB(bq, 0, 1); SB0(); LDA(afA, 1, 0);
  WLG8(); SB0();
  MMA(afB, bq);
  asm volatile("s_waitcnt vmcnt(0)" ::: "memory");
  BAR();
  LDB(bq, 1, 0); SB0(); LDA(afB, 1, 1);
  WLG8(); SB0();
  MMA(afA, bq);
  BAR();
  LDB(bq, 1, 1);
  WLG0(); SB0();
  MMA(afB, bq);
  BAR();  // all reads done before epilogue overwrites LDS

  // ---- epilogue: bias/act -> LDS (bf16 tile) -> coalesced uint4 stores ----
#pragma unroll
  for (int n = 0; n < 4; n++) {
    int cl = wn * 64 + n * 16 + lrow;
    float bb = bias[bn + cl];
#pragma unroll
    for (int m = 0; m < 8; m++) {
      int rl = wm * 128 + m * 16 + g * 4;
#pragma unroll
      for (int i = 0; i < 4; i++) {
        float v = acc[m][n][i] + bb;
        if (ACT == 1) v = fmaxf(v, 0.f);
        lds[(rl + i) * 256 + cl] = f2bf(v);
      }
    }
  }
  BAR();
  const uint4* lv = (const uint4*)lds;
#pragma unroll
  for (int it = 0; it < 16; it++) {
    int idx = it * 512 + tid;
    int row = idx >> 5;
    int cu = (idx & 31) * 8;
    *(uint4*)&C[(bm + row) * (long)N + bn + cu] = lv[idx];
  }
#undef LDA
#undef LDB
#undef MMA
#undef WLG8
#undef WLG0
#undef WVM8
#undef PHASE
}

// -- kv partial: part[b,h,sc,d] = sum_{s in chunk} sig(k)*v  (v bf16) -----
__global__ __launch_bounds__(256) void kv_part(const float* __restrict__ kp,
                                               const u16* __restrict__ v,
                                               float* __restrict__ part) {
  int bid = blockIdx.x;
  int sc = bid & 7, h = (bid >> 3) & 15, b = bid >> 7;
  int d = threadIdx.x & 63, si = threadIdx.x >> 6;
  float acc = 0.f;
  int s0 = sc * 512;
  for (int s = s0 + si; s < s0 + 512; s += 4) {
    long tok = (long)b * 4096 + s;
    float sk = sigmoidf_(kp[tok * 16 + h]);
    acc += sk * bf2f(v[tok * 1024 + h * 64 + d]);
  }
  __shared__ float red[4][64];
  red[si][d] = acc;
  __syncthreads();
  if (si == 0)
    part[(long)bid * 64 + d] = red[0][d] + red[1][d] + red[2][d] + red[3][d];
}

// ---------------- reduce chunks + cumsum over heads ----------------------
__global__ __launch_bounds__(64) void kv_finish(const float* __restrict__ part,
                                                float* __restrict__ scum) {
  int b = blockIdx.x, d = threadIdx.x;
  float run = 0.f;
  for (int h = 0; h < 16; h++) {
    float s = 0.f;
    for (int sc = 0; sc < 8; sc++)
      s += part[(((long)b * 16 + h) * 8 + sc) * 64 + d];
    run += s;
    scum[((long)b * 16 + h) * 64 + d] = run;
  }
}

// ------- pre[t, h*64+d] = sigmoid(q[t,h]) * scum[b,h,d]  -> bf16 ---------
__global__ __launch_bounds__(256) void premul(const float* __restrict__ qp,
                                              const float* __restrict__ scum,
                                              u16* __restrict__ out) {
  long idx = ((long)blockIdx.x * 256 + threadIdx.x) * 8;
  long tok = idx >> 10;
  int c = (int)(idx & 1023);
  int h = c >> 6, d0 = c & 63;
  int b = (int)(tok >> 12);
  float sq = sigmoidf_(qp[tok * 16 + h]);
  const float* sp = scum + ((long)b * 16 + h) * 64 + d0;
  uint4 o;
  o.x = (uint32_t)f2bf(sq * sp[0]) | ((uint32_t)f2bf(sq * sp[1]) << 16);
  o.y = (uint32_t)f2bf(sq * sp[2]) | ((uint32_t)f2bf(sq * sp[3]) << 16);
  o.z = (uint32_t)f2bf(sq * sp[4]) | ((uint32_t)f2bf(sq * sp[5]) << 16);
  o.w = (uint32_t)f2bf(sq * sp[6]) | ((uint32_t)f2bf(sq * sp[7]) << 16);
  *((uint4*)(out + idx)) = o;
}

// --- out_f32 = LayerNorm(a_bf16 + r_f32)*g + be ; optional bf16 copy -----
__global__ __launch_bounds__(256) void ln_res(const u16* __restrict__ a,
                                              const float* __restrict__ r,
                                              const float* __restrict__ g,
                                              const float* __restrict__ be,
                                              float* __restrict__ out,
                                              u16* __restrict__ outb) {
  long row = blockIdx.x;
  int tid = threadIdx.x;
  uint2 av = ((const uint2*)(a + row * 1024))[tid];
  float4 rv = ((const float4*)(r + row * 1024))[tid];
  float y[4];
  y[0] = bf2f((u16)(av.x & 0xffff)) + rv.x;
  y[1] = bf2f((u16)(av.x >> 16)) + rv.y;
  y[2] = bf2f((u16)(av.y & 0xffff)) + rv.z;
  y[3] = bf2f((u16)(av.y >> 16)) + rv.w;
  float s = y[0] + y[1] + y[2] + y[3];
  float q = y[0] * y[0] + y[1] * y[1] + y[2] * y[2] + y[3] * y[3];
#pragma unroll
  for (int o = 32; o > 0; o >>= 1) {
    s += __shfl_down(s, o);
    q += __shfl_down(q, o);
  }
  __shared__ float s1[4], s2[4];
  int wid = tid >> 6, lane = tid & 63;
  if (lane == 0) { s1[wid] = s; s2[wid] = q; }
  __syncthreads();
  s = s1[0] + s1[1] + s1[2] + s1[3];
  q = s2[0] + s2[1] + s2[2] + s2[3];
  float mu = s * (1.f / 1024.f);
  float var = q * (1.f / 1024.f) - mu * mu;
  float inv = rsqrtf(fmaxf(var, 0.f) + 1e-6f);
  float4 gv = ((const float4*)g)[tid], bv = ((const float4*)be)[tid];
  float o0 = gv.x * (y[0] - mu) * inv + bv.x;
  float o1 = gv.y * (y[1] - mu) * inv + bv.y;
  float o2 = gv.z * (y[2] - mu) * inv + bv.z;
  float o3 = gv.w * (y[3] - mu) * inv + bv.w;
  ((float4*)(out + row * 1024))[tid] = make_float4(o0, o1, o2, o3);
  if (outb != nullptr) {
    uint2 ob;
    ob.x = (uint32_t)f2bf(o0) | ((uint32_t)f2bf(o1) << 16);
    ob.y = (uint32_t)f2bf(o2) | ((uint32_t)f2bf(o3) << 16);
    ((uint2*)(outb + row * 1024))[tid] = ob;
  }
}

extern "C" void kernel_launch(void* const* d_in, const int* in_sizes, int n_in,
                              void* d_out, int out_size, void* d_ws,
                              size_t ws_size, hipStream_t stream) {
  const float* x   = (const float*)d_in[0];
  const float* enc = (const float*)d_in[1];
  const float* wq1 = (const float*)d_in[2];  const float* bq1 = (const float*)d_in[3];
  const float* wk1 = (const float*)d_in[4];  const float* bk1 = (const float*)d_in[5];
  const float* wv1 = (const float*)d_in[6];  const float* bv1 = (const float*)d_in[7];
  const float* wo1 = (const float*)d_in[8];  const float* bo1 = (const float*)d_in[9];
  const float* wq2 = (const float*)d_in[10]; const float* bq2 = (const float*)d_in[11];
  const float* wk2 = (const float*)d_in[12]; const float* bk2 = (const float*)d_in[13];
  const float* wv2 = (const float*)d_in[14]; const float* bv2 = (const float*)d_in[15];
  const float* wo2 = (const float*)d_in[16]; const float* bo2 = (const float*)d_in[17];
  const float* wf1 = (const float*)d_in[18]; const float* bf1 = (const float*)d_in[19];
  const float* wf2 = (const float*)d_in[20]; const float* bf2 = (const float*)d_in[21];
  const float* g1 = (const float*)d_in[22];  const float* be1 = (const float*)d_in[23];
  const float* g2 = (const float*)d_in[24];  const float* be2 = (const float*)d_in[25];
  const float* g3 = (const float*)d_in[26];  const float* be3 = (const float*)d_in[27];
  (void)in_sizes; (void)n_in; (void)out_size; (void)ws_size;

  const size_t S = (size_t)16384 * 1024;  // tokens * d_model
  float* O0 = (float*)d_out;              // out3

  char* base = (char*)d_ws;
  size_t off = 0;
  auto alloc = [&](size_t bytes) -> void* {
    void* p = base + off;
    off += (bytes + 255) & ~(size_t)255;
    return p;
  };
  u16* WT1   = (u16*)alloc((size_t)4096 * 1024 * 2);  // weight^T bf16
  u16* WT2   = (u16*)alloc((size_t)4096 * 1024 * 2);
  float* qb  = (float*)alloc((size_t)16384 * 16 * 4);
  float* kb  = (float*)alloc((size_t)16384 * 16 * 4);
  float* kvp = (float*)alloc((size_t)512 * 64 * 4);
  float* scm = (float*)alloc((size_t)4 * 16 * 64 * 4);
  u16* FA    = (u16*)alloc(S * 2);                    // bf16: v / attn / ffn_out
  u16* XB    = (u16*)alloc(S * 2);                    // bf16: x / enc / out2
  u16* FB    = (u16*)alloc(S * 2);                    // bf16: pre (attn input)
  u16* FM    = (u16*)alloc((size_t)16384 * 4096 * 2); // bf16: ffn mid (134MB)
  float* O1f = (float*)alloc(S * 4);                  // f32 out1
  float* O2f = (float*)alloc(S * 4);                  // f32 out2

  const int T = 16384;
  dim3 blk(256), gblk(512);

  // ---- MHA1 (q=k=v from x) ----
  cvt_f2b<<<16384, blk, 0, stream>>>(x, XB);
  transpose_cvt<<<dim3(32, 32), blk, 0, stream>>>(wv1, WT1, 1024, 1024);
  gemm256<0><<<dim3(4, 64), gblk, 0, stream>>>(XB, WT1, bv1, FA, T, 1024, 1024);
  proj_qk_b<<<1024, blk, 0, stream>>>(XB, wq1, bq1, wk1, bk1, qb, kb);
  kv_part<<<512, blk, 0, stream>>>(kb, FA, kvp);
  kv_finish<<<4, 64, 0, stream>>>(kvp, scm);
  premul<<<8192, blk, 0, stream>>>(qb, scm, FB);
  transpose_cvt<<<dim3(32, 32), blk, 0, stream>>>(wo1, WT1, 1024, 1024);
  gemm256<0><<<dim3(4, 64), gblk, 0, stream>>>(FB, WT1, bo1, FA, T, 1024, 1024);
  ln_res<<<16384, blk, 0, stream>>>(FA, x, g1, be1, O1f, nullptr);  // out1

  // ---- MHA2 (q from out1, k/v from enc) ----
  cvt_f2b<<<16384, blk, 0, stream>>>(enc, XB);
  transpose_cvt<<<dim3(32, 32), blk, 0, stream>>>(wv2, WT1, 1024, 1024);
  gemm256<0><<<dim3(4, 64), gblk, 0, stream>>>(XB, WT1, bv2, FA, T, 1024, 1024);
  proj_f<<<1024, blk, 0, stream>>>(O1f, wq2, bq2, qb);
  proj_b<<<1024, blk, 0, stream>>>(XB, wk2, bk2, kb);
  kv_part<<<512, blk, 0, stream>>>(kb, FA, kvp);
  kv_finish<<<4, 64, 0, stream>>>(kvp, scm);
  premul<<<8192, blk, 0, stream>>>(qb, scm, FB);
  transpose_cvt<<<dim3(32, 32), blk, 0, stream>>>(wo2, WT1, 1024, 1024);
  gemm256<0><<<dim3(4, 64), gblk, 0, stream>>>(FB, WT1, bo2, FA, T, 1024, 1024);
  ln_res<<<16384, blk, 0, stream>>>(FA, O1f, g2, be2, O2f, XB);  // out2 (+bf16)

  // ---- FFN ----
  transpose_cvt<<<dim3(128, 32), blk, 0, stream>>>(wf1, WT1, 1024, 4096);
  transpose_cvt<<<dim3(32, 128), blk, 0, stream>>>(wf2, WT2, 4096, 1024);
  gemm256<1><<<dim3(16, 64), gblk, 0, stream>>>(XB, WT1, bf1, FM, T, 4096, 1024);
  gemm256<0><<<dim3(4, 64), gblk, 0, stream>>>(FM, WT2, bf2, FA, T, 1024, 4096);
  ln_res<<<16384, blk, 0, stream>>>(FA, O2f, g3, be3, O0, nullptr);  // out3

  // outputs 1 and 2 must be zeros
  hipMemsetAsync((float*)d_out + S, 0, 2 * S * 4, stream);
}

// Round 9
// 868.823 us; speedup vs baseline: 1.2094x; 1.0732x over previous
//
#include <hip/hip_runtime.h>
#include <cstdint>

typedef unsigned short u16;
typedef __bf16 bf16x8 __attribute__((ext_vector_type(8)));
typedef float f32x4 __attribute__((ext_vector_type(4)));

__device__ __forceinline__ float bf2f(u16 h) {
  union { uint32_t u; float f; } v; v.u = (uint32_t)h << 16; return v.f;
}
__device__ __forceinline__ u16 f2bf(float f) {
  union { float f; uint32_t u; } v; v.f = f;
  uint32_t r = v.u + 0x7fffu + ((v.u >> 16) & 1u);
  return (u16)(r >> 16);
}
__device__ __forceinline__ float sigmoidf_(float x) {
  return 1.0f / (1.0f + __expf(-x));
}
__device__ __forceinline__ void load_lds16(const void* g, void* l) {
  __builtin_amdgcn_global_load_lds(
      (const __attribute__((address_space(1))) void*)g,
      (__attribute__((address_space(3))) void*)l, 16, 0, 0);
}
#define BAR() __builtin_amdgcn_s_barrier()
#define SB0() __builtin_amdgcn_sched_barrier(0)

// ---------------- flat convert f32 -> bf16 (n multiple of 4) -------------
__global__ __launch_bounds__(256) void cvt_f2b(const float* __restrict__ in,
                                               u16* __restrict__ out) {
  long i = ((long)blockIdx.x * 256 + threadIdx.x) * 4;
  float4 v = *(const float4*)(in + i);
  uint2 o;
  o.x = (uint32_t)f2bf(v.x) | ((uint32_t)f2bf(v.y) << 16);
  o.y = (uint32_t)f2bf(v.z) | ((uint32_t)f2bf(v.w) << 16);
  *((uint2*)(out + i)) = o;
}

// ------------- transpose+convert: in f32 [K][N] -> out bf16 [N][K] -------
__global__ __launch_bounds__(256) void transpose_cvt(
    const float* __restrict__ in, u16* __restrict__ out, int K, int N) {
  __shared__ float t[32][33];
  int n0 = blockIdx.x * 32, k0 = blockIdx.y * 32;
  int tx = threadIdx.x & 31, ty = threadIdx.x >> 5;
#pragma unroll
  for (int i = 0; i < 32; i += 8)
    t[ty + i][tx] = in[(long)(k0 + ty + i) * N + n0 + tx];
  __syncthreads();
#pragma unroll
  for (int i = 0; i < 32; i += 8)
    out[(long)(n0 + ty + i) * K + k0 + tx] = f2bf(t[tx][ty + i]);
}

// ------ fused q,k projection from bf16: [T,1024]@[1024,16]x2 -> f32 ------
__global__ __launch_bounds__(256) void proj_qk_b(
    const u16* __restrict__ xb, const float* __restrict__ wq,
    const float* __restrict__ bq, const float* __restrict__ wk,
    const float* __restrict__ bk, float* __restrict__ qout,
    float* __restrict__ kout) {
  int tid = threadIdx.x;
  long t0 = (long)blockIdx.x * 16;
  int col = tid & 15, tok = tid >> 4;
  const u16* xr = xb + (t0 + tok) * 1024;
  float aq = 0.f, ak = 0.f;
  for (int k = 0; k < 1024; k += 4) {
    uint2 xv = *(const uint2*)(xr + k);
    float x0 = bf2f((u16)(xv.x & 0xffff)), x1 = bf2f((u16)(xv.x >> 16));
    float x2 = bf2f((u16)(xv.y & 0xffff)), x3 = bf2f((u16)(xv.y >> 16));
    aq += x0 * wq[(long)k * 16 + col] + x1 * wq[(long)(k + 1) * 16 + col] +
          x2 * wq[(long)(k + 2) * 16 + col] + x3 * wq[(long)(k + 3) * 16 + col];
    ak += x0 * wk[(long)k * 16 + col] + x1 * wk[(long)(k + 1) * 16 + col] +
          x2 * wk[(long)(k + 2) * 16 + col] + x3 * wk[(long)(k + 3) * 16 + col];
  }
  qout[(t0 + tok) * 16 + col] = aq + bq[col];
  kout[(t0 + tok) * 16 + col] = ak + bk[col];
}

// ------ single projection from bf16 ------
__global__ __launch_bounds__(256) void proj_b(const u16* __restrict__ xb,
                                              const float* __restrict__ w,
                                              const float* __restrict__ b,
                                              float* __restrict__ out) {
  int tid = threadIdx.x;
  long t0 = (long)blockIdx.x * 16;
  int col = tid & 15, tok = tid >> 4;
  const u16* xr = xb + (t0 + tok) * 1024;
  float acc = 0.f;
  for (int k = 0; k < 1024; k += 4) {
    uint2 xv = *(const uint2*)(xr + k);
    acc += bf2f((u16)(xv.x & 0xffff)) * w[(long)k * 16 + col] +
           bf2f((u16)(xv.x >> 16)) * w[(long)(k + 1) * 16 + col] +
           bf2f((u16)(xv.y & 0xffff)) * w[(long)(k + 2) * 16 + col] +
           bf2f((u16)(xv.y >> 16)) * w[(long)(k + 3) * 16 + col];
  }
  out[(t0 + tok) * 16 + col] = acc + b[col];
}

// ===== 256x256 MFMA GEMM, r6 structure + 3-slot-ahead vmcnt(12) ============
// C[M,N] = act(A[M,K]bf16 @ BT[N,K]^T + bias). M%256==0, N%256==0, K%256==0
// (KT=K/64 even, >=4). 512 thr = 8 waves (2Mx4N). LDS 128KB = 4 slots
// S=[buf][kk] of {16KB A + 16KB B}, st-swizzled (inverse-swizzled global
// source + swizzled ds_read). Phase: {12 ds_read (af0-3,bq,af4-7; SB0-pinned
// order); stage same slot w/ ktile+2; vmcnt(12) [3 slots in flight, m201's
// depth]; s_barrier; lgkm(4); MMA m0-3; lgkm(0); MMA m4-7; s_barrier}.
// Each phase's vmcnt(12) lands exactly the next phase's slot (staged 3
// phases = ~9k cyc earlier). Prologue: 4 stages, vmcnt(12) -> slot0 landed.
// Tail: 4 peeled phases, vm(8)/vm(4)/vm(0)/none.
template <int ACT>
__global__ __launch_bounds__(512) void gemm256(
    const u16* __restrict__ A, const u16* __restrict__ BT,
    const float* __restrict__ bias, u16* __restrict__ C, int M, int N,
    int K) {
  __shared__ __attribute__((aligned(16))) u16 lds[65536];  // 128 KB
  const int tid = threadIdx.x;
  const int wid = tid >> 6, lane = tid & 63;
  const int wm = wid >> 2, wn = wid & 3;
  const int lrow = lane & 15, g = lane >> 4;

  int nwg = gridDim.x * gridDim.y;
  int orig = blockIdx.y * gridDim.x + blockIdx.x;
  int wg = (nwg & 7) ? orig : ((orig & 7) * (nwg >> 3) + (orig >> 3));
  const long bn = (long)(wg % gridDim.x) * 256;
  const long bm = (long)(wg / gridDim.x) * 256;

  const int rr = wid * 16 + (lane >> 2);                        // staging row
  const int esrc = ((lane & 3) * 8) ^ (((lane >> 5) & 1) * 16); // src swizzle
  const u16* Abase = A + (bm + rr) * (long)K + esrc;
  const u16* Bbase = BT + (bn + rr) * (long)K + esrc;
  const long jstep = (long)128 * K;
  char* ldsc = (char*)lds;
  const int ldsw = wid * 1024;

  const int swr = ((lrow >> 3) & 1) * 32;
  const int aoff = (wm * 128 + lrow) * 64 + ((g * 16) ^ swr);
  const int boff = 32768 + (wn * 64 + lrow) * 64 + ((g * 16) ^ swr);

  f32x4 acc[8][4] = {};
  const int KT = K >> 6;

  auto stage = [&](int buf, int kk, int kt) {  // 4 x global_load_lds
    const u16* sA = Abase + (long)kt * 64 + kk * 32;
    const u16* sB = Bbase + (long)kt * 64 + kk * 32;
    int dA = buf * 65536 + kk * 16384 + ldsw;
    int dB = dA + 32768;
    load_lds16(sA, ldsc + dA);
    load_lds16(sA + jstep, ldsc + dA + 8192);
    load_lds16(sB, ldsc + dB);
    load_lds16(sB + jstep, ldsc + dB + 8192);
  };

  // reads ordered: af0-3, bq0-3 (first 8) | af4-7 (last 4); SB0 pins FIFO
#define LDAB(AF, BQ, BUF, KK)                                               \
  {                                                                         \
    const char* _b = ldsc + (BUF) * 65536 + (KK) * 16384;                   \
    _Pragma("unroll") for (int m = 0; m < 4; m++)                           \
        AF[m] = *(const bf16x8*)(_b + aoff + m * 1024);                     \
    _Pragma("unroll") for (int n = 0; n < 4; n++)                           \
        BQ[n] = *(const bf16x8*)(_b + boff + n * 1024);                     \
    SB0();                                                                  \
    _Pragma("unroll") for (int m = 4; m < 8; m++)                           \
        AF[m] = *(const bf16x8*)(_b + aoff + m * 1024);                     \
    SB0();                                                                  \
  }
#define MMAH(AF, BQ, M0)                                                    \
  __builtin_amdgcn_s_setprio(1);                                            \
  _Pragma("unroll") for (int m = M0; m < M0 + 4; m++)                       \
  _Pragma("unroll") for (int n = 0; n < 4; n++)                             \
      acc[m][n] = __builtin_amdgcn_mfma_f32_16x16x32_bf16(AF[m], BQ[n],     \
                                                          acc[m][n], 0, 0,  \
                                                          0);               \
  __builtin_amdgcn_s_setprio(0);
#define WLG4() asm volatile("s_waitcnt lgkmcnt(4)" ::: "memory")
#define WLG0() asm volatile("s_waitcnt lgkmcnt(0)" ::: "memory")
#define WVM12() asm volatile("s_waitcnt vmcnt(12)" ::: "memory")
#define PHASE(CB, CK, SKT)                                                  \
  LDAB(af, bq, CB, CK);                                                     \
  stage(CB, CK, SKT);                                                       \
  WVM12();                                                                  \
  BAR();                                                                    \
  WLG4();                                                                   \
  SB0();                                                                    \
  MMAH(af, bq, 0);                                                          \
  WLG0();                                                                   \
  SB0();                                                                    \
  MMAH(af, bq, 4);                                                          \
  BAR();
#define TAILPH(CB, CK, VMW)                                                 \
  LDAB(af, bq, CB, CK);                                                     \
  VMW;                                                                      \
  BAR();                                                                    \
  WLG4();                                                                   \
  SB0();                                                                    \
  MMAH(af, bq, 0);                                                          \
  WLG0();                                                                   \
  SB0();                                                                    \
  MMAH(af, bq, 4);                                                          \
  BAR();

  bf16x8 af[8], bq[4];

  // prologue: fill all 4 slots (ktiles 0,0,1,1); slot (0,0) landed
  stage(0, 0, 0);
  stage(0, 1, 0);
  stage(1, 0, 1);
  stage(1, 1, 1);
  WVM12();
  BAR();

  for (int kt = 0; kt + 3 < KT; kt += 2) {
    PHASE(0, 0, kt + 2);  // ktile kt   kk0
    PHASE(0, 1, kt + 2);  // ktile kt   kk1
    PHASE(1, 0, kt + 3);  // ktile kt+1 kk0
    PHASE(1, 1, kt + 3);  // ktile kt+1 kk1
  }
  // peeled tail: ktiles KT-2 (slots 0,*), KT-1 (slots 1,*); exact drains
  TAILPH(0, 0, asm volatile("s_waitcnt vmcnt(8)" ::: "memory"));
  TAILPH(0, 1, asm volatile("s_waitcnt vmcnt(4)" ::: "memory"));
  TAILPH(1, 0, asm volatile("s_waitcnt vmcnt(0)" ::: "memory"));
  TAILPH(1, 1, );

  // ---- epilogue: bias/act -> LDS (bf16 tile) -> coalesced uint4 stores ----
#pragma unroll
  for (int n = 0; n < 4; n++) {
    int cl = wn * 64 + n * 16 + lrow;
    float bb = bias[bn + cl];
#pragma unroll
    for (int m = 0; m < 8; m++) {
      int rl = wm * 128 + m * 16 + g * 4;
#pragma unroll
      for (int i = 0; i < 4; i++) {
        float v = acc[m][n][i] + bb;
        if (ACT == 1) v = fmaxf(v, 0.f);
        lds[(rl + i) * 256 + cl] = f2bf(v);
      }
    }
  }
  BAR();
  const uint4* lv = (const uint4*)lds;
#pragma unroll
  for (int it = 0; it < 16; it++) {
    int idx = it * 512 + tid;
    int row = idx >> 5;
    int cu = (idx & 31) * 8;
    *(uint4*)&C[(bm + row) * (long)N + bn + cu] = lv[idx];
  }
#undef LDAB
#undef MMAH
#undef WLG4
#undef WLG0
#undef WVM12
#undef PHASE
#undef TAILPH
}

// -- kv partial: part[b,h,sc,d] = sum_{s in chunk} sig(k)*v  (v bf16) -----
__global__ __launch_bounds__(256) void kv_part(const float* __restrict__ kp,
                                               const u16* __restrict__ v,
                                               float* __restrict__ part) {
  int bid = blockIdx.x;
  int sc = bid & 7, h = (bid >> 3) & 15, b = bid >> 7;
  int d = threadIdx.x & 63, si = threadIdx.x >> 6;
  float acc = 0.f;
  int s0 = sc * 512;
  for (int s = s0 + si; s < s0 + 512; s += 4) {
    long tok = (long)b * 4096 + s;
    float sk = sigmoidf_(kp[tok * 16 + h]);
    acc += sk * bf2f(v[tok * 1024 + h * 64 + d]);
  }
  __shared__ float red[4][64];
  red[si][d] = acc;
  __syncthreads();
  if (si == 0)
    part[(long)bid * 64 + d] = red[0][d] + red[1][d] + red[2][d] + red[3][d];
}

// ---------------- reduce chunks + cumsum over heads ----------------------
__global__ __launch_bounds__(64) void kv_finish(const float* __restrict__ part,
                                                float* __restrict__ scum) {
  int b = blockIdx.x, d = threadIdx.x;
  float run = 0.f;
  for (int h = 0; h < 16; h++) {
    float s = 0.f;
    for (int sc = 0; sc < 8; sc++)
      s += part[(((long)b * 16 + h) * 8 + sc) * 64 + d];
    run += s;
    scum[((long)b * 16 + h) * 64 + d] = run;
  }
}

// ------- pre[t, h*64+d] = sigmoid(q[t,h]) * scum[b,h,d]  -> bf16 ---------
__global__ __launch_bounds__(256) void premul(const float* __restrict__ qp,
                                              const float* __restrict__ scum,
                                              u16* __restrict__ out) {
  long idx = ((long)blockIdx.x * 256 + threadIdx.x) * 8;
  long tok = idx >> 10;
  int c = (int)(idx & 1023);
  int h = c >> 6, d0 = c & 63;
  int b = (int)(tok >> 12);
  float sq = sigmoidf_(qp[tok * 16 + h]);
  const float* sp = scum + ((long)b * 16 + h) * 64 + d0;
  uint4 o;
  o.x = (uint32_t)f2bf(sq * sp[0]) | ((uint32_t)f2bf(sq * sp[1]) << 16);
  o.y = (uint32_t)f2bf(sq * sp[2]) | ((uint32_t)f2bf(sq * sp[3]) << 16);
  o.z = (uint32_t)f2bf(sq * sp[4]) | ((uint32_t)f2bf(sq * sp[5]) << 16);
  o.w = (uint32_t)f2bf(sq * sp[6]) | ((uint32_t)f2bf(sq * sp[7]) << 16);
  *((uint4*)(out + idx)) = o;
}

// --- LayerNorm(a_bf16 + r)*g + be ; RF32: residual f32/bf16; OF32: out ----
template <int RF32, int OF32>
__global__ __launch_bounds__(256) void ln_res(const u16* __restrict__ a,
                                              const void* __restrict__ r_,
                                              const float* __restrict__ g,
                                              const float* __restrict__ be,
                                              void* __restrict__ out_) {
  long row = blockIdx.x;
  int tid = threadIdx.x;
  uint2 av = ((const uint2*)(a + row * 1024))[tid];
  float y[4];
  if (RF32) {
    float4 rv = ((const float4*)((const float*)r_ + row * 1024))[tid];
    y[0] = bf2f((u16)(av.x & 0xffff)) + rv.x;
    y[1] = bf2f((u16)(av.x >> 16)) + rv.y;
    y[2] = bf2f((u16)(av.y & 0xffff)) + rv.z;
    y[3] = bf2f((u16)(av.y >> 16)) + rv.w;
  } else {
    uint2 rv = ((const uint2*)((const u16*)r_ + row * 1024))[tid];
    y[0] = bf2f((u16)(av.x & 0xffff)) + bf2f((u16)(rv.x & 0xffff));
    y[1] = bf2f((u16)(av.x >> 16)) + bf2f((u16)(rv.x >> 16));
    y[2] = bf2f((u16)(av.y & 0xffff)) + bf2f((u16)(rv.y & 0xffff));
    y[3] = bf2f((u16)(av.y >> 16)) + bf2f((u16)(rv.y >> 16));
  }
  float s = y[0] + y[1] + y[2] + y[3];
  float q = y[0] * y[0] + y[1] * y[1] + y[2] * y[2] + y[3] * y[3];
#pragma unroll
  for (int o = 32; o > 0; o >>= 1) {
    s += __shfl_down(s, o);
    q += __shfl_down(q, o);
  }
  __shared__ float s1[4], s2[4];
  int wid = tid >> 6, lane = tid & 63;
  if (lane == 0) { s1[wid] = s; s2[wid] = q; }
  __syncthreads();
  s = s1[0] + s1[1] + s1[2] + s1[3];
  q = s2[0] + s2[1] + s2[2] + s2[3];
  float mu = s * (1.f / 1024.f);
  float var = q * (1.f / 1024.f) - mu * mu;
  float inv = rsqrtf(fmaxf(var, 0.f) + 1e-6f);
  float4 gv = ((const float4*)g)[tid], bv = ((const float4*)be)[tid];
  float o0 = gv.x * (y[0] - mu) * inv + bv.x;
  float o1 = gv.y * (y[1] - mu) * inv + bv.y;
  float o2 = gv.z * (y[2] - mu) * inv + bv.z;
  float o3 = gv.w * (y[3] - mu) * inv + bv.w;
  if (OF32) {
    ((float4*)((float*)out_ + row * 1024))[tid] = make_float4(o0, o1, o2, o3);
  } else {
    uint2 ob;
    ob.x = (uint32_t)f2bf(o0) | ((uint32_t)f2bf(o1) << 16);
    ob.y = (uint32_t)f2bf(o2) | ((uint32_t)f2bf(o3) << 16);
    ((uint2*)((u16*)out_ + row * 1024))[tid] = ob;
  }
}

extern "C" void kernel_launch(void* const* d_in, const int* in_sizes, int n_in,
                              void* d_out, int out_size, void* d_ws,
                              size_t ws_size, hipStream_t stream) {
  const float* x   = (const float*)d_in[0];
  const float* enc = (const float*)d_in[1];
  const float* wq1 = (const float*)d_in[2];  const float* bq1 = (const float*)d_in[3];
  const float* wk1 = (const float*)d_in[4];  const float* bk1 = (const float*)d_in[5];
  const float* wv1 = (const float*)d_in[6];  const float* bv1 = (const float*)d_in[7];
  const float* wo1 = (const float*)d_in[8];  const float* bo1 = (const float*)d_in[9];
  const float* wq2 = (const float*)d_in[10]; const float* bq2 = (const float*)d_in[11];
  const float* wk2 = (const float*)d_in[12]; const float* bk2 = (const float*)d_in[13];
  const float* wv2 = (const float*)d_in[14]; const float* bv2 = (const float*)d_in[15];
  const float* wo2 = (const float*)d_in[16]; const float* bo2 = (const float*)d_in[17];
  const float* wf1 = (const float*)d_in[18]; const float* bf1 = (const float*)d_in[19];
  const float* wf2 = (const float*)d_in[20]; const float* bf2 = (const float*)d_in[21];
  const float* g1 = (const float*)d_in[22];  const float* be1 = (const float*)d_in[23];
  const float* g2 = (const float*)d_in[24];  const float* be2 = (const float*)d_in[25];
  const float* g3 = (const float*)d_in[26];  const float* be3 = (const float*)d_in[27];
  (void)in_sizes; (void)n_in; (void)out_size; (void)ws_size;

  const size_t S = (size_t)16384 * 1024;  // tokens * d_model
  float* O0 = (float*)d_out;              // out3 (f32)

  char* base = (char*)d_ws;
  size_t off = 0;
  auto alloc = [&](size_t bytes) -> void* {
    void* p = base + off;
    off += (bytes + 255) & ~(size_t)255;
    return p;
  };
  u16* WT1   = (u16*)alloc((size_t)4096 * 1024 * 2);  // weight^T bf16
  u16* WT2   = (u16*)alloc((size_t)4096 * 1024 * 2);
  float* qb  = (float*)alloc((size_t)16384 * 16 * 4);
  float* kb  = (float*)alloc((size_t)16384 * 16 * 4);
  float* kvp = (float*)alloc((size_t)512 * 64 * 4);
  float* scm = (float*)alloc((size_t)4 * 16 * 64 * 4);
  u16* FA    = (u16*)alloc(S * 2);                    // bf16: v / attn / ffn_out
  u16* XB    = (u16*)alloc(S * 2);                    // bf16: x / enc
  u16* FB    = (u16*)alloc(S * 2);                    // bf16: pre (attn input)
  u16* FM    = (u16*)alloc((size_t)16384 * 4096 * 2); // bf16: ffn mid (134MB)
  u16* O1b   = (u16*)alloc(S * 2);                    // bf16 out1
  u16* O2b   = (u16*)alloc(S * 2);                    // bf16 out2

  const int T = 16384;
  dim3 blk(256), gblk(512);

  // ---- MHA1 (q=k=v from x) ----
  cvt_f2b<<<16384, blk, 0, stream>>>(x, XB);
  transpose_cvt<<<dim3(32, 32), blk, 0, stream>>>(wv1, WT1, 1024, 1024);
  gemm256<0><<<dim3(4, 64), gblk, 0, stream>>>(XB, WT1, bv1, FA, T, 1024, 1024);
  proj_qk_b<<<1024, blk, 0, stream>>>(XB, wq1, bq1, wk1, bk1, qb, kb);
  kv_part<<<512, blk, 0, stream>>>(kb, FA, kvp);
  kv_finish<<<4, 64, 0, stream>>>(kvp, scm);
  premul<<<8192, blk, 0, stream>>>(qb, scm, FB);
  transpose_cvt<<<dim3(32, 32), blk, 0, stream>>>(wo1, WT1, 1024, 1024);
  gemm256<0><<<dim3(4, 64), gblk, 0, stream>>>(FB, WT1, bo1, FA, T, 1024, 1024);
  ln_res<1, 0><<<16384, blk, 0, stream>>>(FA, x, g1, be1, O1b);  // out1 bf16

  // ---- MHA2 (q from out1, k/v from enc) ----
  cvt_f2b<<<16384, blk, 0, stream>>>(enc, XB);
  transpose_cvt<<<dim3(32, 32), blk, 0, stream>>>(wv2, WT1, 1024, 1024);
  gemm256<0><<<dim3(4, 64), gblk, 0, stream>>>(XB, WT1, bv2, FA, T, 1024, 1024);
  proj_b<<<1024, blk, 0, stream>>>(O1b, wq2, bq2, qb);
  proj_b<<<1024, blk, 0, stream>>>(XB, wk2, bk2, kb);
  kv_part<<<512, blk, 0, stream>>>(kb, FA, kvp);
  kv_finish<<<4, 64, 0, stream>>>(kvp, scm);
  premul<<<8192, blk, 0, stream>>>(qb, scm, FB);
  transpose_cvt<<<dim3(32, 32), blk, 0, stream>>>(wo2, WT1, 1024, 1024);
  gemm256<0><<<dim3(4, 64), gblk, 0, stream>>>(FB, WT1, bo2, FA, T, 1024, 1024);
  ln_res<0, 0><<<16384, blk, 0, stream>>>(FA, O1b, g2, be2, O2b);  // out2 bf16

  // ---- FFN ----
  transpose_cvt<<<dim3(128, 32), blk, 0, stream>>>(wf1, WT1, 1024, 4096);
  transpose_cvt<<<dim3(32, 128), blk, 0, stream>>>(wf2, WT2, 4096, 1024);
  gemm256<1><<<dim3(16, 64), gblk, 0, stream>>>(O2b, WT1, bf1, FM, T, 4096, 1024);
  gemm256<0><<<dim3(4, 64), gblk, 0, stream>>>(FM, WT2, bf2, FA, T, 1024, 4096);
  ln_res<0, 1><<<16384, blk, 0, stream>>>(FA, O2b, g3, be3, O0);  // out3 f32

  // outputs 1 and 2 must be zeros
  hipMemsetAsync((float*)d_out + S, 0, 2 * S * 4, stream);
}

// Round 10
// 750.733 us; speedup vs baseline: 1.3997x; 1.1573x over previous
//
#include <hip/hip_runtime.h>
#include <cstdint>

typedef unsigned short u16;
typedef __bf16 bf16x8 __attribute__((ext_vector_type(8)));
typedef float f32x4 __attribute__((ext_vector_type(4)));

__device__ __forceinline__ float bf2f(u16 h) {
  union { uint32_t u; float f; } v; v.u = (uint32_t)h << 16; return v.f;
}
__device__ __forceinline__ u16 f2bf(float f) {
  union { float f; uint32_t u; } v; v.f = f;
  uint32_t r = v.u + 0x7fffu + ((v.u >> 16) & 1u);
  return (u16)(r >> 16);
}
__device__ __forceinline__ float sigmoidf_(float x) {
  return 1.0f / (1.0f + __expf(-x));
}
__device__ __forceinline__ void load_lds16(const void* g, void* l) {
  __builtin_amdgcn_global_load_lds(
      (const __attribute__((address_space(1))) void*)g,
      (__attribute__((address_space(3))) void*)l, 16, 0, 0);
}
#define BAR() __builtin_amdgcn_s_barrier()
#define SB0() __builtin_amdgcn_sched_barrier(0)

// ---------------- flat convert f32 -> bf16 (n multiple of 4) -------------
__global__ __launch_bounds__(256) void cvt_f2b(const float* __restrict__ in,
                                               u16* __restrict__ out) {
  long i = ((long)blockIdx.x * 256 + threadIdx.x) * 4;
  float4 v = *(const float4*)(in + i);
  uint2 o;
  o.x = (uint32_t)f2bf(v.x) | ((uint32_t)f2bf(v.y) << 16);
  o.y = (uint32_t)f2bf(v.z) | ((uint32_t)f2bf(v.w) << 16);
  *((uint2*)(out + i)) = o;
}

// ------------- transpose+convert: in f32 [K][N] -> out bf16 [N][K] -------
__global__ __launch_bounds__(256) void transpose_cvt(
    const float* __restrict__ in, u16* __restrict__ out, int K, int N) {
  __shared__ float t[32][33];
  int n0 = blockIdx.x * 32, k0 = blockIdx.y * 32;
  int tx = threadIdx.x & 31, ty = threadIdx.x >> 5;
#pragma unroll
  for (int i = 0; i < 32; i += 8)
    t[ty + i][tx] = in[(long)(k0 + ty + i) * N + n0 + tx];
  __syncthreads();
#pragma unroll
  for (int i = 0; i < 32; i += 8)
    out[(long)(n0 + ty + i) * K + k0 + tx] = f2bf(t[tx][ty + i]);
}

// ===== MFMA projection: q = xq@wq+bq, k = xk@wk+bk ; [T,1024]->[T,16]x2 ===
// Block 256 thr (4 waves), 16 tokens/block, grid T/16. Wave wv covers
// k-slice [wv*256, +256) via 8 x 16x16x32 MFMA per matrix. wq/wk staged in
// LDS transposed [col][k] bf16 with ((col&7)<<4) XOR swizzle (8 lanes per
// 16B slot = b128 minimum, conflict-free). A-frag read from global x rows
// (same fragment pattern as gemm256). Cross-wave k-reduce through LDS.
__global__ __launch_bounds__(256) void proj_mfma(
    const u16* __restrict__ xq, const u16* __restrict__ xk,
    const float* __restrict__ wq, const float* __restrict__ bq,
    const float* __restrict__ wk, const float* __restrict__ bk,
    float* __restrict__ qout, float* __restrict__ kout) {
  __shared__ __attribute__((aligned(16))) u16 wt[2][16384];  // 64KB
  __shared__ __attribute__((aligned(16))) float red[4][64][8];
  const int tid = threadIdx.x;
  // ---- stage weights (transpose + cvt): thread t handles k = kq*256+t ----
  for (int kq = 0; kq < 4; kq++) {
    int k = kq * 256 + tid;
    const float4* q4 = (const float4*)(wq + (long)k * 16);
    const float4* k4 = (const float4*)(wk + (long)k * 16);
#pragma unroll
    for (int p = 0; p < 4; p++) {
      float4 qv = q4[p], kv = k4[p];
      float qf[4] = {qv.x, qv.y, qv.z, qv.w};
      float kf[4] = {kv.x, kv.y, kv.z, kv.w};
#pragma unroll
      for (int j = 0; j < 4; j++) {
        int c = p * 4 + j;
        int off = (c * 2048 + k * 2) ^ ((c & 7) << 4);
        *(u16*)((char*)wt[0] + off) = f2bf(qf[j]);
        *(u16*)((char*)wt[1] + off) = f2bf(kf[j]);
      }
    }
  }
  __syncthreads();
  const int wv = tid >> 6, lane = tid & 63;
  const int lrow = lane & 15, g = lane >> 4;
  const long tok0 = (long)blockIdx.x * 16;
  const u16* xqp = xq + (tok0 + lrow) * 1024 + wv * 256 + g * 8;
  const u16* xkp = xk + (tok0 + lrow) * 1024 + wv * 256 + g * 8;
  const int swz = (lrow & 7) << 4;
  const int wbase = lrow * 2048 + wv * 512 + g * 16;
  f32x4 accq = {}, acck = {};
#pragma unroll
  for (int mf = 0; mf < 8; mf++) {
    bf16x8 aq_ = *(const bf16x8*)(xqp + mf * 32);
    bf16x8 ak_ = *(const bf16x8*)(xkp + mf * 32);
    int off = (wbase + mf * 64) ^ swz;
    bf16x8 bq_ = *(const bf16x8*)((const char*)wt[0] + off);
    bf16x8 bk_ = *(const bf16x8*)((const char*)wt[1] + off);
    accq = __builtin_amdgcn_mfma_f32_16x16x32_bf16(aq_, bq_, accq, 0, 0, 0);
    acck = __builtin_amdgcn_mfma_f32_16x16x32_bf16(ak_, bk_, acck, 0, 0, 0);
  }
  *(f32x4*)&red[wv][lane][0] = accq;
  *(f32x4*)&red[wv][lane][4] = acck;
  __syncthreads();
  if (tid < 64) {
    f32x4 q0 = *(const f32x4*)&red[0][tid][0];
    f32x4 k0 = *(const f32x4*)&red[0][tid][4];
#pragma unroll
    for (int w = 1; w < 4; w++) {
      q0 += *(const f32x4*)&red[w][tid][0];
      k0 += *(const f32x4*)&red[w][tid][4];
    }
    int col = tid & 15, r0 = (tid >> 4) * 4;
    float bqv = bq[col], bkv = bk[col];
#pragma unroll
    for (int i = 0; i < 4; i++) {
      qout[(tok0 + r0 + i) * 16 + col] = q0[i] + bqv;
      kout[(tok0 + r0 + i) * 16 + col] = k0[i] + bkv;
    }
  }
}

// ===== 256x256 MFMA GEMM, r9 structure (3-slot-ahead vmcnt(12)) ============
template <int ACT>
__global__ __launch_bounds__(512) void gemm256(
    const u16* __restrict__ A, const u16* __restrict__ BT,
    const float* __restrict__ bias, u16* __restrict__ C, int M, int N,
    int K) {
  __shared__ __attribute__((aligned(16))) u16 lds[65536];  // 128 KB
  const int tid = threadIdx.x;
  const int wid = tid >> 6, lane = tid & 63;
  const int wm = wid >> 2, wn = wid & 3;
  const int lrow = lane & 15, g = lane >> 4;

  int nwg = gridDim.x * gridDim.y;
  int orig = blockIdx.y * gridDim.x + blockIdx.x;
  int wg = (nwg & 7) ? orig : ((orig & 7) * (nwg >> 3) + (orig >> 3));
  const long bn = (long)(wg % gridDim.x) * 256;
  const long bm = (long)(wg / gridDim.x) * 256;

  const int rr = wid * 16 + (lane >> 2);                        // staging row
  const int esrc = ((lane & 3) * 8) ^ (((lane >> 5) & 1) * 16); // src swizzle
  const u16* Abase = A + (bm + rr) * (long)K + esrc;
  const u16* Bbase = BT + (bn + rr) * (long)K + esrc;
  const long jstep = (long)128 * K;
  char* ldsc = (char*)lds;
  const int ldsw = wid * 1024;

  const int swr = ((lrow >> 3) & 1) * 32;
  const int aoff = (wm * 128 + lrow) * 64 + ((g * 16) ^ swr);
  const int boff = 32768 + (wn * 64 + lrow) * 64 + ((g * 16) ^ swr);

  f32x4 acc[8][4] = {};
  const int KT = K >> 6;

  auto stage = [&](int buf, int kk, int kt) {  // 4 x global_load_lds
    const u16* sA = Abase + (long)kt * 64 + kk * 32;
    const u16* sB = Bbase + (long)kt * 64 + kk * 32;
    int dA = buf * 65536 + kk * 16384 + ldsw;
    int dB = dA + 32768;
    load_lds16(sA, ldsc + dA);
    load_lds16(sA + jstep, ldsc + dA + 8192);
    load_lds16(sB, ldsc + dB);
    load_lds16(sB + jstep, ldsc + dB + 8192);
  };

#define LDAB(AF, BQ, BUF, KK)                                               \
  {                                                                         \
    const char* _b = ldsc + (BUF) * 65536 + (KK) * 16384;                   \
    _Pragma("unroll") for (int m = 0; m < 4; m++)                           \
        AF[m] = *(const bf16x8*)(_b + aoff + m * 1024);                     \
    _Pragma("unroll") for (int n = 0; n < 4; n++)                           \
        BQ[n] = *(const bf16x8*)(_b + boff + n * 1024);                     \
    SB0();                                                                  \
    _Pragma("unroll") for (int m = 4; m < 8; m++)                           \
        AF[m] = *(const bf16x8*)(_b + aoff + m * 1024);                     \
    SB0();                                                                  \
  }
#define MMAH(AF, BQ, M0)                                                    \
  __builtin_amdgcn_s_setprio(1);                                            \
  _Pragma("unroll") for (int m = M0; m < M0 + 4; m++)                       \
  _Pragma("unroll") for (int n = 0; n < 4; n++)                             \
      acc[m][n] = __builtin_amdgcn_mfma_f32_16x16x32_bf16(AF[m], BQ[n],     \
                                                          acc[m][n], 0, 0,  \
                                                          0);               \
  __builtin_amdgcn_s_setprio(0);
#define WLG4() asm volatile("s_waitcnt lgkmcnt(4)" ::: "memory")
#define WLG0() asm volatile("s_waitcnt lgkmcnt(0)" ::: "memory")
#define WVM12() asm volatile("s_waitcnt vmcnt(12)" ::: "memory")
#define PHASE(CB, CK, SKT)                                                  \
  LDAB(af, bq, CB, CK);                                                     \
  stage(CB, CK, SKT);                                                       \
  WVM12();                                                                  \
  BAR();                                                                    \
  WLG4();                                                                   \
  SB0();                                                                    \
  MMAH(af, bq, 0);                                                          \
  WLG0();                                                                   \
  SB0();                                                                    \
  MMAH(af, bq, 4);                                                          \
  BAR();
#define TAILPH(CB, CK, VMW)                                                 \
  LDAB(af, bq, CB, CK);                                                     \
  VMW;                                                                      \
  BAR();                                                                    \
  WLG4();                                                                   \
  SB0();                                                                    \
  MMAH(af, bq, 0);                                                          \
  WLG0();                                                                   \
  SB0();                                                                    \
  MMAH(af, bq, 4);                                                          \
  BAR();

  bf16x8 af[8], bq[4];

  // prologue: fill all 4 slots (ktiles 0,0,1,1); slot (0,0) landed
  stage(0, 0, 0);
  stage(0, 1, 0);
  stage(1, 0, 1);
  stage(1, 1, 1);
  WVM12();
  BAR();

  for (int kt = 0; kt + 3 < KT; kt += 2) {
    PHASE(0, 0, kt + 2);  // ktile kt   kk0
    PHASE(0, 1, kt + 2);  // ktile kt   kk1
    PHASE(1, 0, kt + 3);  // ktile kt+1 kk0
    PHASE(1, 1, kt + 3);  // ktile kt+1 kk1
  }
  // peeled tail: ktiles KT-2 (slots 0,*), KT-1 (slots 1,*); exact drains
  TAILPH(0, 0, asm volatile("s_waitcnt vmcnt(8)" ::: "memory"));
  TAILPH(0, 1, asm volatile("s_waitcnt vmcnt(4)" ::: "memory"));
  TAILPH(1, 0, asm volatile("s_waitcnt vmcnt(0)" ::: "memory"));
  TAILPH(1, 1, );

  // ---- epilogue: bias/act -> LDS (bf16 tile) -> coalesced uint4 stores ----
#pragma unroll
  for (int n = 0; n < 4; n++) {
    int cl = wn * 64 + n * 16 + lrow;
    float bb = bias[bn + cl];
#pragma unroll
    for (int m = 0; m < 8; m++) {
      int rl = wm * 128 + m * 16 + g * 4;
#pragma unroll
      for (int i = 0; i < 4; i++) {
        float v = acc[m][n][i] + bb;
        if (ACT == 1) v = fmaxf(v, 0.f);
        lds[(rl + i) * 256 + cl] = f2bf(v);
      }
    }
  }
  BAR();
  const uint4* lv = (const uint4*)lds;
#pragma unroll
  for (int it = 0; it < 16; it++) {
    int idx = it * 512 + tid;
    int row = idx >> 5;
    int cu = (idx & 31) * 8;
    *(uint4*)&C[(bm + row) * (long)N + bn + cu] = lv[idx];
  }
#undef LDAB
#undef MMAH
#undef WLG4
#undef WLG0
#undef WVM12
#undef PHASE
#undef TAILPH
}

// -- kv partial: part[b,h,sc,d] = sum_{s in chunk} sig(k)*v  (v bf16) -----
__global__ __launch_bounds__(256) void kv_part(const float* __restrict__ kp,
                                               const u16* __restrict__ v,
                                               float* __restrict__ part) {
  int bid = blockIdx.x;
  int sc = bid & 7, h = (bid >> 3) & 15, b = bid >> 7;
  int d = threadIdx.x & 63, si = threadIdx.x >> 6;
  float acc = 0.f;
  int s0 = sc * 512;
  for (int s = s0 + si; s < s0 + 512; s += 4) {
    long tok = (long)b * 4096 + s;
    float sk = sigmoidf_(kp[tok * 16 + h]);
    acc += sk * bf2f(v[tok * 1024 + h * 64 + d]);
  }
  __shared__ float red[4][64];
  red[si][d] = acc;
  __syncthreads();
  if (si == 0)
    part[(long)bid * 64 + d] = red[0][d] + red[1][d] + red[2][d] + red[3][d];
}

// ---------------- reduce chunks + cumsum over heads ----------------------
__global__ __launch_bounds__(64) void kv_finish(const float* __restrict__ part,
                                                float* __restrict__ scum) {
  int b = blockIdx.x, d = threadIdx.x;
  float run = 0.f;
  for (int h = 0; h < 16; h++) {
    float s = 0.f;
    for (int sc = 0; sc < 8; sc++)
      s += part[(((long)b * 16 + h) * 8 + sc) * 64 + d];
    run += s;
    scum[((long)b * 16 + h) * 64 + d] = run;
  }
}

// ------- pre[t, h*64+d] = sigmoid(q[t,h]) * scum[b,h,d]  -> bf16 ---------
__global__ __launch_bounds__(256) void premul(const float* __restrict__ qp,
                                              const float* __restrict__ scum,
                                              u16* __restrict__ out) {
  long idx = ((long)blockIdx.x * 256 + threadIdx.x) * 8;
  long tok = idx >> 10;
  int c = (int)(idx & 1023);
  int h = c >> 6, d0 = c & 63;
  int b = (int)(tok >> 12);
  float sq = sigmoidf_(qp[tok * 16 + h]);
  const float* sp = scum + ((long)b * 16 + h) * 64 + d0;
  uint4 o;
  o.x = (uint32_t)f2bf(sq * sp[0]) | ((uint32_t)f2bf(sq * sp[1]) << 16);
  o.y = (uint32_t)f2bf(sq * sp[2]) | ((uint32_t)f2bf(sq * sp[3]) << 16);
  o.z = (uint32_t)f2bf(sq * sp[4]) | ((uint32_t)f2bf(sq * sp[5]) << 16);
  o.w = (uint32_t)f2bf(sq * sp[6]) | ((uint32_t)f2bf(sq * sp[7]) << 16);
  *((uint4*)(out + idx)) = o;
}

// --- LayerNorm(a_bf16 + r_f32)*g + be ; OMODE 1: f32 out, 2: f32+bf16 ----
template <int OMODE>
__global__ __launch_bounds__(256) void ln_res(const u16* __restrict__ a,
                                              const float* __restrict__ r,
                                              const float* __restrict__ g,
                                              const float* __restrict__ be,
                                              float* __restrict__ outf,
                                              u16* __restrict__ outb) {
  long row = blockIdx.x;
  int tid = threadIdx.x;
  uint2 av = ((const uint2*)(a + row * 1024))[tid];
  float4 rv = ((const float4*)(r + row * 1024))[tid];
  float y[4];
  y[0] = bf2f((u16)(av.x & 0xffff)) + rv.x;
  y[1] = bf2f((u16)(av.x >> 16)) + rv.y;
  y[2] = bf2f((u16)(av.y & 0xffff)) + rv.z;
  y[3] = bf2f((u16)(av.y >> 16)) + rv.w;
  float s = y[0] + y[1] + y[2] + y[3];
  float q = y[0] * y[0] + y[1] * y[1] + y[2] * y[2] + y[3] * y[3];
#pragma unroll
  for (int o = 32; o > 0; o >>= 1) {
    s += __shfl_down(s, o);
    q += __shfl_down(q, o);
  }
  __shared__ float s1[4], s2[4];
  int wid = tid >> 6, lane = tid & 63;
  if (lane == 0) { s1[wid] = s; s2[wid] = q; }
  __syncthreads();
  s = s1[0] + s1[1] + s1[2] + s1[3];
  q = s2[0] + s2[1] + s2[2] + s2[3];
  float mu = s * (1.f / 1024.f);
  float var = q * (1.f / 1024.f) - mu * mu;
  float inv = rsqrtf(fmaxf(var, 0.f) + 1e-6f);
  float4 gv = ((const float4*)g)[tid], bv = ((const float4*)be)[tid];
  float o0 = gv.x * (y[0] - mu) * inv + bv.x;
  float o1 = gv.y * (y[1] - mu) * inv + bv.y;
  float o2 = gv.z * (y[2] - mu) * inv + bv.z;
  float o3 = gv.w * (y[3] - mu) * inv + bv.w;
  ((float4*)(outf + row * 1024))[tid] = make_float4(o0, o1, o2, o3);
  if (OMODE == 2) {
    uint2 ob;
    ob.x = (uint32_t)f2bf(o0) | ((uint32_t)f2bf(o1) << 16);
    ob.y = (uint32_t)f2bf(o2) | ((uint32_t)f2bf(o3) << 16);
    ((uint2*)(outb + row * 1024))[tid] = ob;
  }
}

extern "C" void kernel_launch(void* const* d_in, const int* in_sizes, int n_in,
                              void* d_out, int out_size, void* d_ws,
                              size_t ws_size, hipStream_t stream) {
  const float* x   = (const float*)d_in[0];
  const float* enc = (const float*)d_in[1];
  const float* wq1 = (const float*)d_in[2];  const float* bq1 = (const float*)d_in[3];
  const float* wk1 = (const float*)d_in[4];  const float* bk1 = (const float*)d_in[5];
  const float* wv1 = (const float*)d_in[6];  const float* bv1 = (const float*)d_in[7];
  const float* wo1 = (const float*)d_in[8];  const float* bo1 = (const float*)d_in[9];
  const float* wq2 = (const float*)d_in[10]; const float* bq2 = (const float*)d_in[11];
  const float* wk2 = (const float*)d_in[12]; const float* bk2 = (const float*)d_in[13];
  const float* wv2 = (const float*)d_in[14]; const float* bv2 = (const float*)d_in[15];
  const float* wo2 = (const float*)d_in[16]; const float* bo2 = (const float*)d_in[17];
  const float* wf1 = (const float*)d_in[18]; const float* bf1 = (const float*)d_in[19];
  const float* wf2 = (const float*)d_in[20]; const float* bf2 = (const float*)d_in[21];
  const float* g1 = (const float*)d_in[22];  const float* be1 = (const float*)d_in[23];
  const float* g2 = (const float*)d_in[24];  const float* be2 = (const float*)d_in[25];
  const float* g3 = (const float*)d_in[26];  const float* be3 = (const float*)d_in[27];
  (void)in_sizes; (void)n_in; (void)out_size; (void)ws_size;

  const size_t S = (size_t)16384 * 1024;  // tokens * d_model
  float* O0 = (float*)d_out;              // out3 (f32)

  char* base = (char*)d_ws;
  size_t off = 0;
  auto alloc = [&](size_t bytes) -> void* {
    void* p = base + off;
    off += (bytes + 255) & ~(size_t)255;
    return p;
  };
  u16* WT1   = (u16*)alloc((size_t)4096 * 1024 * 2);  // weight^T bf16
  u16* WT2   = (u16*)alloc((size_t)4096 * 1024 * 2);
  float* qb  = (float*)alloc((size_t)16384 * 16 * 4);
  float* kb  = (float*)alloc((size_t)16384 * 16 * 4);
  float* kvp = (float*)alloc((size_t)512 * 64 * 4);
  float* scm = (float*)alloc((size_t)4 * 16 * 64 * 4);
  u16* FA    = (u16*)alloc(S * 2);                    // bf16: v / attn / ffn_out
  u16* XB    = (u16*)alloc(S * 2);                    // bf16: x / enc
  u16* FB    = (u16*)alloc(S * 2);                    // bf16: pre (attn input)
  u16* FM    = (u16*)alloc((size_t)16384 * 4096 * 2); // bf16: ffn mid (134MB)
  u16* O1b   = (u16*)alloc(S * 2);                    // bf16 out1
  u16* O2b   = (u16*)alloc(S * 2);                    // bf16 out2
  float* O1f = (float*)alloc(S * 4);                  // f32 out1
  float* O2f = (float*)alloc(S * 4);                  // f32 out2

  const int T = 16384;
  dim3 blk(256), gblk(512);

  // ---- MHA1 (q=k=v from x) ----
  cvt_f2b<<<16384, blk, 0, stream>>>(x, XB);
  transpose_cvt<<<dim3(32, 32), blk, 0, stream>>>(wv1, WT1, 1024, 1024);
  gemm256<0><<<dim3(4, 64), gblk, 0, stream>>>(XB, WT1, bv1, FA, T, 1024, 1024);
  proj_mfma<<<1024, blk, 0, stream>>>(XB, XB, wq1, bq1, wk1, bk1, qb, kb);
  kv_part<<<512, blk, 0, stream>>>(kb, FA, kvp);
  kv_finish<<<4, 64, 0, stream>>>(kvp, scm);
  premul<<<8192, blk, 0, stream>>>(qb, scm, FB);
  transpose_cvt<<<dim3(32, 32), blk, 0, stream>>>(wo1, WT1, 1024, 1024);
  gemm256<0><<<dim3(4, 64), gblk, 0, stream>>>(FB, WT1, bo1, FA, T, 1024, 1024);
  ln_res<2><<<16384, blk, 0, stream>>>(FA, x, g1, be1, O1f, O1b);  // out1

  // ---- MHA2 (q from out1, k/v from enc) ----
  cvt_f2b<<<16384, blk, 0, stream>>>(enc, XB);
  transpose_cvt<<<dim3(32, 32), blk, 0, stream>>>(wv2, WT1, 1024, 1024);
  gemm256<0><<<dim3(4, 64), gblk, 0, stream>>>(XB, WT1, bv2, FA, T, 1024, 1024);
  proj_mfma<<<1024, blk, 0, stream>>>(O1b, XB, wq2, bq2, wk2, bk2, qb, kb);
  kv_part<<<512, blk, 0, stream>>>(kb, FA, kvp);
  kv_finish<<<4, 64, 0, stream>>>(kvp, scm);
  premul<<<8192, blk, 0, stream>>>(qb, scm, FB);
  transpose_cvt<<<dim3(32, 32), blk, 0, stream>>>(wo2, WT1, 1024, 1024);
  gemm256<0><<<dim3(4, 64), gblk, 0, stream>>>(FB, WT1, bo2, FA, T, 1024, 1024);
  ln_res<2><<<16384, blk, 0, stream>>>(FA, O1f, g2, be2, O2f, O2b);  // out2

  // ---- FFN ----
  transpose_cvt<<<dim3(128, 32), blk, 0, stream>>>(wf1, WT1, 1024, 4096);
  transpose_cvt<<<dim3(32, 128), blk, 0, stream>>>(wf2, WT2, 4096, 1024);
  gemm256<1><<<dim3(16, 64), gblk, 0, stream>>>(O2b, WT1, bf1, FM, T, 4096, 1024);
  gemm256<0><<<dim3(4, 64), gblk, 0, stream>>>(FM, WT2, bf2, FA, T, 1024, 4096);
  ln_res<1><<<16384, blk, 0, stream>>>(FA, O2f, g3, be3, O0, nullptr);  // out3

  // outputs 1 and 2 must be zeros
  hipMemsetAsync((float*)d_out + S, 0, 2 * S * 4, stream);
}

// Round 11
// 740.863 us; speedup vs baseline: 1.4183x; 1.0133x over previous
//
#include <hip/hip_runtime.h>
#include <cstdint>

typedef unsigned short u16;
typedef __bf16 bf16x8 __attribute__((ext_vector_type(8)));
typedef float f32x4 __attribute__((ext_vector_type(4)));

__device__ __forceinline__ float bf2f(u16 h) {
  union { uint32_t u; float f; } v; v.u = (uint32_t)h << 16; return v.f;
}
__device__ __forceinline__ u16 f2bf(float f) {
  union { float f; uint32_t u; } v; v.f = f;
  uint32_t r = v.u + 0x7fffu + ((v.u >> 16) & 1u);
  return (u16)(r >> 16);
}
__device__ __forceinline__ float sigmoidf_(float x) {
  return 1.0f / (1.0f + __expf(-x));
}
__device__ __forceinline__ void load_lds16(const void* g, void* l) {
  __builtin_amdgcn_global_load_lds(
      (const __attribute__((address_space(1))) void*)g,
      (__attribute__((address_space(3))) void*)l, 16, 0, 0);
}
#define BAR() __builtin_amdgcn_s_barrier()

// ---------------- flat convert f32 -> bf16 (n multiple of 4) -------------
__global__ __launch_bounds__(256) void cvt_f2b(const float* __restrict__ in,
                                               u16* __restrict__ out) {
  long i = ((long)blockIdx.x * 256 + threadIdx.x) * 4;
  float4 v = *(const float4*)(in + i);
  uint2 o;
  o.x = (uint32_t)f2bf(v.x) | ((uint32_t)f2bf(v.y) << 16);
  o.y = (uint32_t)f2bf(v.z) | ((uint32_t)f2bf(v.w) << 16);
  *((uint2*)(out + i)) = o;
}

// ------------- transpose+convert: in f32 [K][N] -> out bf16 [N][K] -------
__global__ __launch_bounds__(256) void transpose_cvt(
    const float* __restrict__ in, u16* __restrict__ out, int K, int N) {
  __shared__ float t[32][33];
  int n0 = blockIdx.x * 32, k0 = blockIdx.y * 32;
  int tx = threadIdx.x & 31, ty = threadIdx.x >> 5;
#pragma unroll
  for (int i = 0; i < 32; i += 8)
    t[ty + i][tx] = in[(long)(k0 + ty + i) * N + n0 + tx];
  __syncthreads();
#pragma unroll
  for (int i = 0; i < 32; i += 8)
    out[(long)(n0 + ty + i) * K + k0 + tx] = f2bf(t[tx][ty + i]);
}

// ===== MFMA projection: q = xq@wq+bq, k = xk@wk+bk ; [T,1024]->[T,16]x2 ===
__global__ __launch_bounds__(256) void proj_mfma(
    const u16* __restrict__ xq, const u16* __restrict__ xk,
    const float* __restrict__ wq, const float* __restrict__ bq,
    const float* __restrict__ wk, const float* __restrict__ bk,
    float* __restrict__ qout, float* __restrict__ kout) {
  __shared__ __attribute__((aligned(16))) u16 wt[2][16384];  // 64KB
  __shared__ __attribute__((aligned(16))) float red[4][64][8];
  const int tid = threadIdx.x;
  for (int kq = 0; kq < 4; kq++) {
    int k = kq * 256 + tid;
    const float4* q4 = (const float4*)(wq + (long)k * 16);
    const float4* k4 = (const float4*)(wk + (long)k * 16);
#pragma unroll
    for (int p = 0; p < 4; p++) {
      float4 qv = q4[p], kv = k4[p];
      float qf[4] = {qv.x, qv.y, qv.z, qv.w};
      float kf[4] = {kv.x, kv.y, kv.z, kv.w};
#pragma unroll
      for (int j = 0; j < 4; j++) {
        int c = p * 4 + j;
        int off = (c * 2048 + k * 2) ^ ((c & 7) << 4);
        *(u16*)((char*)wt[0] + off) = f2bf(qf[j]);
        *(u16*)((char*)wt[1] + off) = f2bf(kf[j]);
      }
    }
  }
  __syncthreads();
  const int wv = tid >> 6, lane = tid & 63;
  const int lrow = lane & 15, g = lane >> 4;
  const long tok0 = (long)blockIdx.x * 16;
  const u16* xqp = xq + (tok0 + lrow) * 1024 + wv * 256 + g * 8;
  const u16* xkp = xk + (tok0 + lrow) * 1024 + wv * 256 + g * 8;
  const int swz = (lrow & 7) << 4;
  const int wbase = lrow * 2048 + wv * 512 + g * 16;
  f32x4 accq = {}, acck = {};
#pragma unroll
  for (int mf = 0; mf < 8; mf++) {
    bf16x8 aq_ = *(const bf16x8*)(xqp + mf * 32);
    bf16x8 ak_ = *(const bf16x8*)(xkp + mf * 32);
    int off = (wbase + mf * 64) ^ swz;
    bf16x8 bq_ = *(const bf16x8*)((const char*)wt[0] + off);
    bf16x8 bk_ = *(const bf16x8*)((const char*)wt[1] + off);
    accq = __builtin_amdgcn_mfma_f32_16x16x32_bf16(aq_, bq_, accq, 0, 0, 0);
    acck = __builtin_amdgcn_mfma_f32_16x16x32_bf16(ak_, bk_, acck, 0, 0, 0);
  }
  *(f32x4*)&red[wv][lane][0] = accq;
  *(f32x4*)&red[wv][lane][4] = acck;
  __syncthreads();
  if (tid < 64) {
    f32x4 q0 = *(const f32x4*)&red[0][tid][0];
    f32x4 k0 = *(const f32x4*)&red[0][tid][4];
#pragma unroll
    for (int w = 1; w < 4; w++) {
      q0 += *(const f32x4*)&red[w][tid][0];
      k0 += *(const f32x4*)&red[w][tid][4];
    }
    int col = tid & 15, r0 = (tid >> 4) * 4;
    float bqv = bq[col], bkv = bk[col];
#pragma unroll
    for (int i = 0; i < 4; i++) {
      qout[(tok0 + r0 + i) * 16 + col] = q0[i] + bqv;
      kout[(tok0 + r0 + i) * 16 + col] = k0[i] + bkv;
    }
  }
}

// ===== 256x256 MFMA GEMM — m201-discipline 4-phase/ktile schedule =========
// C[M,N] = act(A[M,K]bf16 @ BT[N,K]^T + bias). M%256==0, N%256==0, K%128==0
// (KT=K/64 >= 2). 512 thr = 8 waves (2Mx4N). LDS 128KB = 4 slots
// [buf=kt&1][kk] of {16KB A + 16KB B}, st-swizzled (inverse-swizzled global
// source + swizzled ds_read). Per ktile, 4 phases, each:
//   {plain ds_reads (8 or 4 x b128); 2-load stage; [vmcnt(4) ph2/ph4 only];
//    s_barrier; lgkmcnt(0); setprio(1); 16 MFMA; setprio(0); s_barrier}
// No sched_barrier, no split lgkm — compiler owns the fine schedule (plain
// loads are dep-tracked). Stage unit u_j (2 loads, phase j) is consumed at
// phase j+4 (kk0) / j+2 (kk1); vmcnt(4) at even-phase ends lands the 2
// oldest units — exact. Slot refill issues >=2 barriers after its last
// read. Final ktile peeled: no stage, vmcnt(0) at its ph2.
template <int ACT>
__global__ __launch_bounds__(512) void gemm256(
    const u16* __restrict__ A, const u16* __restrict__ BT,
    const float* __restrict__ bias, u16* __restrict__ C, int M, int N,
    int K) {
  __shared__ __attribute__((aligned(16))) u16 lds[65536];  // 128 KB
  const int tid = threadIdx.x;
  const int wid = tid >> 6, lane = tid & 63;
  const int wm = wid >> 2, wn = wid & 3;
  const int lrow = lane & 15, g = lane >> 4;

  int nwg = gridDim.x * gridDim.y;
  int orig = blockIdx.y * gridDim.x + blockIdx.x;
  int wg = (nwg & 7) ? orig : ((orig & 7) * (nwg >> 3) + (orig >> 3));
  const long bn = (long)(wg % gridDim.x) * 256;
  const long bm = (long)(wg / gridDim.x) * 256;

  const int rr = wid * 16 + (lane >> 2);                        // staging row
  const int esrc = ((lane & 3) * 8) ^ (((lane >> 5) & 1) * 16); // src swizzle
  const u16* Abase = A + (bm + rr) * (long)K + esrc;
  const u16* Bbase = BT + (bn + rr) * (long)K + esrc;
  const long jstep = (long)128 * K;
  char* ldsc = (char*)lds;
  const int ldsw = wid * 1024;

  const int swr = ((lrow >> 3) & 1) * 32;
  const int aoff = (wm * 128 + lrow) * 64 + ((g * 16) ^ swr);
  const int boff = 32768 + (wn * 64 + lrow) * 64 + ((g * 16) ^ swr);

  f32x4 acc[8][4] = {};
  const int KT = K >> 6;

  // stage half-slot: HALF 0 = A (2 loads), HALF 1 = B (2 loads)
  auto stage2 = [&](int buf, int kk, int kt, int half) {
    int dA = buf * 65536 + kk * 16384 + ldsw;
    if (half == 0) {
      const u16* sA = Abase + (long)kt * 64 + kk * 32;
      load_lds16(sA, ldsc + dA);
      load_lds16(sA + jstep, ldsc + dA + 8192);
    } else {
      const u16* sB = Bbase + (long)kt * 64 + kk * 32;
      load_lds16(sB, ldsc + dA + 32768);
      load_lds16(sB + jstep, ldsc + dA + 40960);
    }
  };

#define LDAB8(BUF, KK)                                                      \
  {                                                                         \
    const char* _b = ldsc + (BUF) * 65536 + (KK) * 16384;                   \
    _Pragma("unroll") for (int m = 0; m < 4; m++)                           \
        af[m] = *(const bf16x8*)(_b + aoff + m * 1024);                     \
    _Pragma("unroll") for (int n = 0; n < 4; n++)                           \
        bq[n] = *(const bf16x8*)(_b + boff + n * 1024);                     \
  }
#define LDA4(BUF, KK)                                                       \
  {                                                                         \
    const char* _b = ldsc + (BUF) * 65536 + (KK) * 16384;                   \
    _Pragma("unroll") for (int m = 4; m < 8; m++)                           \
        af[m] = *(const bf16x8*)(_b + aoff + m * 1024);                     \
  }
#define MMA16(M0)                                                           \
  __builtin_amdgcn_s_setprio(1);                                            \
  _Pragma("unroll") for (int m = M0; m < M0 + 4; m++)                       \
  _Pragma("unroll") for (int n = 0; n < 4; n++)                             \
      acc[m][n] = __builtin_amdgcn_mfma_f32_16x16x32_bf16(af[m], bq[n],     \
                                                          acc[m][n], 0, 0,  \
                                                          0);               \
  __builtin_amdgcn_s_setprio(0);
#define WLG0() asm volatile("s_waitcnt lgkmcnt(0)" ::: "memory")
#define WVM4() asm volatile("s_waitcnt vmcnt(4)" ::: "memory")
#define WVM0() asm volatile("s_waitcnt vmcnt(0)" ::: "memory")

  bf16x8 af[8], bq[4];

  // prologue: stage ktile 0 (both kk slots, buf 0); land kk0
  stage2(0, 0, 0, 0);
  stage2(0, 0, 0, 1);
  stage2(0, 1, 0, 0);
  stage2(0, 1, 0, 1);
  WVM4();
  BAR();

  for (int kt = 0; kt + 1 < KT; ++kt) {
    const int b0 = kt & 1, b1 = b0 ^ 1;
    // ph1: consume (b0,0) m0-3; stage A of (b1,0) <- ktile kt+1
    LDAB8(b0, 0);
    stage2(b1, 0, kt + 1, 0);
    BAR(); WLG0();
    MMA16(0);
    BAR();
    // ph2: consume (b0,0) m4-7; stage B of (b1,0); vmcnt(4)
    LDA4(b0, 0);
    stage2(b1, 0, kt + 1, 1);
    WVM4();
    BAR(); WLG0();
    MMA16(4);
    BAR();
    // ph3: consume (b0,1) m0-3; stage A of (b1,1)
    LDAB8(b0, 1);
    stage2(b1, 1, kt + 1, 0);
    BAR(); WLG0();
    MMA16(0);
    BAR();
    // ph4: consume (b0,1) m4-7; stage B of (b1,1); vmcnt(4)
    LDA4(b0, 1);
    stage2(b1, 1, kt + 1, 1);
    WVM4();
    BAR(); WLG0();
    MMA16(4);
    BAR();
  }
  {  // peeled final ktile (no staging)
    const int b0 = (KT - 1) & 1;
    LDAB8(b0, 0);
    BAR(); WLG0();
    MMA16(0);
    BAR();
    LDA4(b0, 0);
    WVM0();
    BAR(); WLG0();
    MMA16(4);
    BAR();
    LDAB8(b0, 1);
    BAR(); WLG0();
    MMA16(0);
    BAR();
    LDA4(b0, 1);
    BAR(); WLG0();
    MMA16(4);
    BAR();
  }

  // ---- epilogue: bias/act -> LDS (bf16 tile) -> coalesced uint4 stores ----
#pragma unroll
  for (int n = 0; n < 4; n++) {
    int cl = wn * 64 + n * 16 + lrow;
    float bb = bias[bn + cl];
#pragma unroll
    for (int m = 0; m < 8; m++) {
      int rl = wm * 128 + m * 16 + g * 4;
#pragma unroll
      for (int i = 0; i < 4; i++) {
        float v = acc[m][n][i] + bb;
        if (ACT == 1) v = fmaxf(v, 0.f);
        lds[(rl + i) * 256 + cl] = f2bf(v);
      }
    }
  }
  BAR();
  const uint4* lv = (const uint4*)lds;
#pragma unroll
  for (int it = 0; it < 16; it++) {
    int idx = it * 512 + tid;
    int row = idx >> 5;
    int cu = (idx & 31) * 8;
    *(uint4*)&C[(bm + row) * (long)N + bn + cu] = lv[idx];
  }
#undef LDAB8
#undef LDA4
#undef MMA16
#undef WLG0
#undef WVM4
#undef WVM0
}

// -- kv partial: part[b,h,sc,d] = sum_{s in chunk} sig(k)*v  (v bf16) -----
__global__ __launch_bounds__(256) void kv_part(const float* __restrict__ kp,
                                               const u16* __restrict__ v,
                                               float* __restrict__ part) {
  int bid = blockIdx.x;
  int sc = bid & 7, h = (bid >> 3) & 15, b = bid >> 7;
  int d = threadIdx.x & 63, si = threadIdx.x >> 6;
  float acc = 0.f;
  int s0 = sc * 512;
  for (int s = s0 + si; s < s0 + 512; s += 4) {
    long tok = (long)b * 4096 + s;
    float sk = sigmoidf_(kp[tok * 16 + h]);
    acc += sk * bf2f(v[tok * 1024 + h * 64 + d]);
  }
  __shared__ float red[4][64];
  red[si][d] = acc;
  __syncthreads();
  if (si == 0)
    part[(long)bid * 64 + d] = red[0][d] + red[1][d] + red[2][d] + red[3][d];
}

// ---------------- reduce chunks + cumsum over heads ----------------------
__global__ __launch_bounds__(64) void kv_finish(const float* __restrict__ part,
                                                float* __restrict__ scum) {
  int b = blockIdx.x, d = threadIdx.x;
  float run = 0.f;
  for (int h = 0; h < 16; h++) {
    float s = 0.f;
    for (int sc = 0; sc < 8; sc++)
      s += part[(((long)b * 16 + h) * 8 + sc) * 64 + d];
    run += s;
    scum[((long)b * 16 + h) * 64 + d] = run;
  }
}

// ------- pre[t, h*64+d] = sigmoid(q[t,h]) * scum[b,h,d]  -> bf16 ---------
__global__ __launch_bounds__(256) void premul(const float* __restrict__ qp,
                                              const float* __restrict__ scum,
                                              u16* __restrict__ out) {
  long idx = ((long)blockIdx.x * 256 + threadIdx.x) * 8;
  long tok = idx >> 10;
  int c = (int)(idx & 1023);
  int h = c >> 6, d0 = c & 63;
  int b = (int)(tok >> 12);
  float sq = sigmoidf_(qp[tok * 16 + h]);
  const float* sp = scum + ((long)b * 16 + h) * 64 + d0;
  uint4 o;
  o.x = (uint32_t)f2bf(sq * sp[0]) | ((uint32_t)f2bf(sq * sp[1]) << 16);
  o.y = (uint32_t)f2bf(sq * sp[2]) | ((uint32_t)f2bf(sq * sp[3]) << 16);
  o.z = (uint32_t)f2bf(sq * sp[4]) | ((uint32_t)f2bf(sq * sp[5]) << 16);
  o.w = (uint32_t)f2bf(sq * sp[6]) | ((uint32_t)f2bf(sq * sp[7]) << 16);
  *((uint4*)(out + idx)) = o;
}

// --- LayerNorm(a_bf16 + r_f32)*g + be ; OMODE 1: f32 out, 2: f32+bf16 ----
template <int OMODE>
__global__ __launch_bounds__(256) void ln_res(const u16* __restrict__ a,
                                              const float* __restrict__ r,
                                              const float* __restrict__ g,
                                              const float* __restrict__ be,
                                              float* __restrict__ outf,
                                              u16* __restrict__ outb) {
  long row = blockIdx.x;
  int tid = threadIdx.x;
  uint2 av = ((const uint2*)(a + row * 1024))[tid];
  float4 rv = ((const float4*)(r + row * 1024))[tid];
  float y[4];
  y[0] = bf2f((u16)(av.x & 0xffff)) + rv.x;
  y[1] = bf2f((u16)(av.x >> 16)) + rv.y;
  y[2] = bf2f((u16)(av.y & 0xffff)) + rv.z;
  y[3] = bf2f((u16)(av.y >> 16)) + rv.w;
  float s = y[0] + y[1] + y[2] + y[3];
  float q = y[0] * y[0] + y[1] * y[1] + y[2] * y[2] + y[3] * y[3];
#pragma unroll
  for (int o = 32; o > 0; o >>= 1) {
    s += __shfl_down(s, o);
    q += __shfl_down(q, o);
  }
  __shared__ float s1[4], s2[4];
  int wid = tid >> 6, lane = tid & 63;
  if (lane == 0) { s1[wid] = s; s2[wid] = q; }
  __syncthreads();
  s = s1[0] + s1[1] + s1[2] + s1[3];
  q = s2[0] + s2[1] + s2[2] + s2[3];
  float mu = s * (1.f / 1024.f);
  float var = q * (1.f / 1024.f) - mu * mu;
  float inv = rsqrtf(fmaxf(var, 0.f) + 1e-6f);
  float4 gv = ((const float4*)g)[tid], bv = ((const float4*)be)[tid];
  float o0 = gv.x * (y[0] - mu) * inv + bv.x;
  float o1 = gv.y * (y[1] - mu) * inv + bv.y;
  float o2 = gv.z * (y[2] - mu) * inv + bv.z;
  float o3 = gv.w * (y[3] - mu) * inv + bv.w;
  ((float4*)(outf + row * 1024))[tid] = make_float4(o0, o1, o2, o3);
  if (OMODE == 2) {
    uint2 ob;
    ob.x = (uint32_t)f2bf(o0) | ((uint32_t)f2bf(o1) << 16);
    ob.y = (uint32_t)f2bf(o2) | ((uint32_t)f2bf(o3) << 16);
    ((uint2*)(outb + row * 1024))[tid] = ob;
  }
}

extern "C" void kernel_launch(void* const* d_in, const int* in_sizes, int n_in,
                              void* d_out, int out_size, void* d_ws,
                              size_t ws_size, hipStream_t stream) {
  const float* x   = (const float*)d_in[0];
  const float* enc = (const float*)d_in[1];
  const float* wq1 = (const float*)d_in[2];  const float* bq1 = (const float*)d_in[3];
  const float* wk1 = (const float*)d_in[4];  const float* bk1 = (const float*)d_in[5];
  const float* wv1 = (const float*)d_in[6];  const float* bv1 = (const float*)d_in[7];
  const float* wo1 = (const float*)d_in[8];  const float* bo1 = (const float*)d_in[9];
  const float* wq2 = (const float*)d_in[10]; const float* bq2 = (const float*)d_in[11];
  const float* wk2 = (const float*)d_in[12]; const float* bk2 = (const float*)d_in[13];
  const float* wv2 = (const float*)d_in[14]; const float* bv2 = (const float*)d_in[15];
  const float* wo2 = (const float*)d_in[16]; const float* bo2 = (const float*)d_in[17];
  const float* wf1 = (const float*)d_in[18]; const float* bf1 = (const float*)d_in[19];
  const float* wf2 = (const float*)d_in[20]; const float* bf2 = (const float*)d_in[21];
  const float* g1 = (const float*)d_in[22];  const float* be1 = (const float*)d_in[23];
  const float* g2 = (const float*)d_in[24];  const float* be2 = (const float*)d_in[25];
  const float* g3 = (const float*)d_in[26];  const float* be3 = (const float*)d_in[27];
  (void)in_sizes; (void)n_in; (void)out_size; (void)ws_size;

  const size_t S = (size_t)16384 * 1024;  // tokens * d_model
  float* O0 = (float*)d_out;              // out3 (f32)

  char* base = (char*)d_ws;
  size_t off = 0;
  auto alloc = [&](size_t bytes) -> void* {
    void* p = base + off;
    off += (bytes + 255) & ~(size_t)255;
    return p;
  };
  u16* WT1   = (u16*)alloc((size_t)4096 * 1024 * 2);  // weight^T bf16
  u16* WT2   = (u16*)alloc((size_t)4096 * 1024 * 2);
  float* qb  = (float*)alloc((size_t)16384 * 16 * 4);
  float* kb  = (float*)alloc((size_t)16384 * 16 * 4);
  float* kvp = (float*)alloc((size_t)512 * 64 * 4);
  float* scm = (float*)alloc((size_t)4 * 16 * 64 * 4);
  u16* FA    = (u16*)alloc(S * 2);                    // bf16: v / attn / ffn_out
  u16* XB    = (u16*)alloc(S * 2);                    // bf16: x / enc
  u16* FB    = (u16*)alloc(S * 2);                    // bf16: pre (attn input)
  u16* FM    = (u16*)alloc((size_t)16384 * 4096 * 2); // bf16: ffn mid (134MB)
  u16* O1b   = (u16*)alloc(S * 2);                    // bf16 out1
  u16* O2b   = (u16*)alloc(S * 2);                    // bf16 out2
  float* O1f = (float*)alloc(S * 4);                  // f32 out1
  float* O2f = (float*)alloc(S * 4);                  // f32 out2

  const int T = 16384;
  dim3 blk(256), gblk(512);

  // ---- MHA1 (q=k=v from x) ----
  cvt_f2b<<<16384, blk, 0, stream>>>(x, XB);
  transpose_cvt<<<dim3(32, 32), blk, 0, stream>>>(wv1, WT1, 1024, 1024);
  gemm256<0><<<dim3(4, 64), gblk, 0, stream>>>(XB, WT1, bv1, FA, T, 1024, 1024);
  proj_mfma<<<1024, blk, 0, stream>>>(XB, XB, wq1, bq1, wk1, bk1, qb, kb);
  kv_part<<<512, blk, 0, stream>>>(kb, FA, kvp);
  kv_finish<<<4, 64, 0, stream>>>(kvp, scm);
  premul<<<8192, blk, 0, stream>>>(qb, scm, FB);
  transpose_cvt<<<dim3(32, 32), blk, 0, stream>>>(wo1, WT1, 1024, 1024);
  gemm256<0><<<dim3(4, 64), gblk, 0, stream>>>(FB, WT1, bo1, FA, T, 1024, 1024);
  ln_res<2><<<16384, blk, 0, stream>>>(FA, x, g1, be1, O1f, O1b);  // out1

  // ---- MHA2 (q from out1, k/v from enc) ----
  cvt_f2b<<<16384, blk, 0, stream>>>(enc, XB);
  transpose_cvt<<<dim3(32, 32), blk, 0, stream>>>(wv2, WT1, 1024, 1024);
  gemm256<0><<<dim3(4, 64), gblk, 0, stream>>>(XB, WT1, bv2, FA, T, 1024, 1024);
  proj_mfma<<<1024, blk, 0, stream>>>(O1b, XB, wq2, bq2, wk2, bk2, qb, kb);
  kv_part<<<512, blk, 0, stream>>>(kb, FA, kvp);
  kv_finish<<<4, 64, 0, stream>>>(kvp, scm);
  premul<<<8192, blk, 0, stream>>>(qb, scm, FB);
  transpose_cvt<<<dim3(32, 32), blk, 0, stream>>>(wo2, WT1, 1024, 1024);
  gemm256<0><<<dim3(4, 64), gblk, 0, stream>>>(FB, WT1, bo2, FA, T, 1024, 1024);
  ln_res<2><<<16384, blk, 0, stream>>>(FA, O1f, g2, be2, O2f, O2b);  // out2

  // ---- FFN ----
  transpose_cvt<<<dim3(128, 32), blk, 0, stream>>>(wf1, WT1, 1024, 4096);
  transpose_cvt<<<dim3(32, 128), blk, 0, stream>>>(wf2, WT2, 4096, 1024);
  gemm256<1><<<dim3(16, 64), gblk, 0, stream>>>(O2b, WT1, bf1, FM, T, 4096, 1024);
  gemm256<0><<<dim3(4, 64), gblk, 0, stream>>>(FM, WT2, bf2, FA, T, 1024, 4096);
  ln_res<1><<<16384, blk, 0, stream>>>(FA, O2f, g3, be3, O0, nullptr);  // out3

  // outputs 1 and 2 must be zeros
  hipMemsetAsync((float*)d_out + S, 0, 2 * S * 4, stream);
}

// Round 12
// 697.318 us; speedup vs baseline: 1.5069x; 1.0624x over previous
//
#include <hip/hip_runtime.h>
#include <cstdint>

typedef unsigned short u16;
typedef __bf16 bf16x8 __attribute__((ext_vector_type(8)));
typedef float f32x4 __attribute__((ext_vector_type(4)));

__device__ __forceinline__ float bf2f(u16 h) {
  union { uint32_t u; float f; } v; v.u = (uint32_t)h << 16; return v.f;
}
__device__ __forceinline__ u16 f2bf(float f) {
  union { float f; uint32_t u; } v; v.f = f;
  uint32_t r = v.u + 0x7fffu + ((v.u >> 16) & 1u);
  return (u16)(r >> 16);
}
__device__ __forceinline__ float sigmoidf_(float x) {
  return 1.0f / (1.0f + __expf(-x));
}
__device__ __forceinline__ void load_lds16(const void* g, void* l) {
  __builtin_amdgcn_global_load_lds(
      (const __attribute__((address_space(1))) void*)g,
      (__attribute__((address_space(3))) void*)l, 16, 0, 0);
}
#define BAR() __builtin_amdgcn_s_barrier()

// ---------------- flat convert f32 -> bf16 (n multiple of 4) -------------
__global__ __launch_bounds__(256) void cvt_f2b(const float* __restrict__ in,
                                               u16* __restrict__ out) {
  long i = ((long)blockIdx.x * 256 + threadIdx.x) * 4;
  float4 v = *(const float4*)(in + i);
  uint2 o;
  o.x = (uint32_t)f2bf(v.x) | ((uint32_t)f2bf(v.y) << 16);
  o.y = (uint32_t)f2bf(v.z) | ((uint32_t)f2bf(v.w) << 16);
  *((uint2*)(out + i)) = o;
}

// ------------- transpose+convert: in f32 [K][N] -> out bf16 [N][K] -------
__global__ __launch_bounds__(256) void transpose_cvt(
    const float* __restrict__ in, u16* __restrict__ out, int K, int N) {
  __shared__ float t[32][33];
  int n0 = blockIdx.x * 32, k0 = blockIdx.y * 32;
  int tx = threadIdx.x & 31, ty = threadIdx.x >> 5;
#pragma unroll
  for (int i = 0; i < 32; i += 8)
    t[ty + i][tx] = in[(long)(k0 + ty + i) * N + n0 + tx];
  __syncthreads();
#pragma unroll
  for (int i = 0; i < 32; i += 8)
    out[(long)(n0 + ty + i) * K + k0 + tx] = f2bf(t[tx][ty + i]);
}

// ===== MFMA projection: q = xq@wq+bq, k = xk@wk+bk ; [T,1024]->[T,16]x2 ===
__global__ __launch_bounds__(256) void proj_mfma(
    const u16* __restrict__ xq, const u16* __restrict__ xk,
    const float* __restrict__ wq, const float* __restrict__ bq,
    const float* __restrict__ wk, const float* __restrict__ bk,
    float* __restrict__ qout, float* __restrict__ kout) {
  __shared__ __attribute__((aligned(16))) u16 wt[2][16384];  // 64KB
  __shared__ __attribute__((aligned(16))) float red[4][64][8];
  const int tid = threadIdx.x;
  for (int kq = 0; kq < 4; kq++) {
    int k = kq * 256 + tid;
    const float4* q4 = (const float4*)(wq + (long)k * 16);
    const float4* k4 = (const float4*)(wk + (long)k * 16);
#pragma unroll
    for (int p = 0; p < 4; p++) {
      float4 qv = q4[p], kv = k4[p];
      float qf[4] = {qv.x, qv.y, qv.z, qv.w};
      float kf[4] = {kv.x, kv.y, kv.z, kv.w};
#pragma unroll
      for (int j = 0; j < 4; j++) {
        int c = p * 4 + j;
        int off = (c * 2048 + k * 2) ^ ((c & 7) << 4);
        *(u16*)((char*)wt[0] + off) = f2bf(qf[j]);
        *(u16*)((char*)wt[1] + off) = f2bf(kf[j]);
      }
    }
  }
  __syncthreads();
  const int wv = tid >> 6, lane = tid & 63;
  const int lrow = lane & 15, g = lane >> 4;
  const long tok0 = (long)blockIdx.x * 16;
  const u16* xqp = xq + (tok0 + lrow) * 1024 + wv * 256 + g * 8;
  const u16* xkp = xk + (tok0 + lrow) * 1024 + wv * 256 + g * 8;
  const int swz = (lrow & 7) << 4;
  const int wbase = lrow * 2048 + wv * 512 + g * 16;
  f32x4 accq = {}, acck = {};
#pragma unroll
  for (int mf = 0; mf < 8; mf++) {
    bf16x8 aq_ = *(const bf16x8*)(xqp + mf * 32);
    bf16x8 ak_ = *(const bf16x8*)(xkp + mf * 32);
    int off = (wbase + mf * 64) ^ swz;
    bf16x8 bq_ = *(const bf16x8*)((const char*)wt[0] + off);
    bf16x8 bk_ = *(const bf16x8*)((const char*)wt[1] + off);
    accq = __builtin_amdgcn_mfma_f32_16x16x32_bf16(aq_, bq_, accq, 0, 0, 0);
    acck = __builtin_amdgcn_mfma_f32_16x16x32_bf16(ak_, bk_, acck, 0, 0, 0);
  }
  *(f32x4*)&red[wv][lane][0] = accq;
  *(f32x4*)&red[wv][lane][4] = acck;
  __syncthreads();
  if (tid < 64) {
    f32x4 q0 = *(const f32x4*)&red[0][tid][0];
    f32x4 k0 = *(const f32x4*)&red[0][tid][4];
#pragma unroll
    for (int w = 1; w < 4; w++) {
      q0 += *(const f32x4*)&red[w][tid][0];
      k0 += *(const f32x4*)&red[w][tid][4];
    }
    int col = tid & 15, r0 = (tid >> 4) * 4;
    float bqv = bq[col], bkv = bk[col];
#pragma unroll
    for (int i = 0; i < 4; i++) {
      qout[(tok0 + r0 + i) * 16 + col] = q0[i] + bqv;
      kout[(tok0 + r0 + i) * 16 + col] = k0[i] + bkv;
    }
  }
}

// ===== ksum: y_part[b][p][h][c] = Σ_{s in subset} σ(k[b,s,h])·x[b,s,c] ====
// grid (cc=16, sc=4, b=4), 256 thr = 4 s-subgroups × 64 cols.
// p = sc*4+sg (16 partials per b). Also spart[b][sc][h] = Σ σ(k).
__global__ __launch_bounds__(256) void ksum(const float* __restrict__ kp,
                                            const u16* __restrict__ xb,
                                            float* __restrict__ ypart,
                                            float* __restrict__ spart) {
  __shared__ float sk[256][17];
  const int tid = threadIdx.x;
  const int cc = blockIdx.x, sc = blockIdx.y, b = blockIdx.z;
  const int cl = tid & 63, sg = tid >> 6;
  const int col = cc * 64 + cl;
  float acc[16];
#pragma unroll
  for (int h = 0; h < 16; h++) acc[h] = 0.f;
  float ss = 0.f;
  for (int tile = 0; tile < 4; tile++) {
    const int s0 = sc * 1024 + tile * 256;
    const float* kr = kp + ((long)b * 4096 + s0 + tid) * 16;
#pragma unroll
    for (int p = 0; p < 4; p++) {
      float4 kv4 = *(const float4*)(kr + p * 4);
      sk[tid][p * 4 + 0] = sigmoidf_(kv4.x);
      sk[tid][p * 4 + 1] = sigmoidf_(kv4.y);
      sk[tid][p * 4 + 2] = sigmoidf_(kv4.z);
      sk[tid][p * 4 + 3] = sigmoidf_(kv4.w);
    }
    __syncthreads();
    if (tid < 16) {
      float s_ = 0.f;
      for (int i = 0; i < 256; i++) s_ += sk[i][tid];
      ss += s_;
    }
    const u16* xr = xb + ((long)b * 4096 + s0 + sg * 64) * 1024 + col;
    for (int j = 0; j < 64; j++) {
      float xv = bf2f(xr[(long)j * 1024]);
      const float* skr = sk[sg * 64 + j];
#pragma unroll
      for (int h = 0; h < 16; h++) acc[h] += skr[h] * xv;
    }
    __syncthreads();
  }
  long pbase = (long)(b * 16 + sc * 4 + sg) * 16384 + col;
#pragma unroll
  for (int h = 0; h < 16; h++) ypart[pbase + h * 1024] = acc[h];
  if (tid < 16) spart[(b * 4 + sc) * 16 + tid] = ss;
}

// ===== kv[b,h,d] = (Σ_p y_part)·wv[:,h*64+d] + (Σσ)·bv[h*64+d] ===========
// grid 64 = (b,h); 64 threads (d).
__global__ __launch_bounds__(64) void kv_small(const float* __restrict__ ypart,
                                               const float* __restrict__ spart,
                                               const float* __restrict__ wv,
                                               const float* __restrict__ bv,
                                               float* __restrict__ kv) {
  __shared__ float yl[1024];
  const int b = blockIdx.x >> 4, h = blockIdx.x & 15, d = threadIdx.x;
  for (int c = d; c < 1024; c += 64) {
    float s_ = 0.f;
    const float* yp = ypart + (long)b * 16 * 16384 + h * 1024 + c;
#pragma unroll
    for (int p = 0; p < 16; p++) s_ += yp[(long)p * 16384];
    yl[c] = s_;
  }
  __syncthreads();
  float ss = 0.f;
#pragma unroll
  for (int s_ = 0; s_ < 4; s_++) ss += spart[(b * 4 + s_) * 16 + h];
  float acc = 0.f;
  const float* wcol = wv + h * 64 + d;
  for (int c = 0; c < 1024; c++) acc += yl[c] * wcol[(long)c * 1024];
  kv[(b * 16 + h) * 64 + d] = acc + ss * bv[h * 64 + d];
}

// ---------------- cumsum over heads --------------------------------------
__global__ __launch_bounds__(64) void kv_cumsum(const float* __restrict__ kv,
                                                float* __restrict__ scum) {
  int b = blockIdx.x, d = threadIdx.x;
  float run = 0.f;
  for (int h = 0; h < 16; h++) {
    run += kv[(b * 16 + h) * 64 + d];
    scum[(b * 16 + h) * 64 + d] = run;
  }
}

// ===== z[b,h,n] = Σ_{d<64} scum[b,h,d]·wo[h*64+d, n] ; grid 64, 256 thr ===
__global__ __launch_bounds__(256) void zker(const float* __restrict__ scum,
                                            const float* __restrict__ wo,
                                            float* __restrict__ z) {
  __shared__ float sc_[64];
  const int tid = threadIdx.x;
  const int b = blockIdx.x >> 4, h = blockIdx.x & 15;
  if (tid < 64) sc_[tid] = scum[(b * 16 + h) * 64 + tid];
  __syncthreads();
  float4 acc = make_float4(0.f, 0.f, 0.f, 0.f);
  for (int d = 0; d < 64; d++) {
    float s_ = sc_[d];
    float4 w = ((const float4*)(wo + (long)(h * 64 + d) * 1024))[tid];
    acc.x += s_ * w.x; acc.y += s_ * w.y;
    acc.z += s_ * w.z; acc.w += s_ * w.w;
  }
  ((float4*)(z + (long)(b * 16 + h) * 1024))[tid] = acc;
}

// ===== fused attn-broadcast + residual + LayerNorm ========================
// row: attn = Σ_h σ(q[t,h])·z[b,h,:] + bo ; out = LN(attn + r)·g + be.
// grid 1024 (16 rows each), 256 thr; z[b] staged in LDS (64KB).
template <int OMODE>  // 1: f32 out only; 2: f32 + bf16
__global__ __launch_bounds__(256) void ln_attn(
    const float* __restrict__ qp, const float* __restrict__ z,
    const float* __restrict__ bo, const float* __restrict__ r,
    const float* __restrict__ g, const float* __restrict__ be,
    float* __restrict__ outf, u16* __restrict__ outb) {
  __shared__ float zs[16][1024];
  __shared__ float sq16[16];
  __shared__ float s1[4], s2[4];
  const int tid = threadIdx.x;
  const int b = blockIdx.x >> 8;
  const float4* zg = (const float4*)(z + (long)b * 16384);
  float4* zl = (float4*)zs;
#pragma unroll
  for (int i = 0; i < 16; i++) zl[i * 256 + tid] = zg[i * 256 + tid];
  float4 gv = ((const float4*)g)[tid];
  float4 bev = ((const float4*)be)[tid];
  float4 bov = ((const float4*)bo)[tid];
  const int wid = tid >> 6, lane = tid & 63;
  for (int rr_ = 0; rr_ < 16; rr_++) {
    long row = (long)blockIdx.x * 16 + rr_;
    if (tid < 16) sq16[tid] = sigmoidf_(qp[row * 16 + tid]);
    __syncthreads();  // covers zs staging (iter 0) and sq16
    float4 rv = ((const float4*)(r + row * 1024))[tid];
    float y0 = bov.x + rv.x, y1 = bov.y + rv.y;
    float y2 = bov.z + rv.z, y3 = bov.w + rv.w;
#pragma unroll
    for (int h = 0; h < 16; h++) {
      float s_ = sq16[h];
      float4 zv = *(const float4*)&zs[h][tid * 4];
      y0 += s_ * zv.x; y1 += s_ * zv.y; y2 += s_ * zv.z; y3 += s_ * zv.w;
    }
    float s = y0 + y1 + y2 + y3;
    float q = y0 * y0 + y1 * y1 + y2 * y2 + y3 * y3;
#pragma unroll
    for (int o = 32; o > 0; o >>= 1) {
      s += __shfl_down(s, o);
      q += __shfl_down(q, o);
    }
    if (lane == 0) { s1[wid] = s; s2[wid] = q; }
    __syncthreads();
    s = s1[0] + s1[1] + s1[2] + s1[3];
    q = s2[0] + s2[1] + s2[2] + s2[3];
    float mu = s * (1.f / 1024.f);
    float var = q * (1.f / 1024.f) - mu * mu;
    float inv = rsqrtf(fmaxf(var, 0.f) + 1e-6f);
    float o0 = gv.x * (y0 - mu) * inv + bev.x;
    float o1 = gv.y * (y1 - mu) * inv + bev.y;
    float o2 = gv.z * (y2 - mu) * inv + bev.z;
    float o3 = gv.w * (y3 - mu) * inv + bev.w;
    ((float4*)(outf + row * 1024))[tid] = make_float4(o0, o1, o2, o3);
    if (OMODE == 2) {
      uint2 ob;
      ob.x = (uint32_t)f2bf(o0) | ((uint32_t)f2bf(o1) << 16);
      ob.y = (uint32_t)f2bf(o2) | ((uint32_t)f2bf(o3) << 16);
      ((uint2*)(outb + row * 1024))[tid] = ob;
    }
    __syncthreads();  // protect sq16/s1/s2 for next row
  }
}

// ===== 256x256 MFMA GEMM — m201-discipline 4-phase/ktile (r11) ============
template <int ACT>
__global__ __launch_bounds__(512) void gemm256(
    const u16* __restrict__ A, const u16* __restrict__ BT,
    const float* __restrict__ bias, u16* __restrict__ C, int M, int N,
    int K) {
  __shared__ __attribute__((aligned(16))) u16 lds[65536];  // 128 KB
  const int tid = threadIdx.x;
  const int wid = tid >> 6, lane = tid & 63;
  const int wm = wid >> 2, wn = wid & 3;
  const int lrow = lane & 15, g = lane >> 4;

  int nwg = gridDim.x * gridDim.y;
  int orig = blockIdx.y * gridDim.x + blockIdx.x;
  int wg = (nwg & 7) ? orig : ((orig & 7) * (nwg >> 3) + (orig >> 3));
  const long bn = (long)(wg % gridDim.x) * 256;
  const long bm = (long)(wg / gridDim.x) * 256;

  const int rr = wid * 16 + (lane >> 2);
  const int esrc = ((lane & 3) * 8) ^ (((lane >> 5) & 1) * 16);
  const u16* Abase = A + (bm + rr) * (long)K + esrc;
  const u16* Bbase = BT + (bn + rr) * (long)K + esrc;
  const long jstep = (long)128 * K;
  char* ldsc = (char*)lds;
  const int ldsw = wid * 1024;

  const int swr = ((lrow >> 3) & 1) * 32;
  const int aoff = (wm * 128 + lrow) * 64 + ((g * 16) ^ swr);
  const int boff = 32768 + (wn * 64 + lrow) * 64 + ((g * 16) ^ swr);

  f32x4 acc[8][4] = {};
  const int KT = K >> 6;

  auto stage2 = [&](int buf, int kk, int kt, int half) {
    int dA = buf * 65536 + kk * 16384 + ldsw;
    if (half == 0) {
      const u16* sA = Abase + (long)kt * 64 + kk * 32;
      load_lds16(sA, ldsc + dA);
      load_lds16(sA + jstep, ldsc + dA + 8192);
    } else {
      const u16* sB = Bbase + (long)kt * 64 + kk * 32;
      load_lds16(sB, ldsc + dA + 32768);
      load_lds16(sB + jstep, ldsc + dA + 40960);
    }
  };

#define LDAB8(BUF, KK)                                                      \
  {                                                                         \
    const char* _b = ldsc + (BUF) * 65536 + (KK) * 16384;                   \
    _Pragma("unroll") for (int m = 0; m < 4; m++)                           \
        af[m] = *(const bf16x8*)(_b + aoff + m * 1024);                     \
    _Pragma("unroll") for (int n = 0; n < 4; n++)                           \
        bq[n] = *(const bf16x8*)(_b + boff + n * 1024);                     \
  }
#define LDA4(BUF, KK)                                                       \
  {                                                                         \
    const char* _b = ldsc + (BUF) * 65536 + (KK) * 16384;                   \
    _Pragma("unroll") for (int m = 4; m < 8; m++)                           \
        af[m] = *(const bf16x8*)(_b + aoff + m * 1024);                     \
  }
#define MMA16(M0)                                                           \
  __builtin_amdgcn_s_setprio(1);                                            \
  _Pragma("unroll") for (int m = M0; m < M0 + 4; m++)                       \
  _Pragma("unroll") for (int n = 0; n < 4; n++)                             \
      acc[m][n] = __builtin_amdgcn_mfma_f32_16x16x32_bf16(af[m], bq[n],     \
                                                          acc[m][n], 0, 0,  \
                                                          0);               \
  __builtin_amdgcn_s_setprio(0);
#define WLG0() asm volatile("s_waitcnt lgkmcnt(0)" ::: "memory")
#define WVM4() asm volatile("s_waitcnt vmcnt(4)" ::: "memory")
#define WVM0() asm volatile("s_waitcnt vmcnt(0)" ::: "memory")

  bf16x8 af[8], bq[4];

  stage2(0, 0, 0, 0);
  stage2(0, 0, 0, 1);
  stage2(0, 1, 0, 0);
  stage2(0, 1, 0, 1);
  WVM4();
  BAR();

  for (int kt = 0; kt + 1 < KT; ++kt) {
    const int b0 = kt & 1, b1 = b0 ^ 1;
    LDAB8(b0, 0);
    stage2(b1, 0, kt + 1, 0);
    BAR(); WLG0();
    MMA16(0);
    BAR();
    LDA4(b0, 0);
    stage2(b1, 0, kt + 1, 1);
    WVM4();
    BAR(); WLG0();
    MMA16(4);
    BAR();
    LDAB8(b0, 1);
    stage2(b1, 1, kt + 1, 0);
    BAR(); WLG0();
    MMA16(0);
    BAR();
    LDA4(b0, 1);
    stage2(b1, 1, kt + 1, 1);
    WVM4();
    BAR(); WLG0();
    MMA16(4);
    BAR();
  }
  {
    const int b0 = (KT - 1) & 1;
    LDAB8(b0, 0);
    BAR(); WLG0();
    MMA16(0);
    BAR();
    LDA4(b0, 0);
    WVM0();
    BAR(); WLG0();
    MMA16(4);
    BAR();
    LDAB8(b0, 1);
    BAR(); WLG0();
    MMA16(0);
    BAR();
    LDA4(b0, 1);
    BAR(); WLG0();
    MMA16(4);
    BAR();
  }

#pragma unroll
  for (int n = 0; n < 4; n++) {
    int cl = wn * 64 + n * 16 + lrow;
    float bb = bias[bn + cl];
#pragma unroll
    for (int m = 0; m < 8; m++) {
      int rl = wm * 128 + m * 16 + g * 4;
#pragma unroll
      for (int i = 0; i < 4; i++) {
        float v = acc[m][n][i] + bb;
        if (ACT == 1) v = fmaxf(v, 0.f);
        lds[(rl + i) * 256 + cl] = f2bf(v);
      }
    }
  }
  BAR();
  const uint4* lv = (const uint4*)lds;
#pragma unroll
  for (int it = 0; it < 16; it++) {
    int idx = it * 512 + tid;
    int row = idx >> 5;
    int cu = (idx & 31) * 8;
    *(uint4*)&C[(bm + row) * (long)N + bn + cu] = lv[idx];
  }
#undef LDAB8
#undef LDA4
#undef MMA16
#undef WLG0
#undef WVM4
#undef WVM0
}

// --- LayerNorm(a_bf16 + r_f32)*g + be -> f32 ------------------------------
__global__ __launch_bounds__(256) void ln_res(const u16* __restrict__ a,
                                              const float* __restrict__ r,
                                              const float* __restrict__ g,
                                              const float* __restrict__ be,
                                              float* __restrict__ outf) {
  long row = blockIdx.x;
  int tid = threadIdx.x;
  uint2 av = ((const uint2*)(a + row * 1024))[tid];
  float4 rv = ((const float4*)(r + row * 1024))[tid];
  float y[4];
  y[0] = bf2f((u16)(av.x & 0xffff)) + rv.x;
  y[1] = bf2f((u16)(av.x >> 16)) + rv.y;
  y[2] = bf2f((u16)(av.y & 0xffff)) + rv.z;
  y[3] = bf2f((u16)(av.y >> 16)) + rv.w;
  float s = y[0] + y[1] + y[2] + y[3];
  float q = y[0] * y[0] + y[1] * y[1] + y[2] * y[2] + y[3] * y[3];
#pragma unroll
  for (int o = 32; o > 0; o >>= 1) {
    s += __shfl_down(s, o);
    q += __shfl_down(q, o);
  }
  __shared__ float s1[4], s2[4];
  int wid = tid >> 6, lane = tid & 63;
  if (lane == 0) { s1[wid] = s; s2[wid] = q; }
  __syncthreads();
  s = s1[0] + s1[1] + s1[2] + s1[3];
  q = s2[0] + s2[1] + s2[2] + s2[3];
  float mu = s * (1.f / 1024.f);
  float var = q * (1.f / 1024.f) - mu * mu;
  float inv = rsqrtf(fmaxf(var, 0.f) + 1e-6f);
  float4 gv = ((const float4*)g)[tid], bv = ((const float4*)be)[tid];
  float o0 = gv.x * (y[0] - mu) * inv + bv.x;
  float o1 = gv.y * (y[1] - mu) * inv + bv.y;
  float o2 = gv.z * (y[2] - mu) * inv + bv.z;
  float o3 = gv.w * (y[3] - mu) * inv + bv.w;
  ((float4*)(outf + row * 1024))[tid] = make_float4(o0, o1, o2, o3);
}

extern "C" void kernel_launch(void* const* d_in, const int* in_sizes, int n_in,
                              void* d_out, int out_size, void* d_ws,
                              size_t ws_size, hipStream_t stream) {
  const float* x   = (const float*)d_in[0];
  const float* enc = (const float*)d_in[1];
  const float* wq1 = (const float*)d_in[2];  const float* bq1 = (const float*)d_in[3];
  const float* wk1 = (const float*)d_in[4];  const float* bk1 = (const float*)d_in[5];
  const float* wv1 = (const float*)d_in[6];  const float* bv1 = (const float*)d_in[7];
  const float* wo1 = (const float*)d_in[8];  const float* bo1 = (const float*)d_in[9];
  const float* wq2 = (const float*)d_in[10]; const float* bq2 = (const float*)d_in[11];
  const float* wk2 = (const float*)d_in[12]; const float* bk2 = (const float*)d_in[13];
  const float* wv2 = (const float*)d_in[14]; const float* bv2 = (const float*)d_in[15];
  const float* wo2 = (const float*)d_in[16]; const float* bo2 = (const float*)d_in[17];
  const float* wf1 = (const float*)d_in[18]; const float* bf1 = (const float*)d_in[19];
  const float* wf2 = (const float*)d_in[20]; const float* bf2 = (const float*)d_in[21];
  const float* g1 = (const float*)d_in[22];  const float* be1 = (const float*)d_in[23];
  const float* g2 = (const float*)d_in[24];  const float* be2 = (const float*)d_in[25];
  const float* g3 = (const float*)d_in[26];  const float* be3 = (const float*)d_in[27];
  (void)in_sizes; (void)n_in; (void)out_size; (void)ws_size;

  const size_t S = (size_t)16384 * 1024;  // tokens * d_model
  float* O0 = (float*)d_out;              // out3 (f32)

  char* base = (char*)d_ws;
  size_t off = 0;
  auto alloc = [&](size_t bytes) -> void* {
    void* p = base + off;
    off += (bytes + 255) & ~(size_t)255;
    return p;
  };
  u16* WT1    = (u16*)alloc((size_t)4096 * 1024 * 2);  // wf1^T bf16
  u16* WT2    = (u16*)alloc((size_t)4096 * 1024 * 2);  // wf2^T bf16
  float* qb   = (float*)alloc((size_t)16384 * 16 * 4);
  float* kb   = (float*)alloc((size_t)16384 * 16 * 4);
  float* ypart= (float*)alloc((size_t)4 * 16 * 16 * 1024 * 4);  // 4MB
  float* spart= (float*)alloc((size_t)4 * 4 * 16 * 4);
  float* kvb  = (float*)alloc((size_t)4 * 16 * 64 * 4);
  float* scm  = (float*)alloc((size_t)4 * 16 * 64 * 4);
  float* zb   = (float*)alloc((size_t)4 * 16 * 1024 * 4);       // 256KB
  u16* FA     = (u16*)alloc(S * 2);                    // bf16: ffn_out
  u16* XB     = (u16*)alloc(S * 2);                    // bf16: x / enc
  u16* FM     = (u16*)alloc((size_t)16384 * 4096 * 2); // bf16: ffn mid
  u16* O1b    = (u16*)alloc(S * 2);                    // bf16 out1
  u16* O2b    = (u16*)alloc(S * 2);                    // bf16 out2
  float* O1f  = (float*)alloc(S * 4);                  // f32 out1
  float* O2f  = (float*)alloc(S * 4);                  // f32 out2

  const int T = 16384;
  dim3 blk(256), gblk(512);

  // ---- MHA1 (q=k=v from x) ----
  cvt_f2b<<<16384, blk, 0, stream>>>(x, XB);
  proj_mfma<<<1024, blk, 0, stream>>>(XB, XB, wq1, bq1, wk1, bk1, qb, kb);
  ksum<<<dim3(16, 4, 4), blk, 0, stream>>>(kb, XB, ypart, spart);
  kv_small<<<64, 64, 0, stream>>>(ypart, spart, wv1, bv1, kvb);
  kv_cumsum<<<4, 64, 0, stream>>>(kvb, scm);
  zker<<<64, blk, 0, stream>>>(scm, wo1, zb);
  ln_attn<2><<<1024, blk, 0, stream>>>(qb, zb, bo1, x, g1, be1, O1f, O1b);

  // ---- MHA2 (q from out1, k/v from enc) ----
  cvt_f2b<<<16384, blk, 0, stream>>>(enc, XB);
  proj_mfma<<<1024, blk, 0, stream>>>(O1b, XB, wq2, bq2, wk2, bk2, qb, kb);
  ksum<<<dim3(16, 4, 4), blk, 0, stream>>>(kb, XB, ypart, spart);
  kv_small<<<64, 64, 0, stream>>>(ypart, spart, wv2, bv2, kvb);
  kv_cumsum<<<4, 64, 0, stream>>>(kvb, scm);
  zker<<<64, blk, 0, stream>>>(scm, wo2, zb);
  ln_attn<2><<<1024, blk, 0, stream>>>(qb, zb, bo2, O1f, g2, be2, O2f, O2b);

  // ---- FFN ----
  transpose_cvt<<<dim3(128, 32), blk, 0, stream>>>(wf1, WT1, 1024, 4096);
  transpose_cvt<<<dim3(32, 128), blk, 0, stream>>>(wf2, WT2, 4096, 1024);
  gemm256<1><<<dim3(16, 64), gblk, 0, stream>>>(O2b, WT1, bf1, FM, T, 4096, 1024);
  gemm256<0><<<dim3(4, 64), gblk, 0, stream>>>(FM, WT2, bf2, FA, T, 1024, 4096);
  ln_res<<<16384, blk, 0, stream>>>(FA, O2f, g3, be3, O0);  // out3

  // outputs 1 and 2 must be zeros
  hipMemsetAsync((float*)d_out + S, 0, 2 * S * 4, stream);
}

// Round 13
// 593.167 us; speedup vs baseline: 1.7715x; 1.1756x over previous
//
#include <hip/hip_runtime.h>
#include <cstdint>

typedef unsigned short u16;
typedef __bf16 bf16x8 __attribute__((ext_vector_type(8)));
typedef float f32x4 __attribute__((ext_vector_type(4)));

__device__ __forceinline__ float bf2f(u16 h) {
  union { uint32_t u; float f; } v; v.u = (uint32_t)h << 16; return v.f;
}
__device__ __forceinline__ u16 f2bf(float f) {
  union { float f; uint32_t u; } v; v.f = f;
  uint32_t r = v.u + 0x7fffu + ((v.u >> 16) & 1u);
  return (u16)(r >> 16);
}
__device__ __forceinline__ float sigmoidf_(float x) {
  return 1.0f / (1.0f + __expf(-x));
}
__device__ __forceinline__ void load_lds16(const void* g, void* l) {
  __builtin_amdgcn_global_load_lds(
      (const __attribute__((address_space(1))) void*)g,
      (__attribute__((address_space(3))) void*)l, 16, 0, 0);
}
__device__ __forceinline__ bf16x8 cvt8(const float* p) {
  float4 a = *(const float4*)p, b = *(const float4*)(p + 4);
  union { u16 u[8]; bf16x8 v; } r;
  r.u[0] = f2bf(a.x); r.u[1] = f2bf(a.y); r.u[2] = f2bf(a.z); r.u[3] = f2bf(a.w);
  r.u[4] = f2bf(b.x); r.u[5] = f2bf(b.y); r.u[6] = f2bf(b.z); r.u[7] = f2bf(b.w);
  return r.v;
}
#define BAR() __builtin_amdgcn_s_barrier()

// ------------- transpose+convert: in f32 [K][N] -> out bf16 [N][K] -------
__global__ __launch_bounds__(256) void transpose_cvt(
    const float* __restrict__ in, u16* __restrict__ out, int K, int N) {
  __shared__ float t[32][33];
  int n0 = blockIdx.x * 32, k0 = blockIdx.y * 32;
  int tx = threadIdx.x & 31, ty = threadIdx.x >> 5;
#pragma unroll
  for (int i = 0; i < 32; i += 8)
    t[ty + i][tx] = in[(long)(k0 + ty + i) * N + n0 + tx];
  __syncthreads();
#pragma unroll
  for (int i = 0; i < 32; i += 8)
    out[(long)(n0 + ty + i) * K + k0 + tx] = f2bf(t[tx][ty + i]);
}

// ===== MFMA projection: q = xq@wq+bq, k = xk@wk+bk ; [T,1024]->[T,16]x2 ===
// QBF=1: xq is bf16 (u16*); else f32. xk always f32 (converted in-register).
template <int QBF>
__global__ __launch_bounds__(256) void proj_mfma(
    const void* __restrict__ xq_, const float* __restrict__ xk,
    const float* __restrict__ wq, const float* __restrict__ bq,
    const float* __restrict__ wk, const float* __restrict__ bk,
    float* __restrict__ qout, float* __restrict__ kout) {
  __shared__ __attribute__((aligned(16))) u16 wt[2][16384];  // 64KB
  __shared__ __attribute__((aligned(16))) float red[4][64][8];
  const int tid = threadIdx.x;
  for (int kq = 0; kq < 4; kq++) {
    int k = kq * 256 + tid;
    const float4* q4 = (const float4*)(wq + (long)k * 16);
    const float4* k4 = (const float4*)(wk + (long)k * 16);
#pragma unroll
    for (int p = 0; p < 4; p++) {
      float4 qv = q4[p], kv = k4[p];
      float qf[4] = {qv.x, qv.y, qv.z, qv.w};
      float kf[4] = {kv.x, kv.y, kv.z, kv.w};
#pragma unroll
      for (int j = 0; j < 4; j++) {
        int c = p * 4 + j;
        int off = (c * 2048 + k * 2) ^ ((c & 7) << 4);
        *(u16*)((char*)wt[0] + off) = f2bf(qf[j]);
        *(u16*)((char*)wt[1] + off) = f2bf(kf[j]);
      }
    }
  }
  __syncthreads();
  const int wv = tid >> 6, lane = tid & 63;
  const int lrow = lane & 15, g = lane >> 4;
  const long tok0 = (long)blockIdx.x * 16;
  const long arow = (tok0 + lrow) * 1024 + wv * 256 + g * 8;
  const int swz = (lrow & 7) << 4;
  const int wbase = lrow * 2048 + wv * 512 + g * 16;
  f32x4 accq = {}, acck = {};
#pragma unroll
  for (int mf = 0; mf < 8; mf++) {
    bf16x8 aq_;
    if (QBF)
      aq_ = *(const bf16x8*)((const u16*)xq_ + arow + mf * 32);
    else
      aq_ = cvt8((const float*)xq_ + arow + mf * 32);
    bf16x8 ak_ = cvt8(xk + arow + mf * 32);
    int off = (wbase + mf * 64) ^ swz;
    bf16x8 bq_ = *(const bf16x8*)((const char*)wt[0] + off);
    bf16x8 bk_ = *(const bf16x8*)((const char*)wt[1] + off);
    accq = __builtin_amdgcn_mfma_f32_16x16x32_bf16(aq_, bq_, accq, 0, 0, 0);
    acck = __builtin_amdgcn_mfma_f32_16x16x32_bf16(ak_, bk_, acck, 0, 0, 0);
  }
  *(f32x4*)&red[wv][lane][0] = accq;
  *(f32x4*)&red[wv][lane][4] = acck;
  __syncthreads();
  if (tid < 64) {
    f32x4 q0 = *(const f32x4*)&red[0][tid][0];
    f32x4 k0 = *(const f32x4*)&red[0][tid][4];
#pragma unroll
    for (int w = 1; w < 4; w++) {
      q0 += *(const f32x4*)&red[w][tid][0];
      k0 += *(const f32x4*)&red[w][tid][4];
    }
    int col = tid & 15, r0 = (tid >> 4) * 4;
    float bqv = bq[col], bkv = bk[col];
#pragma unroll
    for (int i = 0; i < 4; i++) {
      qout[(tok0 + r0 + i) * 16 + col] = q0[i] + bqv;
      kout[(tok0 + r0 + i) * 16 + col] = k0[i] + bkv;
    }
  }
}

// ===== ksum v2: y_part[b][p][h][c] = Σ_{s in chunk} σ(k[b,s,h])·x[b,s,c] ==
// grid (cc=8, sc=8, b=4) = 256 blocks, 256 thr = 4 sg × 64 lanes.
// Each thread: 2 cols (col0, col0+64); sk read as float4 ([256][20] pad for
// 16B align); ss reduced in parallel via ssl. p = sc*4+sg (32 partials/b).
__global__ __launch_bounds__(256) void ksum(const float* __restrict__ kp,
                                            const float* __restrict__ x,
                                            float* __restrict__ ypart,
                                            float* __restrict__ spart) {
  __shared__ __attribute__((aligned(16))) float sk[256][20];
  __shared__ float ssl[16][17];
  const int tid = threadIdx.x;
  const int cc = blockIdx.x, sc = blockIdx.y, b = blockIdx.z;
  const int cl = tid & 63, sg = tid >> 6;
  const int col0 = cc * 128 + cl;
  float acc0[16], acc1[16];
#pragma unroll
  for (int h = 0; h < 16; h++) { acc0[h] = 0.f; acc1[h] = 0.f; }
  float ss = 0.f;
  for (int tile = 0; tile < 2; tile++) {
    const int s0 = sc * 512 + tile * 256;
    const float* kr = kp + ((long)b * 4096 + s0 + tid) * 16;
#pragma unroll
    for (int p = 0; p < 4; p++) {
      float4 k4 = *(const float4*)(kr + p * 4);
      *(float4*)&sk[tid][p * 4] = make_float4(
          sigmoidf_(k4.x), sigmoidf_(k4.y), sigmoidf_(k4.z), sigmoidf_(k4.w));
    }
    __syncthreads();
    {  // parallel column-sum of sk into ssl
      int g2 = tid >> 4, h2 = tid & 15;
      float s_ = 0.f;
#pragma unroll
      for (int i = 0; i < 16; i++) s_ += sk[g2 * 16 + i][h2];
      ssl[g2][h2] = s_;
    }
    __syncthreads();
    if (tid < 16) {
      float s_ = 0.f;
#pragma unroll
      for (int gg = 0; gg < 16; gg++) s_ += ssl[gg][tid];
      ss += s_;
    }
    const float* xr = x + ((long)b * 4096 + s0 + sg * 64) * 1024 + col0;
    for (int j = 0; j < 64; j++) {
      float xv0 = xr[(long)j * 1024];
      float xv1 = xr[(long)j * 1024 + 64];
      const float4* skr = (const float4*)sk[sg * 64 + j];
#pragma unroll
      for (int p = 0; p < 4; p++) {
        float4 s4 = skr[p];
        acc0[p * 4 + 0] += s4.x * xv0; acc1[p * 4 + 0] += s4.x * xv1;
        acc0[p * 4 + 1] += s4.y * xv0; acc1[p * 4 + 1] += s4.y * xv1;
        acc0[p * 4 + 2] += s4.z * xv0; acc1[p * 4 + 2] += s4.z * xv1;
        acc0[p * 4 + 3] += s4.w * xv0; acc1[p * 4 + 3] += s4.w * xv1;
      }
    }
    __syncthreads();
  }
  long pbase = (long)(b * 32 + sc * 4 + sg) * 16384 + col0;
#pragma unroll
  for (int h = 0; h < 16; h++) {
    ypart[pbase + h * 1024] = acc0[h];
    ypart[pbase + h * 1024 + 64] = acc1[h];
  }
  if (tid < 16) spart[(b * 8 + sc) * 16 + tid] = ss;
}

// ===== kv[b,h,d] = (Σ_p y_part)·wv[:,h*64+d] + (Σσ)·bv[h*64+d] ===========
// grid 64 = (b,h); 256 threads, wave-split K.
__global__ __launch_bounds__(256) void kv_small(
    const float* __restrict__ ypart, const float* __restrict__ spart,
    const float* __restrict__ wvw, const float* __restrict__ bv,
    float* __restrict__ kv) {
  __shared__ float yl[1024];
  __shared__ float red[4][64];
  const int tid = threadIdx.x;
  const int b = blockIdx.x >> 4, h = blockIdx.x & 15;
  for (int c = tid; c < 1024; c += 256) {
    float s_ = 0.f;
    const float* yp = ypart + (long)(b * 32) * 16384 + h * 1024 + c;
#pragma unroll
    for (int p = 0; p < 32; p++) s_ += yp[(long)p * 16384];
    yl[c] = s_;
  }
  __syncthreads();
  const int wv_ = tid >> 6, d = tid & 63;
  float acc = 0.f;
  const float* wcol = wvw + h * 64 + d;
  for (int c = wv_ * 256; c < wv_ * 256 + 256; c++)
    acc += yl[c] * wcol[(long)c * 1024];
  red[wv_][d] = acc;
  __syncthreads();
  if (tid < 64) {
    float ss = 0.f;
#pragma unroll
    for (int s_ = 0; s_ < 8; s_++) ss += spart[(b * 8 + s_) * 16 + h];
    kv[(b * 16 + h) * 64 + tid] = red[0][tid] + red[1][tid] + red[2][tid] +
                                  red[3][tid] + ss * bv[h * 64 + tid];
  }
}

// ===== z[b,h,n] = Σ_d cumsum_h(kv)[b,h,d]·wo[h*64+d, n]  (cumsum fused) ===
__global__ __launch_bounds__(256) void zker(const float* __restrict__ kvb,
                                            const float* __restrict__ wo,
                                            float* __restrict__ z) {
  __shared__ float sc_[64];
  const int tid = threadIdx.x;
  const int b = blockIdx.x >> 4, h = blockIdx.x & 15;
  if (tid < 64) {
    float run = 0.f;
    for (int hh = 0; hh <= h; hh++) run += kvb[(b * 16 + hh) * 64 + tid];
    sc_[tid] = run;
  }
  __syncthreads();
  float4 acc = make_float4(0.f, 0.f, 0.f, 0.f);
  for (int d = 0; d < 64; d++) {
    float s_ = sc_[d];
    float4 w = ((const float4*)(wo + (long)(h * 64 + d) * 1024))[tid];
    acc.x += s_ * w.x; acc.y += s_ * w.y;
    acc.z += s_ * w.z; acc.w += s_ * w.w;
  }
  ((float4*)(z + (long)(b * 16 + h) * 1024))[tid] = acc;
}

// ===== fused attn-broadcast + residual + LayerNorm ========================
template <int OMODE>  // 1: f32 out only; 2: f32 + bf16
__global__ __launch_bounds__(256) void ln_attn(
    const float* __restrict__ qp, const float* __restrict__ z,
    const float* __restrict__ bo, const float* __restrict__ r,
    const float* __restrict__ g, const float* __restrict__ be,
    float* __restrict__ outf, u16* __restrict__ outb) {
  __shared__ float zs[16][1024];
  __shared__ float sq16[16];
  __shared__ float s1[4], s2[4];
  const int tid = threadIdx.x;
  const int b = blockIdx.x >> 8;
  const float4* zg = (const float4*)(z + (long)b * 16384);
  float4* zl = (float4*)zs;
#pragma unroll
  for (int i = 0; i < 16; i++) zl[i * 256 + tid] = zg[i * 256 + tid];
  float4 gv = ((const float4*)g)[tid];
  float4 bev = ((const float4*)be)[tid];
  float4 bov = ((const float4*)bo)[tid];
  const int wid = tid >> 6, lane = tid & 63;
  for (int rr_ = 0; rr_ < 16; rr_++) {
    long row = (long)blockIdx.x * 16 + rr_;
    if (tid < 16) sq16[tid] = sigmoidf_(qp[row * 16 + tid]);
    __syncthreads();
    float4 rv = ((const float4*)(r + row * 1024))[tid];
    float y0 = bov.x + rv.x, y1 = bov.y + rv.y;
    float y2 = bov.z + rv.z, y3 = bov.w + rv.w;
#pragma unroll
    for (int h = 0; h < 16; h++) {
      float s_ = sq16[h];
      float4 zv = *(const float4*)&zs[h][tid * 4];
      y0 += s_ * zv.x; y1 += s_ * zv.y; y2 += s_ * zv.z; y3 += s_ * zv.w;
    }
    float s = y0 + y1 + y2 + y3;
    float q = y0 * y0 + y1 * y1 + y2 * y2 + y3 * y3;
#pragma unroll
    for (int o = 32; o > 0; o >>= 1) {
      s += __shfl_down(s, o);
      q += __shfl_down(q, o);
    }
    if (lane == 0) { s1[wid] = s; s2[wid] = q; }
    __syncthreads();
    s = s1[0] + s1[1] + s1[2] + s1[3];
    q = s2[0] + s2[1] + s2[2] + s2[3];
    float mu = s * (1.f / 1024.f);
    float var = q * (1.f / 1024.f) - mu * mu;
    float inv = rsqrtf(fmaxf(var, 0.f) + 1e-6f);
    float o0 = gv.x * (y0 - mu) * inv + bev.x;
    float o1 = gv.y * (y1 - mu) * inv + bev.y;
    float o2 = gv.z * (y2 - mu) * inv + bev.z;
    float o3 = gv.w * (y3 - mu) * inv + bev.w;
    ((float4*)(outf + row * 1024))[tid] = make_float4(o0, o1, o2, o3);
    if (OMODE == 2) {
      uint2 ob;
      ob.x = (uint32_t)f2bf(o0) | ((uint32_t)f2bf(o1) << 16);
      ob.y = (uint32_t)f2bf(o2) | ((uint32_t)f2bf(o3) << 16);
      ((uint2*)(outb + row * 1024))[tid] = ob;
    }
    __syncthreads();
  }
}

// ===== 256x256 MFMA GEMM — m201-discipline 4-phase/ktile (r11) ============
template <int ACT>
__global__ __launch_bounds__(512) void gemm256(
    const u16* __restrict__ A, const u16* __restrict__ BT,
    const float* __restrict__ bias, u16* __restrict__ C, int M, int N,
    int K) {
  __shared__ __attribute__((aligned(16))) u16 lds[65536];  // 128 KB
  const int tid = threadIdx.x;
  const int wid = tid >> 6, lane = tid & 63;
  const int wm = wid >> 2, wn = wid & 3;
  const int lrow = lane & 15, g = lane >> 4;

  int nwg = gridDim.x * gridDim.y;
  int orig = blockIdx.y * gridDim.x + blockIdx.x;
  int wg = (nwg & 7) ? orig : ((orig & 7) * (nwg >> 3) + (orig >> 3));
  const long bn = (long)(wg % gridDim.x) * 256;
  const long bm = (long)(wg / gridDim.x) * 256;

  const int rr = wid * 16 + (lane >> 2);
  const int esrc = ((lane & 3) * 8) ^ (((lane >> 5) & 1) * 16);
  const u16* Abase = A + (bm + rr) * (long)K + esrc;
  const u16* Bbase = BT + (bn + rr) * (long)K + esrc;
  const long jstep = (long)128 * K;
  char* ldsc = (char*)lds;
  const int ldsw = wid * 1024;

  const int swr = ((lrow >> 3) & 1) * 32;
  const int aoff = (wm * 128 + lrow) * 64 + ((g * 16) ^ swr);
  const int boff = 32768 + (wn * 64 + lrow) * 64 + ((g * 16) ^ swr);

  f32x4 acc[8][4] = {};
  const int KT = K >> 6;

  auto stage2 = [&](int buf, int kk, int kt, int half) {
    int dA = buf * 65536 + kk * 16384 + ldsw;
    if (half == 0) {
      const u16* sA = Abase + (long)kt * 64 + kk * 32;
      load_lds16(sA, ldsc + dA);
      load_lds16(sA + jstep, ldsc + dA + 8192);
    } else {
      const u16* sB = Bbase + (long)kt * 64 + kk * 32;
      load_lds16(sB, ldsc + dA + 32768);
      load_lds16(sB + jstep, ldsc + dA + 40960);
    }
  };

#define LDAB8(BUF, KK)                                                      \
  {                                                                         \
    const char* _b = ldsc + (BUF) * 65536 + (KK) * 16384;                   \
    _Pragma("unroll") for (int m = 0; m < 4; m++)                           \
        af[m] = *(const bf16x8*)(_b + aoff + m * 1024);                     \
    _Pragma("unroll") for (int n = 0; n < 4; n++)                           \
        bq[n] = *(const bf16x8*)(_b + boff + n * 1024);                     \
  }
#define LDA4(BUF, KK)                                                       \
  {                                                                         \
    const char* _b = ldsc + (BUF) * 65536 + (KK) * 16384;                   \
    _Pragma("unroll") for (int m = 4; m < 8; m++)                           \
        af[m] = *(const bf16x8*)(_b + aoff + m * 1024);                     \
  }
#define MMA16(M0)                                                           \
  __builtin_amdgcn_s_setprio(1);                                            \
  _Pragma("unroll") for (int m = M0; m < M0 + 4; m++)                       \
  _Pragma("unroll") for (int n = 0; n < 4; n++)                             \
      acc[m][n] = __builtin_amdgcn_mfma_f32_16x16x32_bf16(af[m], bq[n],     \
                                                          acc[m][n], 0, 0,  \
                                                          0);               \
  __builtin_amdgcn_s_setprio(0);
#define WLG0() asm volatile("s_waitcnt lgkmcnt(0)" ::: "memory")
#define WVM4() asm volatile("s_waitcnt vmcnt(4)" ::: "memory")
#define WVM0() asm volatile("s_waitcnt vmcnt(0)" ::: "memory")

  bf16x8 af[8], bq[4];

  stage2(0, 0, 0, 0);
  stage2(0, 0, 0, 1);
  stage2(0, 1, 0, 0);
  stage2(0, 1, 0, 1);
  WVM4();
  BAR();

  for (int kt = 0; kt + 1 < KT; ++kt) {
    const int b0 = kt & 1, b1 = b0 ^ 1;
    LDAB8(b0, 0);
    stage2(b1, 0, kt + 1, 0);
    BAR(); WLG0();
    MMA16(0);
    BAR();
    LDA4(b0, 0);
    stage2(b1, 0, kt + 1, 1);
    WVM4();
    BAR(); WLG0();
    MMA16(4);
    BAR();
    LDAB8(b0, 1);
    stage2(b1, 1, kt + 1, 0);
    BAR(); WLG0();
    MMA16(0);
    BAR();
    LDA4(b0, 1);
    stage2(b1, 1, kt + 1, 1);
    WVM4();
    BAR(); WLG0();
    MMA16(4);
    BAR();
  }
  {
    const int b0 = (KT - 1) & 1;
    LDAB8(b0, 0);
    BAR(); WLG0();
    MMA16(0);
    BAR();
    LDA4(b0, 0);
    WVM0();
    BAR(); WLG0();
    MMA16(4);
    BAR();
    LDAB8(b0, 1);
    BAR(); WLG0();
    MMA16(0);
    BAR();
    LDA4(b0, 1);
    BAR(); WLG0();
    MMA16(4);
    BAR();
  }

#pragma unroll
  for (int n = 0; n < 4; n++) {
    int cl = wn * 64 + n * 16 + lrow;
    float bb = bias[bn + cl];
#pragma unroll
    for (int m = 0; m < 8; m++) {
      int rl = wm * 128 + m * 16 + g * 4;
#pragma unroll
      for (int i = 0; i < 4; i++) {
        float v = acc[m][n][i] + bb;
        if (ACT == 1) v = fmaxf(v, 0.f);
        lds[(rl + i) * 256 + cl] = f2bf(v);
      }
    }
  }
  BAR();
  const uint4* lv = (const uint4*)lds;
#pragma unroll
  for (int it = 0; it < 16; it++) {
    int idx = it * 512 + tid;
    int row = idx >> 5;
    int cu = (idx & 31) * 8;
    *(uint4*)&C[(bm + row) * (long)N + bn + cu] = lv[idx];
  }
#undef LDAB8
#undef LDA4
#undef MMA16
#undef WLG0
#undef WVM4
#undef WVM0
}

// --- LayerNorm(a_bf16 + r_f32)*g + be -> f32 ------------------------------
__global__ __launch_bounds__(256) void ln_res(const u16* __restrict__ a,
                                              const float* __restrict__ r,
                                              const float* __restrict__ g,
                                              const float* __restrict__ be,
                                              float* __restrict__ outf) {
  long row = blockIdx.x;
  int tid = threadIdx.x;
  uint2 av = ((const uint2*)(a + row * 1024))[tid];
  float4 rv = ((const float4*)(r + row * 1024))[tid];
  float y[4];
  y[0] = bf2f((u16)(av.x & 0xffff)) + rv.x;
  y[1] = bf2f((u16)(av.x >> 16)) + rv.y;
  y[2] = bf2f((u16)(av.y & 0xffff)) + rv.z;
  y[3] = bf2f((u16)(av.y >> 16)) + rv.w;
  float s = y[0] + y[1] + y[2] + y[3];
  float q = y[0] * y[0] + y[1] * y[1] + y[2] * y[2] + y[3] * y[3];
#pragma unroll
  for (int o = 32; o > 0; o >>= 1) {
    s += __shfl_down(s, o);
    q += __shfl_down(q, o);
  }
  __shared__ float s1[4], s2[4];
  int wid = tid >> 6, lane = tid & 63;
  if (lane == 0) { s1[wid] = s; s2[wid] = q; }
  __syncthreads();
  s = s1[0] + s1[1] + s1[2] + s1[3];
  q = s2[0] + s2[1] + s2[2] + s2[3];
  float mu = s * (1.f / 1024.f);
  float var = q * (1.f / 1024.f) - mu * mu;
  float inv = rsqrtf(fmaxf(var, 0.f) + 1e-6f);
  float4 gv = ((const float4*)g)[tid], bv = ((const float4*)be)[tid];
  float o0 = gv.x * (y[0] - mu) * inv + bv.x;
  float o1 = gv.y * (y[1] - mu) * inv + bv.y;
  float o2 = gv.z * (y[2] - mu) * inv + bv.z;
  float o3 = gv.w * (y[3] - mu) * inv + bv.w;
  ((float4*)(outf + row * 1024))[tid] = make_float4(o0, o1, o2, o3);
}

extern "C" void kernel_launch(void* const* d_in, const int* in_sizes, int n_in,
                              void* d_out, int out_size, void* d_ws,
                              size_t ws_size, hipStream_t stream) {
  const float* x   = (const float*)d_in[0];
  const float* enc = (const float*)d_in[1];
  const float* wq1 = (const float*)d_in[2];  const float* bq1 = (const float*)d_in[3];
  const float* wk1 = (const float*)d_in[4];  const float* bk1 = (const float*)d_in[5];
  const float* wv1 = (const float*)d_in[6];  const float* bv1 = (const float*)d_in[7];
  const float* wo1 = (const float*)d_in[8];  const float* bo1 = (const float*)d_in[9];
  const float* wq2 = (const float*)d_in[10]; const float* bq2 = (const float*)d_in[11];
  const float* wk2 = (const float*)d_in[12]; const float* bk2 = (const float*)d_in[13];
  const float* wv2 = (const float*)d_in[14]; const float* bv2 = (const float*)d_in[15];
  const float* wo2 = (const float*)d_in[16]; const float* bo2 = (const float*)d_in[17];
  const float* wf1 = (const float*)d_in[18]; const float* bf1 = (const float*)d_in[19];
  const float* wf2 = (const float*)d_in[20]; const float* bf2 = (const float*)d_in[21];
  const float* g1 = (const float*)d_in[22];  const float* be1 = (const float*)d_in[23];
  const float* g2 = (const float*)d_in[24];  const float* be2 = (const float*)d_in[25];
  const float* g3 = (const float*)d_in[26];  const float* be3 = (const float*)d_in[27];
  (void)in_sizes; (void)n_in; (void)out_size; (void)ws_size;

  const size_t S = (size_t)16384 * 1024;  // tokens * d_model
  float* O0 = (float*)d_out;              // out3 (f32)

  char* base = (char*)d_ws;
  size_t off = 0;
  auto alloc = [&](size_t bytes) -> void* {
    void* p = base + off;
    off += (bytes + 255) & ~(size_t)255;
    return p;
  };
  u16* WT1    = (u16*)alloc((size_t)4096 * 1024 * 2);  // wf1^T bf16
  u16* WT2    = (u16*)alloc((size_t)4096 * 1024 * 2);  // wf2^T bf16
  float* qb   = (float*)alloc((size_t)16384 * 16 * 4);
  float* kb   = (float*)alloc((size_t)16384 * 16 * 4);
  float* ypart= (float*)alloc((size_t)4 * 32 * 16 * 1024 * 4);  // 8MB
  float* spart= (float*)alloc((size_t)4 * 8 * 16 * 4);
  float* kvb  = (float*)alloc((size_t)4 * 16 * 64 * 4);
  float* zb   = (float*)alloc((size_t)4 * 16 * 1024 * 4);       // 256KB
  u16* FA     = (u16*)alloc(S * 2);                    // bf16: ffn_out
  u16* FM     = (u16*)alloc((size_t)16384 * 4096 * 2); // bf16: ffn mid
  u16* O1b    = (u16*)alloc(S * 2);                    // bf16 out1
  u16* O2b    = (u16*)alloc(S * 2);                    // bf16 out2
  float* O1f  = (float*)alloc(S * 4);                  // f32 out1
  float* O2f  = (float*)alloc(S * 4);                  // f32 out2

  const int T = 16384;
  dim3 blk(256), gblk(512);

  // ---- MHA1 (q=k=v from x, all f32 reads) ----
  proj_mfma<0><<<1024, blk, 0, stream>>>(x, x, wq1, bq1, wk1, bk1, qb, kb);
  ksum<<<dim3(8, 8, 4), blk, 0, stream>>>(kb, x, ypart, spart);
  kv_small<<<64, blk, 0, stream>>>(ypart, spart, wv1, bv1, kvb);
  zker<<<64, blk, 0, stream>>>(kvb, wo1, zb);
  ln_attn<2><<<1024, blk, 0, stream>>>(qb, zb, bo1, x, g1, be1, O1f, O1b);

  // ---- MHA2 (q from out1 bf16, k/v from enc f32) ----
  proj_mfma<1><<<1024, blk, 0, stream>>>(O1b, enc, wq2, bq2, wk2, bk2, qb, kb);
  ksum<<<dim3(8, 8, 4), blk, 0, stream>>>(kb, enc, ypart, spart);
  kv_small<<<64, blk, 0, stream>>>(ypart, spart, wv2, bv2, kvb);
  zker<<<64, blk, 0, stream>>>(kvb, wo2, zb);
  ln_attn<2><<<1024, blk, 0, stream>>>(qb, zb, bo2, O1f, g2, be2, O2f, O2b);

  // ---- FFN ----
  transpose_cvt<<<dim3(128, 32), blk, 0, stream>>>(wf1, WT1, 1024, 4096);
  transpose_cvt<<<dim3(32, 128), blk, 0, stream>>>(wf2, WT2, 4096, 1024);
  gemm256<1><<<dim3(16, 64), gblk, 0, stream>>>(O2b, WT1, bf1, FM, T, 4096, 1024);
  gemm256<0><<<dim3(4, 64), gblk, 0, stream>>>(FM, WT2, bf2, FA, T, 1024, 4096);
  ln_res<<<16384, blk, 0, stream>>>(FA, O2f, g3, be3, O0);  // out3

  // outputs 1 and 2 must be zeros
  hipMemsetAsync((float*)d_out + S, 0, 2 * S * 4, stream);
}

// Round 14
// 593.138 us; speedup vs baseline: 1.7716x; 1.0000x over previous
//
#include <hip/hip_runtime.h>
#include <cstdint>

typedef unsigned short u16;
typedef __bf16 bf16x8 __attribute__((ext_vector_type(8)));
typedef float f32x4 __attribute__((ext_vector_type(4)));

__device__ __forceinline__ float bf2f(u16 h) {
  union { uint32_t u; float f; } v; v.u = (uint32_t)h << 16; return v.f;
}
__device__ __forceinline__ u16 f2bf(float f) {
  union { float f; uint32_t u; } v; v.f = f;
  uint32_t r = v.u + 0x7fffu + ((v.u >> 16) & 1u);
  return (u16)(r >> 16);
}
__device__ __forceinline__ float sigmoidf_(float x) {
  return 1.0f / (1.0f + __expf(-x));
}
__device__ __forceinline__ void load_lds16(const void* g, void* l) {
  __builtin_amdgcn_global_load_lds(
      (const __attribute__((address_space(1))) void*)g,
      (__attribute__((address_space(3))) void*)l, 16, 0, 0);
}
__device__ __forceinline__ bf16x8 cvt8(const float* p) {
  float4 a = *(const float4*)p, b = *(const float4*)(p + 4);
  union { u16 u[8]; bf16x8 v; } r;
  r.u[0] = f2bf(a.x); r.u[1] = f2bf(a.y); r.u[2] = f2bf(a.z); r.u[3] = f2bf(a.w);
  r.u[4] = f2bf(b.x); r.u[5] = f2bf(b.y); r.u[6] = f2bf(b.z); r.u[7] = f2bf(b.w);
  return r.v;
}
#define BAR() __builtin_amdgcn_s_barrier()

// ------------- transpose+convert: in f32 [K][N] -> out bf16 [N][K] -------
__global__ __launch_bounds__(256) void transpose_cvt(
    const float* __restrict__ in, u16* __restrict__ out, int K, int N) {
  __shared__ float t[32][33];
  int n0 = blockIdx.x * 32, k0 = blockIdx.y * 32;
  int tx = threadIdx.x & 31, ty = threadIdx.x >> 5;
#pragma unroll
  for (int i = 0; i < 32; i += 8)
    t[ty + i][tx] = in[(long)(k0 + ty + i) * N + n0 + tx];
  __syncthreads();
#pragma unroll
  for (int i = 0; i < 32; i += 8)
    out[(long)(n0 + ty + i) * K + k0 + tx] = f2bf(t[tx][ty + i]);
}

// ===== MFMA projection v2: q = xq@wq+bq, k = xk@wk+bk ; [T,1024]->[T,16]x2
// grid T/64; 256 thr = 4 waves; wave w owns tokens blk*64+w*16..+16 over
// FULL K=1024 (32 MFMA per matrix, accumulate in-register; no cross-wave
// reduce). Weights staged transposed+swizzled in LDS once per block.
// SAME=1: xk ignored, A-frag shared (MHA1). QBF=1: xq is bf16.
template <int SAME, int QBF>
__global__ __launch_bounds__(256) void proj_mfma(
    const void* __restrict__ xq_, const float* __restrict__ xk,
    const float* __restrict__ wq, const float* __restrict__ bq,
    const float* __restrict__ wk, const float* __restrict__ bk,
    float* __restrict__ qout, float* __restrict__ kout) {
  __shared__ __attribute__((aligned(16))) u16 wt[2][16384];  // 64KB
  const int tid = threadIdx.x;
  for (int kq = 0; kq < 4; kq++) {
    int k = kq * 256 + tid;
    const float4* q4 = (const float4*)(wq + (long)k * 16);
    const float4* k4 = (const float4*)(wk + (long)k * 16);
#pragma unroll
    for (int p = 0; p < 4; p++) {
      float4 qv = q4[p], kv = k4[p];
      float qf[4] = {qv.x, qv.y, qv.z, qv.w};
      float kf[4] = {kv.x, kv.y, kv.z, kv.w};
#pragma unroll
      for (int j = 0; j < 4; j++) {
        int c = p * 4 + j;
        int off = (c * 2048 + k * 2) ^ ((c & 7) << 4);
        *(u16*)((char*)wt[0] + off) = f2bf(qf[j]);
        *(u16*)((char*)wt[1] + off) = f2bf(kf[j]);
      }
    }
  }
  __syncthreads();
  const int wv = tid >> 6, lane = tid & 63;
  const int lrow = lane & 15, g = lane >> 4;
  const long tok0 = (long)blockIdx.x * 64 + wv * 16;
  const int swz = (lrow & 7) << 4;
  const long arow = (tok0 + lrow) * 1024 + g * 8;
  f32x4 accq = {}, acck = {};
#pragma unroll 8
  for (int ks = 0; ks < 32; ks++) {
    bf16x8 aq_;
    if (QBF)
      aq_ = *(const bf16x8*)((const u16*)xq_ + arow + ks * 32);
    else
      aq_ = cvt8((const float*)xq_ + arow + ks * 32);
    bf16x8 ak_;
    if (SAME)
      ak_ = aq_;
    else
      ak_ = cvt8(xk + arow + ks * 32);
    int off = (lrow * 2048 + ks * 64 + g * 16) ^ swz;
    bf16x8 bq_ = *(const bf16x8*)((const char*)wt[0] + off);
    bf16x8 bk_ = *(const bf16x8*)((const char*)wt[1] + off);
    accq = __builtin_amdgcn_mfma_f32_16x16x32_bf16(aq_, bq_, accq, 0, 0, 0);
    acck = __builtin_amdgcn_mfma_f32_16x16x32_bf16(ak_, bk_, acck, 0, 0, 0);
  }
  const int col = lrow, r0 = g * 4;
  float bqv = bq[col], bkv = bk[col];
#pragma unroll
  for (int i = 0; i < 4; i++) {
    qout[(tok0 + r0 + i) * 16 + col] = accq[i] + bqv;
    kout[(tok0 + r0 + i) * 16 + col] = acck[i] + bkv;
  }
}

// ===== ksum: y_part[b][p][h][c] = Σ_{s in chunk} σ(k[b,s,h])·x[b,s,c] ====
__global__ __launch_bounds__(256) void ksum(const float* __restrict__ kp,
                                            const float* __restrict__ x,
                                            float* __restrict__ ypart,
                                            float* __restrict__ spart) {
  __shared__ __attribute__((aligned(16))) float sk[256][20];
  __shared__ float ssl[16][17];
  const int tid = threadIdx.x;
  const int cc = blockIdx.x, sc = blockIdx.y, b = blockIdx.z;
  const int cl = tid & 63, sg = tid >> 6;
  const int col0 = cc * 128 + cl;
  float acc0[16], acc1[16];
#pragma unroll
  for (int h = 0; h < 16; h++) { acc0[h] = 0.f; acc1[h] = 0.f; }
  float ss = 0.f;
  for (int tile = 0; tile < 2; tile++) {
    const int s0 = sc * 512 + tile * 256;
    const float* kr = kp + ((long)b * 4096 + s0 + tid) * 16;
#pragma unroll
    for (int p = 0; p < 4; p++) {
      float4 k4 = *(const float4*)(kr + p * 4);
      *(float4*)&sk[tid][p * 4] = make_float4(
          sigmoidf_(k4.x), sigmoidf_(k4.y), sigmoidf_(k4.z), sigmoidf_(k4.w));
    }
    __syncthreads();
    {
      int g2 = tid >> 4, h2 = tid & 15;
      float s_ = 0.f;
#pragma unroll
      for (int i = 0; i < 16; i++) s_ += sk[g2 * 16 + i][h2];
      ssl[g2][h2] = s_;
    }
    __syncthreads();
    if (tid < 16) {
      float s_ = 0.f;
#pragma unroll
      for (int gg = 0; gg < 16; gg++) s_ += ssl[gg][tid];
      ss += s_;
    }
    const float* xr = x + ((long)b * 4096 + s0 + sg * 64) * 1024 + col0;
    for (int j = 0; j < 64; j++) {
      float xv0 = xr[(long)j * 1024];
      float xv1 = xr[(long)j * 1024 + 64];
      const float4* skr = (const float4*)sk[sg * 64 + j];
#pragma unroll
      for (int p = 0; p < 4; p++) {
        float4 s4 = skr[p];
        acc0[p * 4 + 0] += s4.x * xv0; acc1[p * 4 + 0] += s4.x * xv1;
        acc0[p * 4 + 1] += s4.y * xv0; acc1[p * 4 + 1] += s4.y * xv1;
        acc0[p * 4 + 2] += s4.z * xv0; acc1[p * 4 + 2] += s4.z * xv1;
        acc0[p * 4 + 3] += s4.w * xv0; acc1[p * 4 + 3] += s4.w * xv1;
      }
    }
    __syncthreads();
  }
  long pbase = (long)(b * 32 + sc * 4 + sg) * 16384 + col0;
#pragma unroll
  for (int h = 0; h < 16; h++) {
    ypart[pbase + h * 1024] = acc0[h];
    ypart[pbase + h * 1024 + 64] = acc1[h];
  }
  if (tid < 16) spart[(b * 8 + sc) * 16 + tid] = ss;
}

// ===== kv[b,h,d] = (Σ_p y_part)·wv[:,h*64+d] + (Σσ)·bv[h*64+d] ===========
__global__ __launch_bounds__(256) void kv_small(
    const float* __restrict__ ypart, const float* __restrict__ spart,
    const float* __restrict__ wvw, const float* __restrict__ bv,
    float* __restrict__ kv) {
  __shared__ float yl[1024];
  __shared__ float red[4][64];
  const int tid = threadIdx.x;
  const int b = blockIdx.x >> 4, h = blockIdx.x & 15;
  for (int c = tid; c < 1024; c += 256) {
    float s_ = 0.f;
    const float* yp = ypart + (long)(b * 32) * 16384 + h * 1024 + c;
#pragma unroll
    for (int p = 0; p < 32; p++) s_ += yp[(long)p * 16384];
    yl[c] = s_;
  }
  __syncthreads();
  const int wv_ = tid >> 6, d = tid & 63;
  float acc = 0.f;
  const float* wcol = wvw + h * 64 + d;
  for (int c = wv_ * 256; c < wv_ * 256 + 256; c++)
    acc += yl[c] * wcol[(long)c * 1024];
  red[wv_][d] = acc;
  __syncthreads();
  if (tid < 64) {
    float ss = 0.f;
#pragma unroll
    for (int s_ = 0; s_ < 8; s_++) ss += spart[(b * 8 + s_) * 16 + h];
    kv[(b * 16 + h) * 64 + tid] = red[0][tid] + red[1][tid] + red[2][tid] +
                                  red[3][tid] + ss * bv[h * 64 + tid];
  }
}

// ===== z[b,h,n] = Σ_d cumsum_h(kv)[b,h,d]·wo[h*64+d, n]  (cumsum fused) ===
__global__ __launch_bounds__(256) void zker(const float* __restrict__ kvb,
                                            const float* __restrict__ wo,
                                            float* __restrict__ z) {
  __shared__ float sc_[64];
  const int tid = threadIdx.x;
  const int b = blockIdx.x >> 4, h = blockIdx.x & 15;
  if (tid < 64) {
    float run = 0.f;
    for (int hh = 0; hh <= h; hh++) run += kvb[(b * 16 + hh) * 64 + tid];
    sc_[tid] = run;
  }
  __syncthreads();
  float4 acc = make_float4(0.f, 0.f, 0.f, 0.f);
  for (int d = 0; d < 64; d++) {
    float s_ = sc_[d];
    float4 w = ((const float4*)(wo + (long)(h * 64 + d) * 1024))[tid];
    acc.x += s_ * w.x; acc.y += s_ * w.y;
    acc.z += s_ * w.z; acc.w += s_ * w.w;
  }
  ((float4*)(z + (long)(b * 16 + h) * 1024))[tid] = acc;
}

// ===== fused attn-broadcast + residual + LayerNorm ========================
template <int OMODE>  // 1: f32 out only; 2: f32 + bf16
__global__ __launch_bounds__(256) void ln_attn(
    const float* __restrict__ qp, const float* __restrict__ z,
    const float* __restrict__ bo, const float* __restrict__ r,
    const float* __restrict__ g, const float* __restrict__ be,
    float* __restrict__ outf, u16* __restrict__ outb) {
  __shared__ float zs[16][1024];
  __shared__ float sq16[16];
  __shared__ float s1[4], s2[4];
  const int tid = threadIdx.x;
  const int b = blockIdx.x >> 8;
  const float4* zg = (const float4*)(z + (long)b * 16384);
  float4* zl = (float4*)zs;
#pragma unroll
  for (int i = 0; i < 16; i++) zl[i * 256 + tid] = zg[i * 256 + tid];
  float4 gv = ((const float4*)g)[tid];
  float4 bev = ((const float4*)be)[tid];
  float4 bov = ((const float4*)bo)[tid];
  const int wid = tid >> 6, lane = tid & 63;
  for (int rr_ = 0; rr_ < 16; rr_++) {
    long row = (long)blockIdx.x * 16 + rr_;
    if (tid < 16) sq16[tid] = sigmoidf_(qp[row * 16 + tid]);
    __syncthreads();
    float4 rv = ((const float4*)(r + row * 1024))[tid];
    float y0 = bov.x + rv.x, y1 = bov.y + rv.y;
    float y2 = bov.z + rv.z, y3 = bov.w + rv.w;
#pragma unroll
    for (int h = 0; h < 16; h++) {
      float s_ = sq16[h];
      float4 zv = *(const float4*)&zs[h][tid * 4];
      y0 += s_ * zv.x; y1 += s_ * zv.y; y2 += s_ * zv.z; y3 += s_ * zv.w;
    }
    float s = y0 + y1 + y2 + y3;
    float q = y0 * y0 + y1 * y1 + y2 * y2 + y3 * y3;
#pragma unroll
    for (int o = 32; o > 0; o >>= 1) {
      s += __shfl_down(s, o);
      q += __shfl_down(q, o);
    }
    if (lane == 0) { s1[wid] = s; s2[wid] = q; }
    __syncthreads();
    s = s1[0] + s1[1] + s1[2] + s1[3];
    q = s2[0] + s2[1] + s2[2] + s2[3];
    float mu = s * (1.f / 1024.f);
    float var = q * (1.f / 1024.f) - mu * mu;
    float inv = rsqrtf(fmaxf(var, 0.f) + 1e-6f);
    float o0 = gv.x * (y0 - mu) * inv + bev.x;
    float o1 = gv.y * (y1 - mu) * inv + bev.y;
    float o2 = gv.z * (y2 - mu) * inv + bev.z;
    float o3 = gv.w * (y3 - mu) * inv + bev.w;
    ((float4*)(outf + row * 1024))[tid] = make_float4(o0, o1, o2, o3);
    if (OMODE == 2) {
      uint2 ob;
      ob.x = (uint32_t)f2bf(o0) | ((uint32_t)f2bf(o1) << 16);
      ob.y = (uint32_t)f2bf(o2) | ((uint32_t)f2bf(o3) << 16);
      ((uint2*)(outb + row * 1024))[tid] = ob;
    }
    __syncthreads();
  }
}

// ===== 256x256 MFMA GEMM — m201-discipline 4-phase/ktile (r11, control) ===
template <int ACT>
__global__ __launch_bounds__(512) void gemm256(
    const u16* __restrict__ A, const u16* __restrict__ BT,
    const float* __restrict__ bias, u16* __restrict__ C, int M, int N,
    int K) {
  __shared__ __attribute__((aligned(16))) u16 lds[65536];  // 128 KB
  const int tid = threadIdx.x;
  const int wid = tid >> 6, lane = tid & 63;
  const int wm = wid >> 2, wn = wid & 3;
  const int lrow = lane & 15, g = lane >> 4;

  int nwg = gridDim.x * gridDim.y;
  int orig = blockIdx.y * gridDim.x + blockIdx.x;
  int wg = (nwg & 7) ? orig : ((orig & 7) * (nwg >> 3) + (orig >> 3));
  const long bn = (long)(wg % gridDim.x) * 256;
  const long bm = (long)(wg / gridDim.x) * 256;

  const int rr = wid * 16 + (lane >> 2);
  const int esrc = ((lane & 3) * 8) ^ (((lane >> 5) & 1) * 16);
  const u16* Abase = A + (bm + rr) * (long)K + esrc;
  const u16* Bbase = BT + (bn + rr) * (long)K + esrc;
  const long jstep = (long)128 * K;
  char* ldsc = (char*)lds;
  const int ldsw = wid * 1024;

  const int swr = ((lrow >> 3) & 1) * 32;
  const int aoff = (wm * 128 + lrow) * 64 + ((g * 16) ^ swr);
  const int boff = 32768 + (wn * 64 + lrow) * 64 + ((g * 16) ^ swr);

  f32x4 acc[8][4] = {};
  const int KT = K >> 6;

  auto stage2 = [&](int buf, int kk, int kt, int half) {
    int dA = buf * 65536 + kk * 16384 + ldsw;
    if (half == 0) {
      const u16* sA = Abase + (long)kt * 64 + kk * 32;
      load_lds16(sA, ldsc + dA);
      load_lds16(sA + jstep, ldsc + dA + 8192);
    } else {
      const u16* sB = Bbase + (long)kt * 64 + kk * 32;
      load_lds16(sB, ldsc + dA + 32768);
      load_lds16(sB + jstep, ldsc + dA + 40960);
    }
  };

#define LDAB8(BUF, KK)                                                      \
  {                                                                         \
    const char* _b = ldsc + (BUF) * 65536 + (KK) * 16384;                   \
    _Pragma("unroll") for (int m = 0; m < 4; m++)                           \
        af[m] = *(const bf16x8*)(_b + aoff + m * 1024);                     \
    _Pragma("unroll") for (int n = 0; n < 4; n++)                           \
        bq[n] = *(const bf16x8*)(_b + boff + n * 1024);                     \
  }
#define LDA4(BUF, KK)                                                       \
  {                                                                         \
    const char* _b = ldsc + (BUF) * 65536 + (KK) * 16384;                   \
    _Pragma("unroll") for (int m = 4; m < 8; m++)                           \
        af[m] = *(const bf16x8*)(_b + aoff + m * 1024);                     \
  }
#define MMA16(M0)                                                           \
  __builtin_amdgcn_s_setprio(1);                                            \
  _Pragma("unroll") for (int m = M0; m < M0 + 4; m++)                       \
  _Pragma("unroll") for (int n = 0; n < 4; n++)                             \
      acc[m][n] = __builtin_amdgcn_mfma_f32_16x16x32_bf16(af[m], bq[n],     \
                                                          acc[m][n], 0, 0,  \
                                                          0);               \
  __builtin_amdgcn_s_setprio(0);
#define WLG0() asm volatile("s_waitcnt lgkmcnt(0)" ::: "memory")
#define WVM4() asm volatile("s_waitcnt vmcnt(4)" ::: "memory")
#define WVM0() asm volatile("s_waitcnt vmcnt(0)" ::: "memory")

  bf16x8 af[8], bq[4];

  stage2(0, 0, 0, 0);
  stage2(0, 0, 0, 1);
  stage2(0, 1, 0, 0);
  stage2(0, 1, 0, 1);
  WVM4();
  BAR();

  for (int kt = 0; kt + 1 < KT; ++kt) {
    const int b0 = kt & 1, b1 = b0 ^ 1;
    LDAB8(b0, 0);
    stage2(b1, 0, kt + 1, 0);
    BAR(); WLG0();
    MMA16(0);
    BAR();
    LDA4(b0, 0);
    stage2(b1, 0, kt + 1, 1);
    WVM4();
    BAR(); WLG0();
    MMA16(4);
    BAR();
    LDAB8(b0, 1);
    stage2(b1, 1, kt + 1, 0);
    BAR(); WLG0();
    MMA16(0);
    BAR();
    LDA4(b0, 1);
    stage2(b1, 1, kt + 1, 1);
    WVM4();
    BAR(); WLG0();
    MMA16(4);
    BAR();
  }
  {
    const int b0 = (KT - 1) & 1;
    LDAB8(b0, 0);
    BAR(); WLG0();
    MMA16(0);
    BAR();
    LDA4(b0, 0);
    WVM0();
    BAR(); WLG0();
    MMA16(4);
    BAR();
    LDAB8(b0, 1);
    BAR(); WLG0();
    MMA16(0);
    BAR();
    LDA4(b0, 1);
    BAR(); WLG0();
    MMA16(4);
    BAR();
  }

#pragma unroll
  for (int n = 0; n < 4; n++) {
    int cl = wn * 64 + n * 16 + lrow;
    float bb = bias[bn + cl];
#pragma unroll
    for (int m = 0; m < 8; m++) {
      int rl = wm * 128 + m * 16 + g * 4;
#pragma unroll
      for (int i = 0; i < 4; i++) {
        float v = acc[m][n][i] + bb;
        if (ACT == 1) v = fmaxf(v, 0.f);
        lds[(rl + i) * 256 + cl] = f2bf(v);
      }
    }
  }
  BAR();
  const uint4* lv = (const uint4*)lds;
#pragma unroll
  for (int it = 0; it < 16; it++) {
    int idx = it * 512 + tid;
    int row = idx >> 5;
    int cu = (idx & 31) * 8;
    *(uint4*)&C[(bm + row) * (long)N + bn + cu] = lv[idx];
  }
#undef LDAB8
#undef LDA4
#undef MMA16
#undef WLG0
#undef WVM4
#undef WVM0
}

// --- LayerNorm(a_bf16 + r_f32)*g + be -> f32 ------------------------------
__global__ __launch_bounds__(256) void ln_res(const u16* __restrict__ a,
                                              const float* __restrict__ r,
                                              const float* __restrict__ g,
                                              const float* __restrict__ be,
                                              float* __restrict__ outf) {
  long row = blockIdx.x;
  int tid = threadIdx.x;
  uint2 av = ((const uint2*)(a + row * 1024))[tid];
  float4 rv = ((const float4*)(r + row * 1024))[tid];
  float y[4];
  y[0] = bf2f((u16)(av.x & 0xffff)) + rv.x;
  y[1] = bf2f((u16)(av.x >> 16)) + rv.y;
  y[2] = bf2f((u16)(av.y & 0xffff)) + rv.z;
  y[3] = bf2f((u16)(av.y >> 16)) + rv.w;
  float s = y[0] + y[1] + y[2] + y[3];
  float q = y[0] * y[0] + y[1] * y[1] + y[2] * y[2] + y[3] * y[3];
#pragma unroll
  for (int o = 32; o > 0; o >>= 1) {
    s += __shfl_down(s, o);
    q += __shfl_down(q, o);
  }
  __shared__ float s1[4], s2[4];
  int wid = tid >> 6, lane = tid & 63;
  if (lane == 0) { s1[wid] = s; s2[wid] = q; }
  __syncthreads();
  s = s1[0] + s1[1] + s1[2] + s1[3];
  q = s2[0] + s2[1] + s2[2] + s2[3];
  float mu = s * (1.f / 1024.f);
  float var = q * (1.f / 1024.f) - mu * mu;
  float inv = rsqrtf(fmaxf(var, 0.f) + 1e-6f);
  float4 gv = ((const float4*)g)[tid], bv = ((const float4*)be)[tid];
  float o0 = gv.x * (y[0] - mu) * inv + bv.x;
  float o1 = gv.y * (y[1] - mu) * inv + bv.y;
  float o2 = gv.z * (y[2] - mu) * inv + bv.z;
  float o3 = gv.w * (y[3] - mu) * inv + bv.w;
  ((float4*)(outf + row * 1024))[tid] = make_float4(o0, o1, o2, o3);
}

extern "C" void kernel_launch(void* const* d_in, const int* in_sizes, int n_in,
                              void* d_out, int out_size, void* d_ws,
                              size_t ws_size, hipStream_t stream) {
  const float* x   = (const float*)d_in[0];
  const float* enc = (const float*)d_in[1];
  const float* wq1 = (const float*)d_in[2];  const float* bq1 = (const float*)d_in[3];
  const float* wk1 = (const float*)d_in[4];  const float* bk1 = (const float*)d_in[5];
  const float* wv1 = (const float*)d_in[6];  const float* bv1 = (const float*)d_in[7];
  const float* wo1 = (const float*)d_in[8];  const float* bo1 = (const float*)d_in[9];
  const float* wq2 = (const float*)d_in[10]; const float* bq2 = (const float*)d_in[11];
  const float* wk2 = (const float*)d_in[12]; const float* bk2 = (const float*)d_in[13];
  const float* wv2 = (const float*)d_in[14]; const float* bv2 = (const float*)d_in[15];
  const float* wo2 = (const float*)d_in[16]; const float* bo2 = (const float*)d_in[17];
  const float* wf1 = (const float*)d_in[18]; const float* bf1 = (const float*)d_in[19];
  const float* wf2 = (const float*)d_in[20]; const float* bf2 = (const float*)d_in[21];
  const float* g1 = (const float*)d_in[22];  const float* be1 = (const float*)d_in[23];
  const float* g2 = (const float*)d_in[24];  const float* be2 = (const float*)d_in[25];
  const float* g3 = (const float*)d_in[26];  const float* be3 = (const float*)d_in[27];
  (void)in_sizes; (void)n_in; (void)out_size; (void)ws_size;

  const size_t S = (size_t)16384 * 1024;  // tokens * d_model
  float* O0 = (float*)d_out;              // out3 (f32)

  char* base = (char*)d_ws;
  size_t off = 0;
  auto alloc = [&](size_t bytes) -> void* {
    void* p = base + off;
    off += (bytes + 255) & ~(size_t)255;
    return p;
  };
  u16* WT1    = (u16*)alloc((size_t)4096 * 1024 * 2);  // wf1^T bf16
  u16* WT2    = (u16*)alloc((size_t)4096 * 1024 * 2);  // wf2^T bf16
  float* qb   = (float*)alloc((size_t)16384 * 16 * 4);
  float* kb   = (float*)alloc((size_t)16384 * 16 * 4);
  float* ypart= (float*)alloc((size_t)4 * 32 * 16 * 1024 * 4);  // 8MB
  float* spart= (float*)alloc((size_t)4 * 8 * 16 * 4);
  float* kvb  = (float*)alloc((size_t)4 * 16 * 64 * 4);
  float* zb   = (float*)alloc((size_t)4 * 16 * 1024 * 4);       // 256KB
  u16* FA     = (u16*)alloc(S * 2);                    // bf16: ffn_out
  u16* FM     = (u16*)alloc((size_t)16384 * 4096 * 2); // bf16: ffn mid
  u16* O1b    = (u16*)alloc(S * 2);                    // bf16 out1
  u16* O2b    = (u16*)alloc(S * 2);                    // bf16 out2
  float* O1f  = (float*)alloc(S * 4);                  // f32 out1
  float* O2f  = (float*)alloc(S * 4);                  // f32 out2

  const int T = 16384;
  dim3 blk(256), gblk(512);

  // ---- MHA1 (q=k=v from x, single x read) ----
  proj_mfma<1, 0><<<256, blk, 0, stream>>>(x, nullptr, wq1, bq1, wk1, bk1,
                                           qb, kb);
  ksum<<<dim3(8, 8, 4), blk, 0, stream>>>(kb, x, ypart, spart);
  kv_small<<<64, blk, 0, stream>>>(ypart, spart, wv1, bv1, kvb);
  zker<<<64, blk, 0, stream>>>(kvb, wo1, zb);
  ln_attn<2><<<1024, blk, 0, stream>>>(qb, zb, bo1, x, g1, be1, O1f, O1b);

  // ---- MHA2 (q from out1 bf16, k/v from enc f32) ----
  proj_mfma<0, 1><<<256, blk, 0, stream>>>(O1b, enc, wq2, bq2, wk2, bk2,
                                           qb, kb);
  ksum<<<dim3(8, 8, 4), blk, 0, stream>>>(kb, enc, ypart, spart);
  kv_small<<<64, blk, 0, stream>>>(ypart, spart, wv2, bv2, kvb);
  zker<<<64, blk, 0, stream>>>(kvb, wo2, zb);
  ln_attn<2><<<1024, blk, 0, stream>>>(qb, zb, bo2, O1f, g2, be2, O2f, O2b);

  // ---- FFN ----
  transpose_cvt<<<dim3(128, 32), blk, 0, stream>>>(wf1, WT1, 1024, 4096);
  transpose_cvt<<<dim3(32, 128), blk, 0, stream>>>(wf2, WT2, 4096, 1024);
  gemm256<1><<<dim3(16, 64), gblk, 0, stream>>>(O2b, WT1, bf1, FM, T, 4096, 1024);
  gemm256<0><<<dim3(4, 64), gblk, 0, stream>>>(FM, WT2, bf2, FA, T, 1024, 4096);
  ln_res<<<16384, blk, 0, stream>>>(FA, O2f, g3, be3, O0);  // out3

  // outputs 1 and 2 must be zeros
  hipMemsetAsync((float*)d_out + S, 0, 2 * S * 4, stream);
}

// Round 15
// 589.526 us; speedup vs baseline: 1.7824x; 1.0061x over previous
//
#include <hip/hip_runtime.h>
#include <cstdint>

typedef unsigned short u16;
typedef __bf16 bf16x8 __attribute__((ext_vector_type(8)));
typedef float f32x4 __attribute__((ext_vector_type(4)));

__device__ __forceinline__ float bf2f(u16 h) {
  union { uint32_t u; float f; } v; v.u = (uint32_t)h << 16; return v.f;
}
__device__ __forceinline__ u16 f2bf(float f) {
  union { float f; uint32_t u; } v; v.f = f;
  uint32_t r = v.u + 0x7fffu + ((v.u >> 16) & 1u);
  return (u16)(r >> 16);
}
__device__ __forceinline__ float sigmoidf_(float x) {
  return 1.0f / (1.0f + __expf(-x));
}
__device__ __forceinline__ void load_lds16(const void* g, void* l) {
  __builtin_amdgcn_global_load_lds(
      (const __attribute__((address_space(1))) void*)g,
      (__attribute__((address_space(3))) void*)l, 16, 0, 0);
}
__device__ __forceinline__ bf16x8 cvt8(const float* p) {
  float4 a = *(const float4*)p, b = *(const float4*)(p + 4);
  union { u16 u[8]; bf16x8 v; } r;
  r.u[0] = f2bf(a.x); r.u[1] = f2bf(a.y); r.u[2] = f2bf(a.z); r.u[3] = f2bf(a.w);
  r.u[4] = f2bf(b.x); r.u[5] = f2bf(b.y); r.u[6] = f2bf(b.z); r.u[7] = f2bf(b.w);
  return r.v;
}
#define BAR() __builtin_amdgcn_s_barrier()

// ------------- transpose+convert: in f32 [K][N] -> out bf16 [N][K] -------
__global__ __launch_bounds__(256) void transpose_cvt(
    const float* __restrict__ in, u16* __restrict__ out, int K, int N) {
  __shared__ float t[32][33];
  int n0 = blockIdx.x * 32, k0 = blockIdx.y * 32;
  int tx = threadIdx.x & 31, ty = threadIdx.x >> 5;
#pragma unroll
  for (int i = 0; i < 32; i += 8)
    t[ty + i][tx] = in[(long)(k0 + ty + i) * N + n0 + tx];
  __syncthreads();
#pragma unroll
  for (int i = 0; i < 32; i += 8)
    out[(long)(n0 + ty + i) * K + k0 + tx] = f2bf(t[tx][ty + i]);
}

// ===== MFMA projection: q = xq@wq+bq, k = xk@wk+bk ; [T,1024]->[T,16]x2 ===
// grid T/64; 4 waves; wave w owns 16 tokens over full K (in-register acc).
// SAME=1: xk ignored (A shared). QBF=1: xq bf16, else f32.
template <int SAME, int QBF>
__global__ __launch_bounds__(256) void proj_mfma(
    const void* __restrict__ xq_, const float* __restrict__ xk,
    const float* __restrict__ wq, const float* __restrict__ bq,
    const float* __restrict__ wk, const float* __restrict__ bk,
    float* __restrict__ qout, float* __restrict__ kout) {
  __shared__ __attribute__((aligned(16))) u16 wt[2][16384];  // 64KB
  const int tid = threadIdx.x;
  for (int kq = 0; kq < 4; kq++) {
    int k = kq * 256 + tid;
    const float4* q4 = (const float4*)(wq + (long)k * 16);
    const float4* k4 = (const float4*)(wk + (long)k * 16);
#pragma unroll
    for (int p = 0; p < 4; p++) {
      float4 qv = q4[p], kv = k4[p];
      float qf[4] = {qv.x, qv.y, qv.z, qv.w};
      float kf[4] = {kv.x, kv.y, kv.z, kv.w};
#pragma unroll
      for (int j = 0; j < 4; j++) {
        int c = p * 4 + j;
        int off = (c * 2048 + k * 2) ^ ((c & 7) << 4);
        *(u16*)((char*)wt[0] + off) = f2bf(qf[j]);
        *(u16*)((char*)wt[1] + off) = f2bf(kf[j]);
      }
    }
  }
  __syncthreads();
  const int wv = tid >> 6, lane = tid & 63;
  const int lrow = lane & 15, g = lane >> 4;
  const long tok0 = (long)blockIdx.x * 64 + wv * 16;
  const int swz = (lrow & 7) << 4;
  const long arow = (tok0 + lrow) * 1024 + g * 8;
  f32x4 accq = {}, acck = {};
#pragma unroll 8
  for (int ks = 0; ks < 32; ks++) {
    bf16x8 aq_;
    if (QBF)
      aq_ = *(const bf16x8*)((const u16*)xq_ + arow + ks * 32);
    else
      aq_ = cvt8((const float*)xq_ + arow + ks * 32);
    bf16x8 ak_;
    if (SAME)
      ak_ = aq_;
    else
      ak_ = cvt8(xk + arow + ks * 32);
    int off = (lrow * 2048 + ks * 64 + g * 16) ^ swz;
    bf16x8 bq_ = *(const bf16x8*)((const char*)wt[0] + off);
    bf16x8 bk_ = *(const bf16x8*)((const char*)wt[1] + off);
    accq = __builtin_amdgcn_mfma_f32_16x16x32_bf16(aq_, bq_, accq, 0, 0, 0);
    acck = __builtin_amdgcn_mfma_f32_16x16x32_bf16(ak_, bk_, acck, 0, 0, 0);
  }
  const int col = lrow, r0 = g * 4;
  float bqv = bq[col], bkv = bk[col];
#pragma unroll
  for (int i = 0; i < 4; i++) {
    qout[(tok0 + r0 + i) * 16 + col] = accq[i] + bqv;
    kout[(tok0 + r0 + i) * 16 + col] = acck[i] + bkv;
  }
}

// ===== ksum: y_part[b][p][h][c] = Σ_{s in chunk} σ(k[b,s,h])·x[b,s,c] ====
__global__ __launch_bounds__(256) void ksum(const float* __restrict__ kp,
                                            const float* __restrict__ x,
                                            float* __restrict__ ypart,
                                            float* __restrict__ spart) {
  __shared__ __attribute__((aligned(16))) float sk[256][20];
  __shared__ float ssl[16][17];
  const int tid = threadIdx.x;
  const int cc = blockIdx.x, sc = blockIdx.y, b = blockIdx.z;
  const int cl = tid & 63, sg = tid >> 6;
  const int col0 = cc * 128 + cl;
  float acc0[16], acc1[16];
#pragma unroll
  for (int h = 0; h < 16; h++) { acc0[h] = 0.f; acc1[h] = 0.f; }
  float ss = 0.f;
  for (int tile = 0; tile < 2; tile++) {
    const int s0 = sc * 512 + tile * 256;
    const float* kr = kp + ((long)b * 4096 + s0 + tid) * 16;
#pragma unroll
    for (int p = 0; p < 4; p++) {
      float4 k4 = *(const float4*)(kr + p * 4);
      *(float4*)&sk[tid][p * 4] = make_float4(
          sigmoidf_(k4.x), sigmoidf_(k4.y), sigmoidf_(k4.z), sigmoidf_(k4.w));
    }
    __syncthreads();
    {
      int g2 = tid >> 4, h2 = tid & 15;
      float s_ = 0.f;
#pragma unroll
      for (int i = 0; i < 16; i++) s_ += sk[g2 * 16 + i][h2];
      ssl[g2][h2] = s_;
    }
    __syncthreads();
    if (tid < 16) {
      float s_ = 0.f;
#pragma unroll
      for (int gg = 0; gg < 16; gg++) s_ += ssl[gg][tid];
      ss += s_;
    }
    const float* xr = x + ((long)b * 4096 + s0 + sg * 64) * 1024 + col0;
    for (int j = 0; j < 64; j++) {
      float xv0 = xr[(long)j * 1024];
      float xv1 = xr[(long)j * 1024 + 64];
      const float4* skr = (const float4*)sk[sg * 64 + j];
#pragma unroll
      for (int p = 0; p < 4; p++) {
        float4 s4 = skr[p];
        acc0[p * 4 + 0] += s4.x * xv0; acc1[p * 4 + 0] += s4.x * xv1;
        acc0[p * 4 + 1] += s4.y * xv0; acc1[p * 4 + 1] += s4.y * xv1;
        acc0[p * 4 + 2] += s4.z * xv0; acc1[p * 4 + 2] += s4.z * xv1;
        acc0[p * 4 + 3] += s4.w * xv0; acc1[p * 4 + 3] += s4.w * xv1;
      }
    }
    __syncthreads();
  }
  long pbase = (long)(b * 32 + sc * 4 + sg) * 16384 + col0;
#pragma unroll
  for (int h = 0; h < 16; h++) {
    ypart[pbase + h * 1024] = acc0[h];
    ypart[pbase + h * 1024 + 64] = acc1[h];
  }
  if (tid < 16) spart[(b * 8 + sc) * 16 + tid] = ss;
}

// ===== kv[b,h,d] = (Σ_p y_part)·wv[:,h*64+d] + (Σσ)·bv[h*64+d] ===========
__global__ __launch_bounds__(256) void kv_small(
    const float* __restrict__ ypart, const float* __restrict__ spart,
    const float* __restrict__ wvw, const float* __restrict__ bv,
    float* __restrict__ kv) {
  __shared__ float yl[1024];
  __shared__ float red[4][64];
  const int tid = threadIdx.x;
  const int b = blockIdx.x >> 4, h = blockIdx.x & 15;
  for (int c = tid; c < 1024; c += 256) {
    float s_ = 0.f;
    const float* yp = ypart + (long)(b * 32) * 16384 + h * 1024 + c;
#pragma unroll
    for (int p = 0; p < 32; p++) s_ += yp[(long)p * 16384];
    yl[c] = s_;
  }
  __syncthreads();
  const int wv_ = tid >> 6, d = tid & 63;
  float acc = 0.f;
  const float* wcol = wvw + h * 64 + d;
  for (int c = wv_ * 256; c < wv_ * 256 + 256; c++)
    acc += yl[c] * wcol[(long)c * 1024];
  red[wv_][d] = acc;
  __syncthreads();
  if (tid < 64) {
    float ss = 0.f;
#pragma unroll
    for (int s_ = 0; s_ < 8; s_++) ss += spart[(b * 8 + s_) * 16 + h];
    kv[(b * 16 + h) * 64 + tid] = red[0][tid] + red[1][tid] + red[2][tid] +
                                  red[3][tid] + ss * bv[h * 64 + tid];
  }
}

// ===== z[b,h,n] = Σ_d cumsum_h(kv)[b,h,d]·wo[h*64+d, n]  (cumsum fused) ===
__global__ __launch_bounds__(256) void zker(const float* __restrict__ kvb,
                                            const float* __restrict__ wo,
                                            float* __restrict__ z) {
  __shared__ float sc_[64];
  const int tid = threadIdx.x;
  const int b = blockIdx.x >> 4, h = blockIdx.x & 15;
  if (tid < 64) {
    float run = 0.f;
    for (int hh = 0; hh <= h; hh++) run += kvb[(b * 16 + hh) * 64 + tid];
    sc_[tid] = run;
  }
  __syncthreads();
  float4 acc = make_float4(0.f, 0.f, 0.f, 0.f);
  for (int d = 0; d < 64; d++) {
    float s_ = sc_[d];
    float4 w = ((const float4*)(wo + (long)(h * 64 + d) * 1024))[tid];
    acc.x += s_ * w.x; acc.y += s_ * w.y;
    acc.z += s_ * w.z; acc.w += s_ * w.w;
  }
  ((float4*)(z + (long)(b * 16 + h) * 1024))[tid] = acc;
}

// ===== fused attn-broadcast + residual + LayerNorm ========================
template <int OMODE>  // 1: f32 out only; 2: f32 + bf16
__global__ __launch_bounds__(256) void ln_attn(
    const float* __restrict__ qp, const float* __restrict__ z,
    const float* __restrict__ bo, const float* __restrict__ r,
    const float* __restrict__ g, const float* __restrict__ be,
    float* __restrict__ outf, u16* __restrict__ outb) {
  __shared__ float zs[16][1024];
  __shared__ float sq16[16];
  __shared__ float s1[4], s2[4];
  const int tid = threadIdx.x;
  const int b = blockIdx.x >> 8;
  const float4* zg = (const float4*)(z + (long)b * 16384);
  float4* zl = (float4*)zs;
#pragma unroll
  for (int i = 0; i < 16; i++) zl[i * 256 + tid] = zg[i * 256 + tid];
  float4 gv = ((const float4*)g)[tid];
  float4 bev = ((const float4*)be)[tid];
  float4 bov = ((const float4*)bo)[tid];
  const int wid = tid >> 6, lane = tid & 63;
  for (int rr_ = 0; rr_ < 16; rr_++) {
    long row = (long)blockIdx.x * 16 + rr_;
    if (tid < 16) sq16[tid] = sigmoidf_(qp[row * 16 + tid]);
    __syncthreads();
    float4 rv = ((const float4*)(r + row * 1024))[tid];
    float y0 = bov.x + rv.x, y1 = bov.y + rv.y;
    float y2 = bov.z + rv.z, y3 = bov.w + rv.w;
#pragma unroll
    for (int h = 0; h < 16; h++) {
      float s_ = sq16[h];
      float4 zv = *(const float4*)&zs[h][tid * 4];
      y0 += s_ * zv.x; y1 += s_ * zv.y; y2 += s_ * zv.z; y3 += s_ * zv.w;
    }
    float s = y0 + y1 + y2 + y3;
    float q = y0 * y0 + y1 * y1 + y2 * y2 + y3 * y3;
#pragma unroll
    for (int o = 32; o > 0; o >>= 1) {
      s += __shfl_down(s, o);
      q += __shfl_down(q, o);
    }
    if (lane == 0) { s1[wid] = s; s2[wid] = q; }
    __syncthreads();
    s = s1[0] + s1[1] + s1[2] + s1[3];
    q = s2[0] + s2[1] + s2[2] + s2[3];
    float mu = s * (1.f / 1024.f);
    float var = q * (1.f / 1024.f) - mu * mu;
    float inv = rsqrtf(fmaxf(var, 0.f) + 1e-6f);
    float o0 = gv.x * (y0 - mu) * inv + bev.x;
    float o1 = gv.y * (y1 - mu) * inv + bev.y;
    float o2 = gv.z * (y2 - mu) * inv + bev.z;
    float o3 = gv.w * (y3 - mu) * inv + bev.w;
    ((float4*)(outf + row * 1024))[tid] = make_float4(o0, o1, o2, o3);
    if (OMODE == 2) {
      uint2 ob;
      ob.x = (uint32_t)f2bf(o0) | ((uint32_t)f2bf(o1) << 16);
      ob.y = (uint32_t)f2bf(o2) | ((uint32_t)f2bf(o3) << 16);
      ((uint2*)(outb + row * 1024))[tid] = ob;
    }
    __syncthreads();
  }
}

// ===== 256x256 MFMA GEMM — r11 schedule + 2-bit XOR swizzle (2-way free) ==
// LDS slot [buf][kk]: rows 0..255 x k 0..31 bf16, linear. Slot-permutation:
// LDS b128-slot s_l of row r holds src slot s_l ^ ((r>>1)&3). Applied on
// staging SOURCE (esrc) and ds_read address; involution verified. Bank-
// starts for 16 lrow lanes: 8 distinct -> 2 lanes/bank = free (m136).
template <int ACT>
__global__ __launch_bounds__(512) void gemm256(
    const u16* __restrict__ A, const u16* __restrict__ BT,
    const float* __restrict__ bias, u16* __restrict__ C, int M, int N,
    int K) {
  __shared__ __attribute__((aligned(16))) u16 lds[65536];  // 128 KB
  const int tid = threadIdx.x;
  const int wid = tid >> 6, lane = tid & 63;
  const int wm = wid >> 2, wn = wid & 3;
  const int lrow = lane & 15, g = lane >> 4;

  int nwg = gridDim.x * gridDim.y;
  int orig = blockIdx.y * gridDim.x + blockIdx.x;
  int wg = (nwg & 7) ? orig : ((orig & 7) * (nwg >> 3) + (orig >> 3));
  const long bn = (long)(wg % gridDim.x) * 256;
  const long bm = (long)(wg / gridDim.x) * 256;

  const int rr = wid * 16 + (lane >> 2);
  // 2-bit slot permutation: src slot = lds slot ^ (row bits 1-2)
  const int esrc = (((lane & 3) ^ ((lane >> 3) & 3)) * 8);  // elements
  const u16* Abase = A + (bm + rr) * (long)K + esrc;
  const u16* Bbase = BT + (bn + rr) * (long)K + esrc;
  const long jstep = (long)128 * K;
  char* ldsc = (char*)lds;
  const int ldsw = wid * 1024;

  const int slotr = (g ^ ((lrow >> 1) & 3)) * 16;  // read-side slot bytes
  const int aoff = (wm * 128 + lrow) * 64 + slotr;
  const int boff = 32768 + (wn * 64 + lrow) * 64 + slotr;

  f32x4 acc[8][4] = {};
  const int KT = K >> 6;

  auto stage2 = [&](int buf, int kk, int kt, int half) {
    int dA = buf * 65536 + kk * 16384 + ldsw;
    if (half == 0) {
      const u16* sA = Abase + (long)kt * 64 + kk * 32;
      load_lds16(sA, ldsc + dA);
      load_lds16(sA + jstep, ldsc + dA + 8192);
    } else {
      const u16* sB = Bbase + (long)kt * 64 + kk * 32;
      load_lds16(sB, ldsc + dA + 32768);
      load_lds16(sB + jstep, ldsc + dA + 40960);
    }
  };

#define LDAB8(BUF, KK)                                                      \
  {                                                                         \
    const char* _b = ldsc + (BUF) * 65536 + (KK) * 16384;                   \
    _Pragma("unroll") for (int m = 0; m < 4; m++)                           \
        af[m] = *(const bf16x8*)(_b + aoff + m * 1024);                     \
    _Pragma("unroll") for (int n = 0; n < 4; n++)                           \
        bq[n] = *(const bf16x8*)(_b + boff + n * 1024);                     \
  }
#define LDA4(BUF, KK)                                                       \
  {                                                                         \
    const char* _b = ldsc + (BUF) * 65536 + (KK) * 16384;                   \
    _Pragma("unroll") for (int m = 4; m < 8; m++)                           \
        af[m] = *(const bf16x8*)(_b + aoff + m * 1024);                     \
  }
#define MMA16(M0)                                                           \
  __builtin_amdgcn_s_setprio(1);                                            \
  _Pragma("unroll") for (int m = M0; m < M0 + 4; m++)                       \
  _Pragma("unroll") for (int n = 0; n < 4; n++)                             \
      acc[m][n] = __builtin_amdgcn_mfma_f32_16x16x32_bf16(af[m], bq[n],     \
                                                          acc[m][n], 0, 0,  \
                                                          0);               \
  __builtin_amdgcn_s_setprio(0);
#define WLG0() asm volatile("s_waitcnt lgkmcnt(0)" ::: "memory")
#define WVM4() asm volatile("s_waitcnt vmcnt(4)" ::: "memory")
#define WVM0() asm volatile("s_waitcnt vmcnt(0)" ::: "memory")

  bf16x8 af[8], bq[4];

  stage2(0, 0, 0, 0);
  stage2(0, 0, 0, 1);
  stage2(0, 1, 0, 0);
  stage2(0, 1, 0, 1);
  WVM4();
  BAR();

  for (int kt = 0; kt + 1 < KT; ++kt) {
    const int b0 = kt & 1, b1 = b0 ^ 1;
    LDAB8(b0, 0);
    stage2(b1, 0, kt + 1, 0);
    BAR(); WLG0();
    MMA16(0);
    BAR();
    LDA4(b0, 0);
    stage2(b1, 0, kt + 1, 1);
    WVM4();
    BAR(); WLG0();
    MMA16(4);
    BAR();
    LDAB8(b0, 1);
    stage2(b1, 1, kt + 1, 0);
    BAR(); WLG0();
    MMA16(0);
    BAR();
    LDA4(b0, 1);
    stage2(b1, 1, kt + 1, 1);
    WVM4();
    BAR(); WLG0();
    MMA16(4);
    BAR();
  }
  {
    const int b0 = (KT - 1) & 1;
    LDAB8(b0, 0);
    BAR(); WLG0();
    MMA16(0);
    BAR();
    LDA4(b0, 0);
    WVM0();
    BAR(); WLG0();
    MMA16(4);
    BAR();
    LDAB8(b0, 1);
    BAR(); WLG0();
    MMA16(0);
    BAR();
    LDA4(b0, 1);
    BAR(); WLG0();
    MMA16(4);
    BAR();
  }

#pragma unroll
  for (int n = 0; n < 4; n++) {
    int cl = wn * 64 + n * 16 + lrow;
    float bb = bias[bn + cl];
#pragma unroll
    for (int m = 0; m < 8; m++) {
      int rl = wm * 128 + m * 16 + g * 4;
#pragma unroll
      for (int i = 0; i < 4; i++) {
        float v = acc[m][n][i] + bb;
        if (ACT == 1) v = fmaxf(v, 0.f);
        lds[(rl + i) * 256 + cl] = f2bf(v);
      }
    }
  }
  BAR();
  const uint4* lv = (const uint4*)lds;
#pragma unroll
  for (int it = 0; it < 16; it++) {
    int idx = it * 512 + tid;
    int row = idx >> 5;
    int cu = (idx & 31) * 8;
    *(uint4*)&C[(bm + row) * (long)N + bn + cu] = lv[idx];
  }
#undef LDAB8
#undef LDA4
#undef MMA16
#undef WLG0
#undef WVM4
#undef WVM0
}

// --- LayerNorm(a_bf16 + r_f32)*g + be -> f32 ------------------------------
__global__ __launch_bounds__(256) void ln_res(const u16* __restrict__ a,
                                              const float* __restrict__ r,
                                              const float* __restrict__ g,
                                              const float* __restrict__ be,
                                              float* __restrict__ outf) {
  long row = blockIdx.x;
  int tid = threadIdx.x;
  uint2 av = ((const uint2*)(a + row * 1024))[tid];
  float4 rv = ((const float4*)(r + row * 1024))[tid];
  float y[4];
  y[0] = bf2f((u16)(av.x & 0xffff)) + rv.x;
  y[1] = bf2f((u16)(av.x >> 16)) + rv.y;
  y[2] = bf2f((u16)(av.y & 0xffff)) + rv.z;
  y[3] = bf2f((u16)(av.y >> 16)) + rv.w;
  float s = y[0] + y[1] + y[2] + y[3];
  float q = y[0] * y[0] + y[1] * y[1] + y[2] * y[2] + y[3] * y[3];
#pragma unroll
  for (int o = 32; o > 0; o >>= 1) {
    s += __shfl_down(s, o);
    q += __shfl_down(q, o);
  }
  __shared__ float s1[4], s2[4];
  int wid = tid >> 6, lane = tid & 63;
  if (lane == 0) { s1[wid] = s; s2[wid] = q; }
  __syncthreads();
  s = s1[0] + s1[1] + s1[2] + s1[3];
  q = s2[0] + s2[1] + s2[2] + s2[3];
  float mu = s * (1.f / 1024.f);
  float var = q * (1.f / 1024.f) - mu * mu;
  float inv = rsqrtf(fmaxf(var, 0.f) + 1e-6f);
  float4 gv = ((const float4*)g)[tid], bv = ((const float4*)be)[tid];
  float o0 = gv.x * (y[0] - mu) * inv + bv.x;
  float o1 = gv.y * (y[1] - mu) * inv + bv.y;
  float o2 = gv.z * (y[2] - mu) * inv + bv.z;
  float o3 = gv.w * (y[3] - mu) * inv + bv.w;
  ((float4*)(outf + row * 1024))[tid] = make_float4(o0, o1, o2, o3);
}

extern "C" void kernel_launch(void* const* d_in, const int* in_sizes, int n_in,
                              void* d_out, int out_size, void* d_ws,
                              size_t ws_size, hipStream_t stream) {
  const float* x   = (const float*)d_in[0];
  const float* enc = (const float*)d_in[1];
  const float* wq1 = (const float*)d_in[2];  const float* bq1 = (const float*)d_in[3];
  const float* wk1 = (const float*)d_in[4];  const float* bk1 = (const float*)d_in[5];
  const float* wv1 = (const float*)d_in[6];  const float* bv1 = (const float*)d_in[7];
  const float* wo1 = (const float*)d_in[8];  const float* bo1 = (const float*)d_in[9];
  const float* wq2 = (const float*)d_in[10]; const float* bq2 = (const float*)d_in[11];
  const float* wk2 = (const float*)d_in[12]; const float* bk2 = (const float*)d_in[13];
  const float* wv2 = (const float*)d_in[14]; const float* bv2 = (const float*)d_in[15];
  const float* wo2 = (const float*)d_in[16]; const float* bo2 = (const float*)d_in[17];
  const float* wf1 = (const float*)d_in[18]; const float* bf1 = (const float*)d_in[19];
  const float* wf2 = (const float*)d_in[20]; const float* bf2 = (const float*)d_in[21];
  const float* g1 = (const float*)d_in[22];  const float* be1 = (const float*)d_in[23];
  const float* g2 = (const float*)d_in[24];  const float* be2 = (const float*)d_in[25];
  const float* g3 = (const float*)d_in[26];  const float* be3 = (const float*)d_in[27];
  (void)in_sizes; (void)n_in; (void)out_size; (void)ws_size;

  const size_t S = (size_t)16384 * 1024;  // tokens * d_model
  float* O0 = (float*)d_out;              // out3 (f32)

  char* base = (char*)d_ws;
  size_t off = 0;
  auto alloc = [&](size_t bytes) -> void* {
    void* p = base + off;
    off += (bytes + 255) & ~(size_t)255;
    return p;
  };
  u16* WT1    = (u16*)alloc((size_t)4096 * 1024 * 2);  // wf1^T bf16
  u16* WT2    = (u16*)alloc((size_t)4096 * 1024 * 2);  // wf2^T bf16
  float* qb   = (float*)alloc((size_t)16384 * 16 * 4);
  float* kb   = (float*)alloc((size_t)16384 * 16 * 4);
  float* ypart= (float*)alloc((size_t)4 * 32 * 16 * 1024 * 4);  // 8MB
  float* spart= (float*)alloc((size_t)4 * 8 * 16 * 4);
  float* kvb  = (float*)alloc((size_t)4 * 16 * 64 * 4);
  float* zb   = (float*)alloc((size_t)4 * 16 * 1024 * 4);       // 256KB
  u16* FA     = (u16*)alloc(S * 2);                    // bf16: ffn_out
  u16* FM     = (u16*)alloc((size_t)16384 * 4096 * 2); // bf16: ffn mid
  u16* O2b    = (u16*)alloc(S * 2);                    // bf16 out2
  float* O1f  = (float*)alloc(S * 4);                  // f32 out1
  float* O2f  = (float*)alloc(S * 4);                  // f32 out2

  const int T = 16384;
  dim3 blk(256), gblk(512);

  // ---- MHA1 (q=k=v from x, single x read) ----
  proj_mfma<1, 0><<<256, blk, 0, stream>>>(x, nullptr, wq1, bq1, wk1, bk1,
                                           qb, kb);
  ksum<<<dim3(8, 8, 4), blk, 0, stream>>>(kb, x, ypart, spart);
  kv_small<<<64, blk, 0, stream>>>(ypart, spart, wv1, bv1, kvb);
  zker<<<64, blk, 0, stream>>>(kvb, wo1, zb);
  ln_attn<1><<<1024, blk, 0, stream>>>(qb, zb, bo1, x, g1, be1, O1f, nullptr);

  // ---- MHA2 (q from out1 f32, k/v from enc f32) ----
  proj_mfma<0, 0><<<256, blk, 0, stream>>>(O1f, enc, wq2, bq2, wk2, bk2,
                                           qb, kb);
  ksum<<<dim3(8, 8, 4), blk, 0, stream>>>(kb, enc, ypart, spart);
  kv_small<<<64, blk, 0, stream>>>(ypart, spart, wv2, bv2, kvb);
  zker<<<64, blk, 0, stream>>>(kvb, wo2, zb);
  ln_attn<2><<<1024, blk, 0, stream>>>(qb, zb, bo2, O1f, g2, be2, O2f, O2b);

  // ---- FFN ----
  transpose_cvt<<<dim3(128, 32), blk, 0, stream>>>(wf1, WT1, 1024, 4096);
  transpose_cvt<<<dim3(32, 128), blk, 0, stream>>>(wf2, WT2, 4096, 1024);
  gemm256<1><<<dim3(16, 64), gblk, 0, stream>>>(O2b, WT1, bf1, FM, T, 4096, 1024);
  gemm256<0><<<dim3(4, 64), gblk, 0, stream>>>(FM, WT2, bf2, FA, T, 1024, 4096);
  ln_res<<<16384, blk, 0, stream>>>(FA, O2f, g3, be3, O0);  // out3

  // outputs 1 and 2 must be zeros
  hipMemsetAsync((float*)d_out + S, 0, 2 * S * 4, stream);
}